// Round 1
// baseline (875.304 us; speedup 1.0000x reference)
//
#include <hip/hip_runtime.h>

#define TPB 256
static inline int cdiv(int a, int b){ return (a + b - 1) / b; }

#define EPSL 1e-6f

__device__ __forceinline__ float sigf(float x){ return 1.0f / (1.0f + expf(-x)); }

// ---------------- workspace layout (float offsets) ----------------
// OFF_Y1  : y1 (128*16*688=1409024)   ; later u2 (128*64*172=1409024)
// OFF_XF  : xf (128*16*343=702464)    ; later w  (128*32*171=700416)
// OFF_XMIU: x_miu (128*32*171=700416)
// OFF_H1  : h1 (128*64*85=696320)     ; later u1 (344064) ; later h4 (712704, spans into H2)
// OFF_H2  : h2 (128*32*42=172032)
// OFF_H3  : h3 (128*64*86=704512)
// OFF_INP : inp (128*160*171=3502080) ; later x2 (261120) ; fc2h at +262144 (393216)
// OFF_X1  : x1 (128*200*170=4352000)  ; later fc1h (1572864)
// OFF_TAIL: stats(64) + wn(17600)
#define OFF_Y1   0
#define OFF_XF   1409024
#define OFF_XMIU 2111488
#define OFF_H1   2811904
#define OFF_H2   3508224
#define OFF_H3   3680256
#define OFF_INP  4384768
#define OFF_X1   7886848
#define OFF_TAIL 12238848

// ---------------- softmax prep for logic weights ----------------
// wn layout: [0,6400) and2 (20x320); [6400,12800) or2; [12800,15200) and (6x400); [15200,17600) or
__global__ void k_softmax(const float* __restrict__ a2, const float* __restrict__ o2,
                          const float* __restrict__ aw, const float* __restrict__ ow,
                          float* __restrict__ wn){
  int blk = blockIdx.x;
  const float* src; float* dst; int n;
  if (blk < 20)      { src = a2 + blk*320;      dst = wn + blk*320;            n = 320; }
  else if (blk < 40) { src = o2 + (blk-20)*320; dst = wn + 6400 + (blk-20)*320; n = 320; }
  else if (blk < 46) { src = aw + (blk-40)*400; dst = wn + 12800 + (blk-40)*400; n = 400; }
  else               { src = ow + (blk-46)*400; dst = wn + 15200 + (blk-46)*400; n = 400; }
  __shared__ float sh[TPB];
  float m = -1e30f;
  for (int i = threadIdx.x; i < n; i += TPB) m = fmaxf(m, src[i]);
  sh[threadIdx.x] = m; __syncthreads();
  for (int off = TPB/2; off > 0; off >>= 1){
    if (threadIdx.x < off) sh[threadIdx.x] = fmaxf(sh[threadIdx.x], sh[threadIdx.x+off]);
    __syncthreads();
  }
  m = sh[0]; __syncthreads();
  float s = 0.f;
  for (int i = threadIdx.x; i < n; i += TPB) s += expf(src[i] - m);
  sh[threadIdx.x] = s; __syncthreads();
  for (int off = TPB/2; off > 0; off >>= 1){
    if (threadIdx.x < off) sh[threadIdx.x] += sh[threadIdx.x+off];
    __syncthreads();
  }
  float inv = 1.0f / sh[0];
  __syncthreads();
  for (int i = threadIdx.x; i < n; i += TPB) dst[i] = expf(src[i] - m) * inv;
}

// ---------------- stage 1: wave conv (128,1,719)->(128,16,688) ----------------
__global__ void k_conv_wave(const float* __restrict__ x, const float* __restrict__ ww,
                            float* __restrict__ y){
  int idx = blockIdx.x*blockDim.x + threadIdx.x;
  if (idx >= 128*16*688) return;
  int l = idx % 688; int t = idx / 688; int o = t & 15; int b = t >> 4;
  const float* xr = x + b*719 + l;
  const float* wr = ww + o*32;
  float s = 0.f;
  #pragma unroll
  for (int k = 0; k < 32; k++) s = fmaf(xr[k], wr[k], s);
  y[idx] = s;
}

// ---------------- BN stats: per-channel mean/rstd over (b,l) ----------------
__global__ void k_bn_stats(const float* __restrict__ y, float* __restrict__ stats){
  int c = blockIdx.x;
  double s = 0.0, s2 = 0.0;
  for (int i = threadIdx.x; i < 128*688; i += TPB){
    int b = i / 688, l = i % 688;
    float v = y[(b*16 + c)*688 + l];
    s += (double)v; s2 += (double)v * (double)v;
  }
  __shared__ double sh[TPB], sh2[TPB];
  sh[threadIdx.x] = s; sh2[threadIdx.x] = s2; __syncthreads();
  for (int off = TPB/2; off > 0; off >>= 1){
    if (threadIdx.x < off){ sh[threadIdx.x] += sh[threadIdx.x+off]; sh2[threadIdx.x] += sh2[threadIdx.x+off]; }
    __syncthreads();
  }
  if (threadIdx.x == 0){
    double n = 128.0*688.0;
    double m = sh[0] / n;
    double var = sh2[0] / n - m*m;
    stats[c]      = (float)m;
    stats[16 + c] = (float)(1.0 / sqrt(var + 1e-5));
  }
}

// ---------------- xf = maxpool3s2(relu(bn(y))) -> (128,16,343) ----------------
__global__ void k_xf(const float* __restrict__ y, const float* __restrict__ stats,
                     const float* __restrict__ g, const float* __restrict__ bb,
                     float* __restrict__ xf){
  int idx = blockIdx.x*blockDim.x + threadIdx.x;
  if (idx >= 128*16*343) return;
  int l = idx % 343; int t = idx / 343; int c = t & 15; int b = t >> 4;
  float mean = stats[c], rstd = stats[16 + c];
  float gc = g[c], bc = bb[c];
  const float* yr = y + (b*16 + c)*688 + 2*l;
  float m = -1e30f;
  #pragma unroll
  for (int j = 0; j < 3; j++){
    float v = fmaf(gc*(yr[j] - mean), rstd, bc);
    v = fmaxf(v, 0.f);
    m = fmaxf(m, v);
  }
  xf[idx] = m;
}

// ---------------- x_miu = pool3s2(sigmoid(±a(x-b))) -> (128,32,171) ----------------
__global__ void k_xmiu(const float* __restrict__ xf,
                       const float* __restrict__ ap, const float* __restrict__ bp,
                       const float* __restrict__ an, const float* __restrict__ bn,
                       float* __restrict__ out){
  int idx = blockIdx.x*blockDim.x + threadIdx.x;
  if (idx >= 128*32*171) return;
  int l = idx % 171; int t = idx / 171; int c = t & 31; int b = t >> 5;
  int cc = c & 15;
  float sign = (c < 16) ? 1.f : -1.f;
  float a  = (c < 16) ? ap[cc] : an[cc];
  float bo = (c < 16) ? bp[cc] : bn[cc];
  const float* xr = xf + (b*16 + cc)*343 + 2*l;
  float m = -1e30f;
  #pragma unroll
  for (int j = 0; j < 3; j++){
    float v = sigf(sign * a * (xr[j] - bo));
    m = fmaxf(m, v);
  }
  out[idx] = m;
}

// ---------------- h1 = pool3s2(tanh(conv(x_miu, w1, pad1))) -> (128,64,85) ----------------
__global__ void __launch_bounds__(TPB) k_h1(const float* __restrict__ xin, const float* __restrict__ w1,
                                            const float* __restrict__ b1, float* __restrict__ h1){
  int idx = blockIdx.x*blockDim.x + threadIdx.x;
  if (idx >= 128*64*85) return;
  int l = idx % 85; int t = idx / 85; int o = t & 63; int b = t >> 6;
  int base = 2*l;                        // conv positions base..base+2 (len 171)
  float bv = b1[o];
  float s0 = bv, s1 = bv, s2 = bv;
  for (int i = 0; i < 32; i++){
    const float* xr = xin + (b*32 + i)*171 + base;
    float v0 = (base >= 1)     ? xr[-1] : 0.f;
    float v1 = xr[0], v2 = xr[1], v3 = xr[2];
    float v4 = (base + 3 < 171) ? xr[3] : 0.f;
    const float* wr = w1 + (o*32 + i)*3;
    float w0 = wr[0], wv1 = wr[1], w2 = wr[2];
    s0 = fmaf(v0,w0, fmaf(v1,wv1, fmaf(v2,w2, s0)));
    s1 = fmaf(v1,w0, fmaf(v2,wv1, fmaf(v3,w2, s1)));
    s2 = fmaf(v2,w0, fmaf(v3,wv1, fmaf(v4,w2, s2)));
  }
  float m = fmaxf(tanhf(s0), fmaxf(tanhf(s1), tanhf(s2)));
  h1[idx] = m;
}

// ---------------- h2 = pool3s2(relu(conv(h1, w2, pad1))) -> (128,32,42) ----------------
__global__ void __launch_bounds__(TPB) k_h2(const float* __restrict__ xin, const float* __restrict__ w2,
                                            const float* __restrict__ b2, float* __restrict__ h2){
  int idx = blockIdx.x*blockDim.x + threadIdx.x;
  if (idx >= 128*32*42) return;
  int l = idx % 42; int t = idx / 42; int o = t & 31; int b = t >> 5;
  int base = 2*l;                        // conv positions base..base+2 (len 85)
  float bv = b2[o];
  float s0 = bv, s1 = bv, s2 = bv;
  for (int i = 0; i < 64; i++){
    const float* xr = xin + (b*64 + i)*85 + base;
    float v0 = (base >= 1)    ? xr[-1] : 0.f;
    float v1 = xr[0], v2 = xr[1], v3 = xr[2];
    float v4 = (base + 3 < 85) ? xr[3] : 0.f;
    const float* wr = w2 + (o*64 + i)*3;
    float w0 = wr[0], wv1 = wr[1], w2v = wr[2];
    s0 = fmaf(v0,w0, fmaf(v1,wv1, fmaf(v2,w2v, s0)));
    s1 = fmaf(v1,w0, fmaf(v2,wv1, fmaf(v3,w2v, s1)));
    s2 = fmaf(v2,w0, fmaf(v3,wv1, fmaf(v4,w2v, s2)));
  }
  float m = fmaxf(fmaxf(s0,0.f), fmaxf(fmaxf(s1,0.f), fmaxf(s2,0.f)));
  h2[idx] = m;
}

// ---------------- upsample2 (jax linear, half-pixel) ----------------
__global__ void k_up(const float* __restrict__ in, float* __restrict__ out, int rows, int Lin){
  int Lo = 2*Lin;
  int idx = blockIdx.x*blockDim.x + threadIdx.x;
  if (idx >= rows*Lo) return;
  int i = idx % Lo; int r = idx / Lo;
  const float* xr = in + r*Lin;
  float v;
  if (i == 0)            v = xr[0];
  else if (i == Lo - 1)  v = xr[Lin-1];
  else {
    int k = i >> 1;
    if (i & 1) v = 0.75f*xr[k]   + 0.25f*xr[k+1];
    else       v = 0.25f*xr[k-1] + 0.75f*xr[k];
  }
  out[idx] = v;
}

// ---------------- h3 = tanh(conv(u1, w3, pad2)) -> (128,64,86) ----------------
__global__ void __launch_bounds__(TPB) k_h3(const float* __restrict__ xin, const float* __restrict__ w3,
                                            const float* __restrict__ b3, float* __restrict__ h3){
  int idx = blockIdx.x*blockDim.x + threadIdx.x;
  if (idx >= 128*64*86) return;
  int p = idx % 86; int t = idx / 86; int o = t & 63; int b = t >> 6;
  float s = b3[o];
  for (int i = 0; i < 32; i++){
    const float* xr = xin + (b*32 + i)*84;
    const float* wr = w3 + (o*32 + i)*3;
    #pragma unroll
    for (int k = 0; k < 3; k++){
      int q = p - 2 + k;
      if (q >= 0 && q < 84) s = fmaf(xr[q], wr[k], s);
    }
  }
  h3[idx] = tanhf(s);
}

// ---------------- h4 = sigmoid(conv(u2, w4, pad2)) -> (128,32,174) ----------------
__global__ void __launch_bounds__(TPB) k_h4(const float* __restrict__ xin, const float* __restrict__ w4,
                                            const float* __restrict__ b4, float* __restrict__ h4){
  int idx = blockIdx.x*blockDim.x + threadIdx.x;
  if (idx >= 128*32*174) return;
  int p = idx % 174; int t = idx / 174; int o = t & 31; int b = t >> 5;
  float s = b4[o];
  for (int i = 0; i < 64; i++){
    const float* xr = xin + (b*64 + i)*172;
    const float* wr = w4 + (o*64 + i)*3;
    #pragma unroll
    for (int k = 0; k < 3; k++){
      int q = p - 2 + k;
      if (q >= 0 && q < 172) s = fmaf(xr[q], wr[k], s);
    }
  }
  h4[idx] = sigf(s);
}

// ---------------- w = maxpool4s1(h4) -> (128,32,171) ----------------
__global__ void k_w(const float* __restrict__ h4, float* __restrict__ wout){
  int idx = blockIdx.x*blockDim.x + threadIdx.x;
  if (idx >= 128*32*171) return;
  int l = idx % 171; int t = idx / 171;
  const float* xr = h4 + t*174 + l;
  float m = fmaxf(fmaxf(xr[0], xr[1]), fmaxf(xr[2], xr[3]));
  wout[idx] = m;
}

// ---------------- inp: segment masking -> (128,160,171) ----------------
__global__ void k_inp(const float* __restrict__ wbuf, const float* __restrict__ xmiu,
                      float* __restrict__ inp){
  int idx = blockIdx.x*blockDim.x + threadIdx.x;
  if (idx >= 128*32*171) return;
  int l = idx % 171; int t = idx / 171; int c = t & 31; int b = t >> 5;
  float wv = wbuf[idx];
  float xm = xmiu[idx];
  float prod = wv * xm;
  const float lo[5] = {0.0f, 0.2f, 0.4f, 0.6f, 0.8f};
  const float hi[5] = {0.2f, 0.4f, 0.6f, 0.8f, 2.0f};
  float* op = inp + ((b*160) + c)*171 + l;
  #pragma unroll
  for (int s = 0; s < 5; s++){
    bool m = (wv >= lo[s]) && (wv < hi[s]);
    op[s*32*171] = m ? prod : 0.f;
  }
}

// ---------------- until -> x1 channels [40,200) ----------------
__global__ void k_until(const float* __restrict__ inp, float* __restrict__ x1){
  int idx = blockIdx.x*blockDim.x + threadIdx.x;
  if (idx >= 128*160*170) return;
  int l = idx % 170; int t = idx / 170; int c = t % 160; int b = t / 160;
  const float* xr = inp + (b*160 + c)*171;
  float runmin = xr[l];
  float outv = 0.f;
  #pragma unroll 5
  for (int d = 1; d <= 25; d++){
    float xs = (l + d < 171) ? xr[l + d] : 0.f;
    outv = fmaxf(outv, fminf(runmin, xs));
    runmin = fminf(runmin, xs);
  }
  x1[((b*200) + 40 + c)*170 + l] = outv;
}

// ---------------- logic stage 1 -> x1 channels [0,40) ----------------
__global__ void __launch_bounds__(TPB) k_logic1(const float* __restrict__ inp, const float* __restrict__ wn,
                                                float* __restrict__ x1){
  int idx = blockIdx.x*blockDim.x + threadIdx.x;
  if (idx >= 128*2*170) return;
  int l = idx % 170; int t = idx / 170; int v = t & 1; int b = t >> 1;
  const float* W = wn + (v ? 6400 : 0);
  float acc[20];
  #pragma unroll
  for (int o = 0; o < 20; o++) acc[o] = 0.f;
  const float* ir = inp + b*160*171 + l;
  for (int c = 0; c < 160; c++){
    float u0 = ir[c*171];
    float u1 = ir[c*171 + 1];
    u0 = fminf(fmaxf(u0, 0.f), 1.f);
    u1 = fminf(fmaxf(u1, 0.f), 1.f);
    float g0, g1;
    if (v){ g0 = logf(1.f - u0 + EPSL); g1 = logf(1.f - u1 + EPSL); }
    else  { g0 = logf(u0 + EPSL);       g1 = logf(u1 + EPSL); }
    const float* wc = W + c*2;
    #pragma unroll
    for (int o = 0; o < 20; o++)
      acc[o] = fmaf(wc[o*320], g0, fmaf(wc[o*320 + 1], g1, acc[o]));
  }
  float* xr = x1 + (b*200 + v*20)*170 + l;
  #pragma unroll
  for (int o = 0; o < 20; o++){
    float e = expf(acc[o]);
    xr[o*170] = v ? fmaxf(0.f, 1.f - e) : e;
  }
}

// ---------------- logic stage 2 -> x2 (128,12,170) ----------------
__global__ void __launch_bounds__(TPB) k_logic2(const float* __restrict__ x1, const float* __restrict__ wn,
                                                float* __restrict__ x2){
  int idx = blockIdx.x*blockDim.x + threadIdx.x;
  if (idx >= 128*2*170) return;
  int l = idx % 170; int t = idx / 170; int v = t & 1; int b = t >> 1;
  const float* W = wn + 12800 + (v ? 2400 : 0);
  float acc[6];
  #pragma unroll
  for (int o = 0; o < 6; o++) acc[o] = 0.f;
  const float* xr = x1 + b*200*170;
  for (int c = 0; c < 200; c++){
    float g0 = 0.f;                      // left zero-pad (log-domain)
    if (l > 0){
      float u = xr[c*170 + l - 1];
      u = fminf(fmaxf(u, 0.f), 1.f);
      g0 = v ? logf(1.f - u + EPSL) : logf(u + EPSL);
    }
    float u1 = xr[c*170 + l];
    u1 = fminf(fmaxf(u1, 0.f), 1.f);
    float g1 = v ? logf(1.f - u1 + EPSL) : logf(u1 + EPSL);
    const float* wc = W + c*2;
    #pragma unroll
    for (int o = 0; o < 6; o++)
      acc[o] = fmaf(wc[o*400], g0, fmaf(wc[o*400 + 1], g1, acc[o]));
  }
  float* op = x2 + (b*12 + v*6)*170 + l;
  #pragma unroll
  for (int o = 0; o < 6; o++){
    float e = expf(acc[o]);
    op[o*170] = v ? fmaxf(0.f, 1.f - e) : e;
  }
}

// ---------------- fc1: (1536,170)x(1024,170)^T + relu ----------------
__global__ void __launch_bounds__(TPB) k_fc1(const float* __restrict__ x2, const float* __restrict__ w,
                                             const float* __restrict__ bias, float* __restrict__ out){
  __shared__ float rows[8][170];
  int bc0 = blockIdx.x * 8;
  for (int i = threadIdx.x; i < 8*170; i += TPB){
    int r = i / 170, l = i % 170;
    rows[r][l] = x2[(bc0 + r)*170 + l];
  }
  __syncthreads();
  for (int j = 0; j < 4; j++){
    int o = threadIdx.x + j*TPB;
    float bv = bias[o];
    float acc[8];
    #pragma unroll
    for (int r = 0; r < 8; r++) acc[r] = bv;
    const float* wr = w + o*170;
    for (int l = 0; l < 170; l++){
      float wv = wr[l];
      #pragma unroll
      for (int r = 0; r < 8; r++) acc[r] = fmaf(rows[r][l], wv, acc[r]);
    }
    #pragma unroll
    for (int r = 0; r < 8; r++) out[(bc0 + r)*1024 + o] = fmaxf(acc[r], 0.f);
  }
}

// ---------------- fc2: (1536,1024)x(256,1024)^T + relu ----------------
__global__ void __launch_bounds__(TPB) k_fc2(const float* __restrict__ h, const float* __restrict__ w,
                                             const float* __restrict__ bias, float* __restrict__ out){
  __shared__ float rows[8][1024];
  int bc0 = blockIdx.x * 8;
  for (int i = threadIdx.x; i < 8*1024; i += TPB){
    int r = i >> 10, l = i & 1023;
    rows[r][l] = h[(bc0 + r)*1024 + l];
  }
  __syncthreads();
  int p = threadIdx.x;
  float bv = bias[p];
  float acc[8];
  #pragma unroll
  for (int r = 0; r < 8; r++) acc[r] = bv;
  const float* wr = w + p*1024;
  for (int o = 0; o < 1024; o++){
    float wv = wr[o];
    #pragma unroll
    for (int r = 0; r < 8; r++) acc[r] = fmaf(rows[r][o], wv, acc[r]);
  }
  #pragma unroll
  for (int r = 0; r < 8; r++) out[(bc0 + r)*256 + p] = fmaxf(acc[r], 0.f);
}

// ---------------- fc3: (1536,256)x(10,256)^T ----------------
__global__ void k_fc3(const float* __restrict__ h, const float* __restrict__ w,
                      const float* __restrict__ bias, float* __restrict__ out){
  int idx = blockIdx.x*blockDim.x + threadIdx.x;
  if (idx >= 1536*10) return;
  int q = idx % 10; int bc = idx / 10;
  const float* hr = h + bc*256;
  const float* wr = w + q*256;
  float s = bias[q];
  for (int p = 0; p < 256; p++) s = fmaf(hr[p], wr[p], s);
  out[idx] = s;
}

extern "C" void kernel_launch(void* const* d_in, const int* in_sizes, int n_in,
                              void* d_out, int out_size, void* d_ws, size_t ws_size,
                              hipStream_t stream) {
  const float* x      = (const float*)d_in[0];
  const float* wave_w = (const float*)d_in[1];
  const float* bn_g   = (const float*)d_in[2];
  const float* bn_b   = (const float*)d_in[3];
  const float* miu_ap = (const float*)d_in[4];
  const float* miu_bp = (const float*)d_in[5];
  const float* miu_an = (const float*)d_in[6];
  const float* miu_bn = (const float*)d_in[7];
  const float* ae_w1  = (const float*)d_in[8];
  const float* ae_b1  = (const float*)d_in[9];
  const float* ae_w2  = (const float*)d_in[10];
  const float* ae_b2  = (const float*)d_in[11];
  const float* ae_w3  = (const float*)d_in[12];
  const float* ae_b3  = (const float*)d_in[13];
  const float* ae_w4  = (const float*)d_in[14];
  const float* ae_b4  = (const float*)d_in[15];
  const float* and2_w = (const float*)d_in[16];
  const float* or2_w  = (const float*)d_in[17];
  const float* and_w  = (const float*)d_in[18];
  const float* or_w   = (const float*)d_in[19];
  const float* fc1_w  = (const float*)d_in[20];
  const float* fc1_b  = (const float*)d_in[21];
  const float* fc2_w  = (const float*)d_in[22];
  const float* fc2_b  = (const float*)d_in[23];
  const float* fc3_w  = (const float*)d_in[24];
  const float* fc3_b  = (const float*)d_in[25];
  float* out = (float*)d_out;
  float* ws  = (float*)d_ws;

  float* y1    = ws + OFF_Y1;
  float* xf    = ws + OFF_XF;
  float* xmiu  = ws + OFF_XMIU;
  float* h1    = ws + OFF_H1;
  float* h2    = ws + OFF_H2;
  float* u1    = ws + OFF_H1;            // reuse (h1 dead)
  float* h3    = ws + OFF_H3;
  float* u2    = ws + OFF_Y1;            // reuse (y1 dead)
  float* h4    = ws + OFF_H1;            // reuse (u1+h2 dead, spans H1+H2)
  float* wbuf  = ws + OFF_XF;            // reuse (xf dead)
  float* inp   = ws + OFF_INP;
  float* x1    = ws + OFF_X1;
  float* x2    = ws + OFF_INP;           // reuse (inp dead)
  float* fc1h  = ws + OFF_X1;            // reuse (x1 dead)
  float* fc2h  = ws + OFF_INP + 262144;  // after x2
  float* stats = ws + OFF_TAIL;
  float* wn    = ws + OFF_TAIL + 64;

  k_softmax  <<<52, TPB, 0, stream>>>(and2_w, or2_w, and_w, or_w, wn);
  k_conv_wave<<<cdiv(128*16*688, TPB), TPB, 0, stream>>>(x, wave_w, y1);
  k_bn_stats <<<16, TPB, 0, stream>>>(y1, stats);
  k_xf       <<<cdiv(128*16*343, TPB), TPB, 0, stream>>>(y1, stats, bn_g, bn_b, xf);
  k_xmiu     <<<cdiv(128*32*171, TPB), TPB, 0, stream>>>(xf, miu_ap, miu_bp, miu_an, miu_bn, xmiu);
  k_h1       <<<cdiv(128*64*85,  TPB), TPB, 0, stream>>>(xmiu, ae_w1, ae_b1, h1);
  k_h2       <<<cdiv(128*32*42,  TPB), TPB, 0, stream>>>(h1, ae_w2, ae_b2, h2);
  k_up       <<<cdiv(128*32*84,  TPB), TPB, 0, stream>>>(h2, u1, 128*32, 42);
  k_h3       <<<cdiv(128*64*86,  TPB), TPB, 0, stream>>>(u1, ae_w3, ae_b3, h3);
  k_up       <<<cdiv(128*64*172, TPB), TPB, 0, stream>>>(h3, u2, 128*64, 86);
  k_h4       <<<cdiv(128*32*174, TPB), TPB, 0, stream>>>(u2, ae_w4, ae_b4, h4);
  k_w        <<<cdiv(128*32*171, TPB), TPB, 0, stream>>>(h4, wbuf);
  k_inp      <<<cdiv(128*32*171, TPB), TPB, 0, stream>>>(wbuf, xmiu, inp);
  k_until    <<<cdiv(128*160*170,TPB), TPB, 0, stream>>>(inp, x1);
  k_logic1   <<<cdiv(128*2*170,  TPB), TPB, 0, stream>>>(inp, wn, x1);
  k_logic2   <<<cdiv(128*2*170,  TPB), TPB, 0, stream>>>(x1, wn, x2);
  k_fc1      <<<192, TPB, 0, stream>>>(x2, fc1_w, fc1_b, fc1h);
  k_fc2      <<<192, TPB, 0, stream>>>(fc1h, fc2_w, fc2_b, fc2h);
  k_fc3      <<<cdiv(1536*10, TPB), TPB, 0, stream>>>(fc2h, fc3_w, fc3_b, out);
}

// Round 2
// 635.806 us; speedup vs baseline: 1.3767x; 1.3767x over previous
//
#include <hip/hip_runtime.h>

#define TPB 256
static inline int cdiv(int a, int b){ return (a + b - 1) / b; }

#define EPSL 1e-6f

__device__ __forceinline__ float sigf(float x){ return 1.0f / (1.0f + expf(-x)); }
__device__ __forceinline__ float clip01(float x){ return fminf(fmaxf(x, 0.f), 1.f); }

// ---------------- workspace layout (float offsets) ----------------
#define OFF_Y1   0
#define OFF_XF   1409024
#define OFF_XMIU 2111488
#define OFF_H1   2811904
#define OFF_H2   3508224
#define OFF_H3   3680256
#define OFF_INP  4384768
#define OFF_X1   7886848
#define OFF_TAIL 12238848
// p1 (logic1 partials, 4*128*40*170=3481600) reuses [0, 3481600) (y1/xf/xmiu/h1 all dead)
#define OFF_P1   0
// p2 (logic2 partials, 4*128*12*170=1044480) inside dead inp region, clear of x2/fc2h
#define OFF_P2   (OFF_INP + 700000)
// tail: stats(32) @TAIL, bn partials (128 doubles*2 = 512 floats) @TAIL+64, wn @TAIL+64+512
#define OFF_STATS OFF_TAIL
#define OFF_BNP  (OFF_TAIL + 64)
#define OFF_WN   (OFF_TAIL + 64 + 512)

// ---------------- softmax prep for logic weights ----------------
// wn layout: [0,6400) and2 (20x320); [6400,12800) or2; [12800,15200) and (6x400); [15200,17600) or
__global__ void k_softmax(const float* __restrict__ a2, const float* __restrict__ o2,
                          const float* __restrict__ aw, const float* __restrict__ ow,
                          float* __restrict__ wn){
  int blk = blockIdx.x;
  const float* src; float* dst; int n;
  if (blk < 20)      { src = a2 + blk*320;      dst = wn + blk*320;              n = 320; }
  else if (blk < 40) { src = o2 + (blk-20)*320; dst = wn + 6400 + (blk-20)*320;  n = 320; }
  else if (blk < 46) { src = aw + (blk-40)*400; dst = wn + 12800 + (blk-40)*400; n = 400; }
  else               { src = ow + (blk-46)*400; dst = wn + 15200 + (blk-46)*400; n = 400; }
  __shared__ float sh[TPB];
  float m = -1e30f;
  for (int i = threadIdx.x; i < n; i += TPB) m = fmaxf(m, src[i]);
  sh[threadIdx.x] = m; __syncthreads();
  for (int off = TPB/2; off > 0; off >>= 1){
    if (threadIdx.x < off) sh[threadIdx.x] = fmaxf(sh[threadIdx.x], sh[threadIdx.x+off]);
    __syncthreads();
  }
  m = sh[0]; __syncthreads();
  float s = 0.f;
  for (int i = threadIdx.x; i < n; i += TPB) s += expf(src[i] - m);
  sh[threadIdx.x] = s; __syncthreads();
  for (int off = TPB/2; off > 0; off >>= 1){
    if (threadIdx.x < off) sh[threadIdx.x] += sh[threadIdx.x+off];
    __syncthreads();
  }
  float inv = 1.0f / sh[0];
  __syncthreads();
  for (int i = threadIdx.x; i < n; i += TPB) dst[i] = expf(src[i] - m) * inv;
}

// ---------------- stage 1: wave conv (128,1,719)->(128,16,688) ----------------
__global__ void k_conv_wave(const float* __restrict__ x, const float* __restrict__ ww,
                            float* __restrict__ y){
  int idx = blockIdx.x*blockDim.x + threadIdx.x;
  if (idx >= 128*16*688) return;
  int l = idx % 688; int t = idx / 688; int o = t & 15; int b = t >> 4;
  const float* xr = x + b*719 + l;
  const float* wr = ww + o*32;
  float s = 0.f;
  #pragma unroll
  for (int k = 0; k < 32; k++) s = fmaf(xr[k], wr[k], s);
  y[idx] = s;
}

// ---------------- BN stats, stage A: per-(channel,chunk) partial sums ----------------
__global__ void k_bn_part(const float* __restrict__ y, double* __restrict__ bnp){
  int c = blockIdx.x & 15, ch = blockIdx.x >> 4;   // 16 channels x 8 chunks of 16 batches
  double s = 0.0, s2 = 0.0;
  for (int i = threadIdx.x; i < 16*688; i += TPB){
    int b = ch*16 + i/688, l = i % 688;
    float v = y[(b*16 + c)*688 + l];
    s += (double)v; s2 += (double)v * (double)v;
  }
  __shared__ double sh[TPB], sh2[TPB];
  sh[threadIdx.x] = s; sh2[threadIdx.x] = s2; __syncthreads();
  for (int off = TPB/2; off > 0; off >>= 1){
    if (threadIdx.x < off){ sh[threadIdx.x] += sh[threadIdx.x+off]; sh2[threadIdx.x] += sh2[threadIdx.x+off]; }
    __syncthreads();
  }
  if (threadIdx.x == 0){ bnp[blockIdx.x] = sh[0]; bnp[128 + blockIdx.x] = sh2[0]; }
}

// ---------------- BN stats, stage B ----------------
__global__ void k_bn_fin(const double* __restrict__ bnp, float* __restrict__ stats){
  int c = threadIdx.x;
  if (c >= 16) return;
  double s = 0.0, s2 = 0.0;
  for (int j = 0; j < 8; j++){ s += bnp[j*16 + c]; s2 += bnp[128 + j*16 + c]; }
  double n = 128.0*688.0;
  double m = s / n;
  double var = s2 / n - m*m;
  stats[c]      = (float)m;
  stats[16 + c] = (float)(1.0 / sqrt(var + 1e-5));
}

// ---------------- xf = maxpool3s2(relu(bn(y))) -> (128,16,343) ----------------
__global__ void k_xf(const float* __restrict__ y, const float* __restrict__ stats,
                     const float* __restrict__ g, const float* __restrict__ bb,
                     float* __restrict__ xf){
  int idx = blockIdx.x*blockDim.x + threadIdx.x;
  if (idx >= 128*16*343) return;
  int l = idx % 343; int t = idx / 343; int c = t & 15; int b = t >> 4;
  float mean = stats[c], rstd = stats[16 + c];
  float gc = g[c], bc = bb[c];
  const float* yr = y + (b*16 + c)*688 + 2*l;
  float m = -1e30f;
  #pragma unroll
  for (int j = 0; j < 3; j++){
    float v = fmaf(gc*(yr[j] - mean), rstd, bc);
    v = fmaxf(v, 0.f);
    m = fmaxf(m, v);
  }
  xf[idx] = m;
}

// ---------------- x_miu = pool3s2(sigmoid(±a(x-b))) -> (128,32,171) ----------------
__global__ void k_xmiu(const float* __restrict__ xf,
                       const float* __restrict__ ap, const float* __restrict__ bp,
                       const float* __restrict__ an, const float* __restrict__ bn,
                       float* __restrict__ out){
  int idx = blockIdx.x*blockDim.x + threadIdx.x;
  if (idx >= 128*32*171) return;
  int l = idx % 171; int t = idx / 171; int c = t & 31; int b = t >> 5;
  int cc = c & 15;
  float sign = (c < 16) ? 1.f : -1.f;
  float a  = (c < 16) ? ap[cc] : an[cc];
  float bo = (c < 16) ? bp[cc] : bn[cc];
  const float* xr = xf + (b*16 + cc)*343 + 2*l;
  float m = -1e30f;
  #pragma unroll
  for (int j = 0; j < 3; j++){
    float v = sigf(sign * a * (xr[j] - bo));
    m = fmaxf(m, v);
  }
  out[idx] = m;
}

// ---------------- h1 = pool3s2(tanh(conv(x_miu, w1, pad1))) -> (128,64,85) ----------------
__global__ void __launch_bounds__(TPB) k_h1(const float* __restrict__ xin, const float* __restrict__ w1,
                                            const float* __restrict__ b1, float* __restrict__ h1){
  int idx = blockIdx.x*blockDim.x + threadIdx.x;
  if (idx >= 128*64*85) return;
  int l = idx % 85; int t = idx / 85; int o = t & 63; int b = t >> 6;
  int base = 2*l;
  float bv = b1[o];
  float s0 = bv, s1 = bv, s2 = bv;
  for (int i = 0; i < 32; i++){
    const float* xr = xin + (b*32 + i)*171 + base;
    float v0 = (base >= 1)     ? xr[-1] : 0.f;
    float v1 = xr[0], v2 = xr[1], v3 = xr[2];
    float v4 = (base + 3 < 171) ? xr[3] : 0.f;
    const float* wr = w1 + (o*32 + i)*3;
    float w0 = wr[0], wv1 = wr[1], w2 = wr[2];
    s0 = fmaf(v0,w0, fmaf(v1,wv1, fmaf(v2,w2, s0)));
    s1 = fmaf(v1,w0, fmaf(v2,wv1, fmaf(v3,w2, s1)));
    s2 = fmaf(v2,w0, fmaf(v3,wv1, fmaf(v4,w2, s2)));
  }
  float m = fmaxf(tanhf(s0), fmaxf(tanhf(s1), tanhf(s2)));
  h1[idx] = m;
}

// ---------------- h2 = pool3s2(relu(conv(h1, w2, pad1))) -> (128,32,42) ----------------
__global__ void __launch_bounds__(TPB) k_h2(const float* __restrict__ xin, const float* __restrict__ w2,
                                            const float* __restrict__ b2, float* __restrict__ h2){
  int idx = blockIdx.x*blockDim.x + threadIdx.x;
  if (idx >= 128*32*42) return;
  int l = idx % 42; int t = idx / 42; int o = t & 31; int b = t >> 5;
  int base = 2*l;
  float bv = b2[o];
  float s0 = bv, s1 = bv, s2 = bv;
  for (int i = 0; i < 64; i++){
    const float* xr = xin + (b*64 + i)*85 + base;
    float v0 = (base >= 1)    ? xr[-1] : 0.f;
    float v1 = xr[0], v2 = xr[1], v3 = xr[2];
    float v4 = (base + 3 < 85) ? xr[3] : 0.f;
    const float* wr = w2 + (o*64 + i)*3;
    float w0 = wr[0], wv1 = wr[1], w2v = wr[2];
    s0 = fmaf(v0,w0, fmaf(v1,wv1, fmaf(v2,w2v, s0)));
    s1 = fmaf(v1,w0, fmaf(v2,wv1, fmaf(v3,w2v, s1)));
    s2 = fmaf(v2,w0, fmaf(v3,wv1, fmaf(v4,w2v, s2)));
  }
  float m = fmaxf(fmaxf(s0,0.f), fmaxf(fmaxf(s1,0.f), fmaxf(s2,0.f)));
  h2[idx] = m;
}

// ---------------- upsample2 (jax linear, half-pixel) ----------------
__global__ void k_up(const float* __restrict__ in, float* __restrict__ out, int rows, int Lin){
  int Lo = 2*Lin;
  int idx = blockIdx.x*blockDim.x + threadIdx.x;
  if (idx >= rows*Lo) return;
  int i = idx % Lo; int r = idx / Lo;
  const float* xr = in + r*Lin;
  float v;
  if (i == 0)            v = xr[0];
  else if (i == Lo - 1)  v = xr[Lin-1];
  else {
    int k = i >> 1;
    if (i & 1) v = 0.75f*xr[k]   + 0.25f*xr[k+1];
    else       v = 0.25f*xr[k-1] + 0.75f*xr[k];
  }
  out[idx] = v;
}

// ---------------- h3 = tanh(conv(u1, w3, pad2)) -> (128,64,86) ----------------
__global__ void __launch_bounds__(TPB) k_h3(const float* __restrict__ xin, const float* __restrict__ w3,
                                            const float* __restrict__ b3, float* __restrict__ h3){
  int idx = blockIdx.x*blockDim.x + threadIdx.x;
  if (idx >= 128*64*86) return;
  int p = idx % 86; int t = idx / 86; int o = t & 63; int b = t >> 6;
  float s = b3[o];
  for (int i = 0; i < 32; i++){
    const float* xr = xin + (b*32 + i)*84;
    const float* wr = w3 + (o*32 + i)*3;
    #pragma unroll
    for (int k = 0; k < 3; k++){
      int q = p - 2 + k;
      if (q >= 0 && q < 84) s = fmaf(xr[q], wr[k], s);
    }
  }
  h3[idx] = tanhf(s);
}

// ---------------- h4 = sigmoid(conv(u2, w4, pad2)) -> (128,32,174) ----------------
__global__ void __launch_bounds__(TPB) k_h4(const float* __restrict__ xin, const float* __restrict__ w4,
                                            const float* __restrict__ b4, float* __restrict__ h4){
  int idx = blockIdx.x*blockDim.x + threadIdx.x;
  if (idx >= 128*32*174) return;
  int p = idx % 174; int t = idx / 174; int o = t & 31; int b = t >> 5;
  float s = b4[o];
  for (int i = 0; i < 64; i++){
    const float* xr = xin + (b*64 + i)*172;
    const float* wr = w4 + (o*64 + i)*3;
    #pragma unroll
    for (int k = 0; k < 3; k++){
      int q = p - 2 + k;
      if (q >= 0 && q < 172) s = fmaf(xr[q], wr[k], s);
    }
  }
  h4[idx] = sigf(s);
}

// ---------------- inp: fused maxpool4(h4) + segment masking -> (128,160,171) ----------------
__global__ void k_inp(const float* __restrict__ h4, const float* __restrict__ xmiu,
                      float* __restrict__ inp){
  int idx = blockIdx.x*blockDim.x + threadIdx.x;
  if (idx >= 128*32*171) return;
  int l = idx % 171; int t = idx / 171; int c = t & 31; int b = t >> 5;
  const float* hr = h4 + t*174 + l;
  float wv = fmaxf(fmaxf(hr[0], hr[1]), fmaxf(hr[2], hr[3]));
  float xm = xmiu[idx];
  float prod = wv * xm;
  const float lo[5] = {0.0f, 0.2f, 0.4f, 0.6f, 0.8f};
  const float hi[5] = {0.2f, 0.4f, 0.6f, 0.8f, 2.0f};
  float* op = inp + ((b*160) + c)*171 + l;
  #pragma unroll
  for (int s = 0; s < 5; s++){
    bool m = (wv >= lo[s]) && (wv < hi[s]);
    op[s*32*171] = m ? prod : 0.f;
  }
}

// ---------------- until -> x1 channels [40,200) ----------------
__global__ void k_until(const float* __restrict__ inp, float* __restrict__ x1){
  int idx = blockIdx.x*blockDim.x + threadIdx.x;
  if (idx >= 128*160*170) return;
  int l = idx % 170; int t = idx / 170; int c = t % 160; int b = t / 160;
  const float* xr = inp + (b*160 + c)*171;
  float runmin = xr[l];
  float outv = 0.f;
  #pragma unroll 5
  for (int d = 1; d <= 25; d++){
    float xs = (l + d < 171) ? xr[l + d] : 0.f;
    outv = fmaxf(outv, fminf(runmin, xs));
    runmin = fminf(runmin, xs);
  }
  x1[((b*200) + 40 + c)*170 + l] = outv;
}

// ---------------- logic stage 1 partials: 4-way channel split, and+or fused ----------------
// p1 layout: [ch][b][o(40: 20 and, 20 or)][l]
__global__ void __launch_bounds__(TPB) k_logic1p(const float* __restrict__ inp, const float* __restrict__ wn,
                                                 float* __restrict__ p1){
  int idx = blockIdx.x*blockDim.x + threadIdx.x;
  if (idx >= 4*128*170) return;
  int l = idx % 170; int b = (idx/170) & 127; int ch = idx / (170*128);
  float aA[20], aO[20];
  #pragma unroll
  for (int o = 0; o < 20; o++){ aA[o] = 0.f; aO[o] = 0.f; }
  const float* WA = wn;
  const float* WO = wn + 6400;
  int c0 = ch*40;
  for (int c = c0; c < c0 + 40; c++){
    const float* ir = inp + (b*160 + c)*171 + l;
    float u0 = clip01(ir[0]);
    float u1 = clip01(ir[1]);
    float la0 = logf(u0 + EPSL),       la1 = logf(u1 + EPSL);
    float lo0 = logf(1.f - u0 + EPSL), lo1 = logf(1.f - u1 + EPSL);
    #pragma unroll
    for (int o = 0; o < 20; o++){
      aA[o] = fmaf(WA[o*320 + 2*c], la0, fmaf(WA[o*320 + 2*c + 1], la1, aA[o]));
      aO[o] = fmaf(WO[o*320 + 2*c], lo0, fmaf(WO[o*320 + 2*c + 1], lo1, aO[o]));
    }
  }
  float* pp = p1 + ((ch*128 + b)*40)*170 + l;
  #pragma unroll
  for (int o = 0; o < 20; o++){
    pp[o*170]        = aA[o];
    pp[(20 + o)*170] = aO[o];
  }
}

// ---------------- logic stage 1 finalize -> x1 channels [0,40) ----------------
__global__ void k_fin1(const float* __restrict__ p1, float* __restrict__ x1){
  int idx = blockIdx.x*blockDim.x + threadIdx.x;
  if (idx >= 128*40*170) return;
  int l = idx % 170; int o = (idx/170) % 40; int b = idx / (170*40);
  float s = 0.f;
  #pragma unroll
  for (int ch = 0; ch < 4; ch++) s += p1[((ch*128 + b)*40 + o)*170 + l];
  float e = expf(s);
  float r = (o < 20) ? e : fmaxf(0.f, 1.f - e);
  x1[(b*200 + o)*170 + l] = r;
}

// ---------------- logic stage 2 partials: 4-way channel split (50 each) ----------------
// p2 layout: [ch][b][o(12: 6 and, 6 or)][l]
__global__ void __launch_bounds__(TPB) k_logic2p(const float* __restrict__ x1, const float* __restrict__ wn,
                                                 float* __restrict__ p2){
  int idx = blockIdx.x*blockDim.x + threadIdx.x;
  if (idx >= 4*128*170) return;
  int l = idx % 170; int b = (idx/170) & 127; int ch = idx / (170*128);
  float aA[6], aO[6];
  #pragma unroll
  for (int o = 0; o < 6; o++){ aA[o] = 0.f; aO[o] = 0.f; }
  const float* WA = wn + 12800;
  const float* WO = wn + 15200;
  int c0 = ch*50;
  for (int c = c0; c < c0 + 50; c++){
    const float* xr = x1 + (b*200 + c)*170 + l;
    float la0 = 0.f, lo0 = 0.f;       // left zero-pad in log domain
    if (l > 0){
      float u0 = clip01(xr[-1]);
      la0 = logf(u0 + EPSL); lo0 = logf(1.f - u0 + EPSL);
    }
    float u1 = clip01(xr[0]);
    float la1 = logf(u1 + EPSL), lo1 = logf(1.f - u1 + EPSL);
    #pragma unroll
    for (int o = 0; o < 6; o++){
      aA[o] = fmaf(WA[o*400 + 2*c], la0, fmaf(WA[o*400 + 2*c + 1], la1, aA[o]));
      aO[o] = fmaf(WO[o*400 + 2*c], lo0, fmaf(WO[o*400 + 2*c + 1], lo1, aO[o]));
    }
  }
  float* pp = p2 + ((ch*128 + b)*12)*170 + l;
  #pragma unroll
  for (int o = 0; o < 6; o++){
    pp[o*170]       = aA[o];
    pp[(6 + o)*170] = aO[o];
  }
}

// ---------------- logic stage 2 finalize -> x2 (128,12,170) ----------------
__global__ void k_fin2(const float* __restrict__ p2, float* __restrict__ x2){
  int idx = blockIdx.x*blockDim.x + threadIdx.x;
  if (idx >= 128*12*170) return;
  int l = idx % 170; int o = (idx/170) % 12; int b = idx / (170*12);
  float s = 0.f;
  #pragma unroll
  for (int ch = 0; ch < 4; ch++) s += p2[((ch*128 + b)*12 + o)*170 + l];
  float e = expf(s);
  float r = (o < 6) ? e : fmaxf(0.f, 1.f - e);
  x2[(b*12 + o)*170 + l] = r;
}

// ---------------- fc1: (1536,170)x(1024,170)^T + relu ----------------
__global__ void __launch_bounds__(TPB) k_fc1(const float* __restrict__ x2, const float* __restrict__ w,
                                             const float* __restrict__ bias, float* __restrict__ out){
  __shared__ float rows[8][172];                     // padded for aligned float4
  int bc0 = blockIdx.x * 8;
  for (int i = threadIdx.x; i < 8*172; i += TPB){
    int r = i / 172, l = i % 172;
    rows[r][l] = (l < 170) ? x2[(bc0 + r)*170 + l] : 0.f;
  }
  __syncthreads();
  for (int j = 0; j < 4; j++){
    int o = threadIdx.x + j*TPB;
    float bv = bias[o];
    float acc[8];
    #pragma unroll
    for (int r = 0; r < 8; r++) acc[r] = bv;
    const float* wr = w + o*170;
    for (int l = 0; l < 168; l += 4){
      float w0 = wr[l], w1 = wr[l+1], w2 = wr[l+2], w3 = wr[l+3];
      #pragma unroll
      for (int r = 0; r < 8; r++){
        const float4 rv = *(const float4*)(&rows[r][l]);
        acc[r] = fmaf(rv.x, w0, fmaf(rv.y, w1, fmaf(rv.z, w2, fmaf(rv.w, w3, acc[r]))));
      }
    }
    #pragma unroll
    for (int l = 168; l < 170; l++){
      float wv = wr[l];
      #pragma unroll
      for (int r = 0; r < 8; r++) acc[r] = fmaf(rows[r][l], wv, acc[r]);
    }
    #pragma unroll
    for (int r = 0; r < 8; r++) out[(bc0 + r)*1024 + o] = fmaxf(acc[r], 0.f);
  }
}

// ---------------- fc2: (1536,1024)x(256,1024)^T + relu ----------------
__global__ void __launch_bounds__(TPB) k_fc2(const float* __restrict__ h, const float* __restrict__ w,
                                             const float* __restrict__ bias, float* __restrict__ out){
  __shared__ float rows[8][1024];
  int bc0 = blockIdx.x * 8;
  for (int i = threadIdx.x; i < 8*1024; i += TPB){
    int r = i >> 10, l = i & 1023;
    rows[r][l] = h[(bc0 + r)*1024 + l];
  }
  __syncthreads();
  int p = threadIdx.x;
  float bv = bias[p];
  float acc[8];
  #pragma unroll
  for (int r = 0; r < 8; r++) acc[r] = bv;
  const float* wr = w + p*1024;                      // p*1024*4B: 16B-aligned
  for (int o = 0; o < 1024; o += 4){
    const float4 wv = *(const float4*)(wr + o);
    #pragma unroll
    for (int r = 0; r < 8; r++){
      const float4 rv = *(const float4*)(&rows[r][o]);
      acc[r] = fmaf(rv.x, wv.x, fmaf(rv.y, wv.y, fmaf(rv.z, wv.z, fmaf(rv.w, wv.w, acc[r]))));
    }
  }
  #pragma unroll
  for (int r = 0; r < 8; r++) out[(bc0 + r)*256 + p] = fmaxf(acc[r], 0.f);
}

// ---------------- fc3: (1536,256)x(10,256)^T ----------------
__global__ void k_fc3(const float* __restrict__ h, const float* __restrict__ w,
                      const float* __restrict__ bias, float* __restrict__ out){
  int idx = blockIdx.x*blockDim.x + threadIdx.x;
  if (idx >= 1536*10) return;
  int q = idx % 10; int bc = idx / 10;
  const float* hr = h + bc*256;
  const float* wr = w + q*256;
  float s = bias[q];
  for (int p = 0; p < 256; p++) s = fmaf(hr[p], wr[p], s);
  out[idx] = s;
}

extern "C" void kernel_launch(void* const* d_in, const int* in_sizes, int n_in,
                              void* d_out, int out_size, void* d_ws, size_t ws_size,
                              hipStream_t stream) {
  const float* x      = (const float*)d_in[0];
  const float* wave_w = (const float*)d_in[1];
  const float* bn_g   = (const float*)d_in[2];
  const float* bn_b   = (const float*)d_in[3];
  const float* miu_ap = (const float*)d_in[4];
  const float* miu_bp = (const float*)d_in[5];
  const float* miu_an = (const float*)d_in[6];
  const float* miu_bn = (const float*)d_in[7];
  const float* ae_w1  = (const float*)d_in[8];
  const float* ae_b1  = (const float*)d_in[9];
  const float* ae_w2  = (const float*)d_in[10];
  const float* ae_b2  = (const float*)d_in[11];
  const float* ae_w3  = (const float*)d_in[12];
  const float* ae_b3  = (const float*)d_in[13];
  const float* ae_w4  = (const float*)d_in[14];
  const float* ae_b4  = (const float*)d_in[15];
  const float* and2_w = (const float*)d_in[16];
  const float* or2_w  = (const float*)d_in[17];
  const float* and_w  = (const float*)d_in[18];
  const float* or_w   = (const float*)d_in[19];
  const float* fc1_w  = (const float*)d_in[20];
  const float* fc1_b  = (const float*)d_in[21];
  const float* fc2_w  = (const float*)d_in[22];
  const float* fc2_b  = (const float*)d_in[23];
  const float* fc3_w  = (const float*)d_in[24];
  const float* fc3_b  = (const float*)d_in[25];
  float* out = (float*)d_out;
  float* ws  = (float*)d_ws;

  float* y1    = ws + OFF_Y1;
  float* xf    = ws + OFF_XF;
  float* xmiu  = ws + OFF_XMIU;
  float* h1    = ws + OFF_H1;
  float* h2    = ws + OFF_H2;
  float* u1    = ws + OFF_H1;            // reuse (h1 dead)
  float* h3    = ws + OFF_H3;
  float* u2    = ws + OFF_Y1;            // reuse (y1 dead)
  float* h4    = ws + OFF_H1;            // reuse (u1+h2 dead)
  float* inp   = ws + OFF_INP;
  float* x1    = ws + OFF_X1;
  float* p1    = ws + OFF_P1;            // reuse (y1/xf/xmiu/h1 dead)
  float* p2    = ws + OFF_P2;            // reuse (inp dead after until+logic1p)
  float* x2    = ws + OFF_INP;           // reuse (inp dead)
  float* fc1h  = ws + OFF_X1;            // reuse (x1 dead)
  float* fc2h  = ws + OFF_INP + 262144;  // after x2, clear of p2
  float* stats = ws + OFF_STATS;
  double* bnp  = (double*)(ws + OFF_BNP);
  float* wn    = ws + OFF_WN;

  k_softmax  <<<52, TPB, 0, stream>>>(and2_w, or2_w, and_w, or_w, wn);
  k_conv_wave<<<cdiv(128*16*688, TPB), TPB, 0, stream>>>(x, wave_w, y1);
  k_bn_part  <<<128, TPB, 0, stream>>>(y1, bnp);
  k_bn_fin   <<<1, 64, 0, stream>>>(bnp, stats);
  k_xf       <<<cdiv(128*16*343, TPB), TPB, 0, stream>>>(y1, stats, bn_g, bn_b, xf);
  k_xmiu     <<<cdiv(128*32*171, TPB), TPB, 0, stream>>>(xf, miu_ap, miu_bp, miu_an, miu_bn, xmiu);
  k_h1       <<<cdiv(128*64*85,  TPB), TPB, 0, stream>>>(xmiu, ae_w1, ae_b1, h1);
  k_h2       <<<cdiv(128*32*42,  TPB), TPB, 0, stream>>>(h1, ae_w2, ae_b2, h2);
  k_up       <<<cdiv(128*32*84,  TPB), TPB, 0, stream>>>(h2, u1, 128*32, 42);
  k_h3       <<<cdiv(128*64*86,  TPB), TPB, 0, stream>>>(u1, ae_w3, ae_b3, h3);
  k_up       <<<cdiv(128*64*172, TPB), TPB, 0, stream>>>(h3, u2, 128*64, 86);
  k_h4       <<<cdiv(128*32*174, TPB), TPB, 0, stream>>>(u2, ae_w4, ae_b4, h4);
  k_inp      <<<cdiv(128*32*171, TPB), TPB, 0, stream>>>(h4, xmiu, inp);
  k_until    <<<cdiv(128*160*170,TPB), TPB, 0, stream>>>(inp, x1);
  k_logic1p  <<<cdiv(4*128*170,  TPB), TPB, 0, stream>>>(inp, wn, p1);
  k_fin1     <<<cdiv(128*40*170, TPB), TPB, 0, stream>>>(p1, x1);
  k_logic2p  <<<cdiv(4*128*170,  TPB), TPB, 0, stream>>>(x1, wn, p2);
  k_fin2     <<<cdiv(128*12*170, TPB), TPB, 0, stream>>>(p2, x2);
  k_fc1      <<<192, TPB, 0, stream>>>(x2, fc1_w, fc1_b, fc1h);
  k_fc2      <<<192, TPB, 0, stream>>>(fc1h, fc2_w, fc2_b, fc2h);
  k_fc3      <<<cdiv(1536*10, TPB), TPB, 0, stream>>>(fc2h, fc3_w, fc3_b, out);
}

// Round 3
// 569.193 us; speedup vs baseline: 1.5378x; 1.1170x over previous
//
#include <hip/hip_runtime.h>

#define TPB 256
static inline int cdiv(int a, int b){ return (a + b - 1) / b; }

#define EPSL 1e-6f

__device__ __forceinline__ float sigf(float x){ return 1.0f / (1.0f + __expf(-x)); }
__device__ __forceinline__ float clip01(float x){ return fminf(fmaxf(x, 0.f), 1.f); }

// ---------------- workspace layout (float offsets) ----------------
#define OFF_Y1   0
#define OFF_XF   1409024
#define OFF_XMIU 2111488
#define OFF_H1   2811904
#define OFF_H2   3508224
#define OFF_H3   3680256
#define OFF_INP  4384768
#define OFF_X1   7886848
#define OFF_TAIL 12238848
// p1 (logic1 partials, 4*128*40*170=3481600) reuses [0, 3481600) (front buffers dead)
#define OFF_P1   0
// p2 (logic2 partials, 4*128*12*170=1044480) reuses [0,...) (p1 dead by then)
#define OFF_P2   0
#define OFF_STATS OFF_TAIL
#define OFF_BNP  (OFF_TAIL + 64)
#define OFF_WN   (OFF_TAIL + 64 + 512)

// ---------------- softmax prep for logic weights ----------------
// wn layout: [0,6400) and2 (20x320); [6400,12800) or2; [12800,15200) and (6x400); [15200,17600) or
__global__ void k_softmax(const float* __restrict__ a2, const float* __restrict__ o2,
                          const float* __restrict__ aw, const float* __restrict__ ow,
                          float* __restrict__ wn){
  int blk = blockIdx.x;
  const float* src; float* dst; int n;
  if (blk < 20)      { src = a2 + blk*320;      dst = wn + blk*320;              n = 320; }
  else if (blk < 40) { src = o2 + (blk-20)*320; dst = wn + 6400 + (blk-20)*320;  n = 320; }
  else if (blk < 46) { src = aw + (blk-40)*400; dst = wn + 12800 + (blk-40)*400; n = 400; }
  else               { src = ow + (blk-46)*400; dst = wn + 15200 + (blk-46)*400; n = 400; }
  __shared__ float sh[TPB];
  float m = -1e30f;
  for (int i = threadIdx.x; i < n; i += TPB) m = fmaxf(m, src[i]);
  sh[threadIdx.x] = m; __syncthreads();
  for (int off = TPB/2; off > 0; off >>= 1){
    if (threadIdx.x < off) sh[threadIdx.x] = fmaxf(sh[threadIdx.x], sh[threadIdx.x+off]);
    __syncthreads();
  }
  m = sh[0]; __syncthreads();
  float s = 0.f;
  for (int i = threadIdx.x; i < n; i += TPB) s += expf(src[i] - m);
  sh[threadIdx.x] = s; __syncthreads();
  for (int off = TPB/2; off > 0; off >>= 1){
    if (threadIdx.x < off) sh[threadIdx.x] += sh[threadIdx.x+off];
    __syncthreads();
  }
  float inv = 1.0f / sh[0];
  __syncthreads();
  for (int i = threadIdx.x; i < n; i += TPB) dst[i] = expf(src[i] - m) * inv;
}

// ---------------- stage 1: wave conv (128,1,719)->(128,16,688) ----------------
__global__ void k_conv_wave(const float* __restrict__ x, const float* __restrict__ ww,
                            float* __restrict__ y){
  int idx = blockIdx.x*blockDim.x + threadIdx.x;
  if (idx >= 128*16*688) return;
  int l = idx % 688; int t = idx / 688; int o = t & 15; int b = t >> 4;
  const float* xr = x + b*719 + l;
  const float* wr = ww + o*32;
  float s = 0.f;
  #pragma unroll
  for (int k = 0; k < 32; k++) s = fmaf(xr[k], wr[k], s);
  y[idx] = s;
}

// ---------------- BN stats, stage A ----------------
__global__ void k_bn_part(const float* __restrict__ y, double* __restrict__ bnp){
  int c = blockIdx.x & 15, ch = blockIdx.x >> 4;
  double s = 0.0, s2 = 0.0;
  for (int i = threadIdx.x; i < 16*688; i += TPB){
    int b = ch*16 + i/688, l = i % 688;
    float v = y[(b*16 + c)*688 + l];
    s += (double)v; s2 += (double)v * (double)v;
  }
  __shared__ double sh[TPB], sh2[TPB];
  sh[threadIdx.x] = s; sh2[threadIdx.x] = s2; __syncthreads();
  for (int off = TPB/2; off > 0; off >>= 1){
    if (threadIdx.x < off){ sh[threadIdx.x] += sh[threadIdx.x+off]; sh2[threadIdx.x] += sh2[threadIdx.x+off]; }
    __syncthreads();
  }
  if (threadIdx.x == 0){ bnp[blockIdx.x] = sh[0]; bnp[128 + blockIdx.x] = sh2[0]; }
}

// ---------------- BN stats, stage B ----------------
__global__ void k_bn_fin(const double* __restrict__ bnp, float* __restrict__ stats){
  int c = threadIdx.x;
  if (c >= 16) return;
  double s = 0.0, s2 = 0.0;
  for (int j = 0; j < 8; j++){ s += bnp[j*16 + c]; s2 += bnp[128 + j*16 + c]; }
  double n = 128.0*688.0;
  double m = s / n;
  double var = s2 / n - m*m;
  stats[c]      = (float)m;
  stats[16 + c] = (float)(1.0 / sqrt(var + 1e-5));
}

// ---------------- xf = maxpool3s2(relu(bn(y))) -> (128,16,343) ----------------
__global__ void k_xf(const float* __restrict__ y, const float* __restrict__ stats,
                     const float* __restrict__ g, const float* __restrict__ bb,
                     float* __restrict__ xf){
  int idx = blockIdx.x*blockDim.x + threadIdx.x;
  if (idx >= 128*16*343) return;
  int l = idx % 343; int t = idx / 343; int c = t & 15; int b = t >> 4;
  float mean = stats[c], rstd = stats[16 + c];
  float gc = g[c], bc = bb[c];
  const float* yr = y + (b*16 + c)*688 + 2*l;
  float m = -1e30f;
  #pragma unroll
  for (int j = 0; j < 3; j++){
    float v = fmaf(gc*(yr[j] - mean), rstd, bc);
    v = fmaxf(v, 0.f);
    m = fmaxf(m, v);
  }
  xf[idx] = m;
}

// ---------------- x_miu = pool3s2(sigmoid(±a(x-b))) -> (128,32,171) ----------------
__global__ void k_xmiu(const float* __restrict__ xf,
                       const float* __restrict__ ap, const float* __restrict__ bp,
                       const float* __restrict__ an, const float* __restrict__ bn,
                       float* __restrict__ out){
  int idx = blockIdx.x*blockDim.x + threadIdx.x;
  if (idx >= 128*32*171) return;
  int l = idx % 171; int t = idx / 171; int c = t & 31; int b = t >> 5;
  int cc = c & 15;
  float sign = (c < 16) ? 1.f : -1.f;
  float a  = (c < 16) ? ap[cc] : an[cc];
  float bo = (c < 16) ? bp[cc] : bn[cc];
  const float* xr = xf + (b*16 + cc)*343 + 2*l;
  float m = -1e30f;
  #pragma unroll
  for (int j = 0; j < 3; j++){
    float v = sigf(sign * a * (xr[j] - bo));
    m = fmaxf(m, v);
  }
  out[idx] = m;
}

// ---------------- h1 = pool3s2(tanh(conv(x_miu, w1, pad1))) -> (128,64,85) ----------------
__global__ void __launch_bounds__(TPB) k_h1(const float* __restrict__ xin, const float* __restrict__ w1,
                                            const float* __restrict__ b1, float* __restrict__ h1){
  int idx = blockIdx.x*blockDim.x + threadIdx.x;
  if (idx >= 128*64*85) return;
  int l = idx % 85; int t = idx / 85; int o = t & 63; int b = t >> 6;
  int base = 2*l;
  float bv = b1[o];
  float s0 = bv, s1 = bv, s2 = bv;
  for (int i = 0; i < 32; i++){
    const float* xr = xin + (b*32 + i)*171 + base;
    float v0 = (base >= 1)     ? xr[-1] : 0.f;
    float v1 = xr[0], v2 = xr[1], v3 = xr[2];
    float v4 = (base + 3 < 171) ? xr[3] : 0.f;
    const float* wr = w1 + (o*32 + i)*3;
    float w0 = wr[0], wv1 = wr[1], w2 = wr[2];
    s0 = fmaf(v0,w0, fmaf(v1,wv1, fmaf(v2,w2, s0)));
    s1 = fmaf(v1,w0, fmaf(v2,wv1, fmaf(v3,w2, s1)));
    s2 = fmaf(v2,w0, fmaf(v3,wv1, fmaf(v4,w2, s2)));
  }
  float m = fmaxf(tanhf(s0), fmaxf(tanhf(s1), tanhf(s2)));
  h1[idx] = m;
}

// ---------------- h2 = pool3s2(relu(conv(h1, w2, pad1))) -> (128,32,42) ----------------
__global__ void __launch_bounds__(TPB) k_h2(const float* __restrict__ xin, const float* __restrict__ w2,
                                            const float* __restrict__ b2, float* __restrict__ h2){
  int idx = blockIdx.x*blockDim.x + threadIdx.x;
  if (idx >= 128*32*42) return;
  int l = idx % 42; int t = idx / 42; int o = t & 31; int b = t >> 5;
  int base = 2*l;
  float bv = b2[o];
  float s0 = bv, s1 = bv, s2 = bv;
  for (int i = 0; i < 64; i++){
    const float* xr = xin + (b*64 + i)*85 + base;
    float v0 = (base >= 1)    ? xr[-1] : 0.f;
    float v1 = xr[0], v2 = xr[1], v3 = xr[2];
    float v4 = (base + 3 < 85) ? xr[3] : 0.f;
    const float* wr = w2 + (o*64 + i)*3;
    float w0 = wr[0], wv1 = wr[1], w2v = wr[2];
    s0 = fmaf(v0,w0, fmaf(v1,wv1, fmaf(v2,w2v, s0)));
    s1 = fmaf(v1,w0, fmaf(v2,wv1, fmaf(v3,w2v, s1)));
    s2 = fmaf(v2,w0, fmaf(v3,wv1, fmaf(v4,w2v, s2)));
  }
  float m = fmaxf(fmaxf(s0,0.f), fmaxf(fmaxf(s1,0.f), fmaxf(s2,0.f)));
  h2[idx] = m;
}

// ---------------- upsample2 (jax linear, half-pixel) ----------------
__global__ void k_up(const float* __restrict__ in, float* __restrict__ out, int rows, int Lin){
  int Lo = 2*Lin;
  int idx = blockIdx.x*blockDim.x + threadIdx.x;
  if (idx >= rows*Lo) return;
  int i = idx % Lo; int r = idx / Lo;
  const float* xr = in + r*Lin;
  float v;
  if (i == 0)            v = xr[0];
  else if (i == Lo - 1)  v = xr[Lin-1];
  else {
    int k = i >> 1;
    if (i & 1) v = 0.75f*xr[k]   + 0.25f*xr[k+1];
    else       v = 0.25f*xr[k-1] + 0.75f*xr[k];
  }
  out[idx] = v;
}

// ---------------- h3 = tanh(conv(u1, w3, pad2)) -> (128,64,86) ----------------
__global__ void __launch_bounds__(TPB) k_h3(const float* __restrict__ xin, const float* __restrict__ w3,
                                            const float* __restrict__ b3, float* __restrict__ h3){
  int idx = blockIdx.x*blockDim.x + threadIdx.x;
  if (idx >= 128*64*86) return;
  int p = idx % 86; int t = idx / 86; int o = t & 63; int b = t >> 6;
  float s = b3[o];
  for (int i = 0; i < 32; i++){
    const float* xr = xin + (b*32 + i)*84;
    const float* wr = w3 + (o*32 + i)*3;
    #pragma unroll
    for (int k = 0; k < 3; k++){
      int q = p - 2 + k;
      if (q >= 0 && q < 84) s = fmaf(xr[q], wr[k], s);
    }
  }
  h3[idx] = tanhf(s);
}

// ---------------- h4 = sigmoid(conv(u2, w4, pad2)) -> (128,32,174) ----------------
__global__ void __launch_bounds__(TPB) k_h4(const float* __restrict__ xin, const float* __restrict__ w4,
                                            const float* __restrict__ b4, float* __restrict__ h4){
  int idx = blockIdx.x*blockDim.x + threadIdx.x;
  if (idx >= 128*32*174) return;
  int p = idx % 174; int t = idx / 174; int o = t & 31; int b = t >> 5;
  float s = b4[o];
  for (int i = 0; i < 64; i++){
    const float* xr = xin + (b*64 + i)*172;
    const float* wr = w4 + (o*64 + i)*3;
    #pragma unroll
    for (int k = 0; k < 3; k++){
      int q = p - 2 + k;
      if (q >= 0 && q < 172) s = fmaf(xr[q], wr[k], s);
    }
  }
  h4[idx] = sigf(s);
}

// ---------------- inp: fused maxpool4(h4) + segment masking -> (128,160,171) ----------------
__global__ void k_inp(const float* __restrict__ h4, const float* __restrict__ xmiu,
                      float* __restrict__ inp){
  int idx = blockIdx.x*blockDim.x + threadIdx.x;
  if (idx >= 128*32*171) return;
  int l = idx % 171; int t = idx / 171; int c = t & 31; int b = t >> 5;
  const float* hr = h4 + t*174 + l;
  float wv = fmaxf(fmaxf(hr[0], hr[1]), fmaxf(hr[2], hr[3]));
  float xm = xmiu[idx];
  float prod = wv * xm;
  const float lo[5] = {0.0f, 0.2f, 0.4f, 0.6f, 0.8f};
  const float hi[5] = {0.2f, 0.4f, 0.6f, 0.8f, 2.0f};
  float* op = inp + ((b*160) + c)*171 + l;
  #pragma unroll
  for (int s = 0; s < 5; s++){
    bool m = (wv >= lo[s]) && (wv < hi[s]);
    op[s*32*171] = m ? prod : 0.f;
  }
}

// ---------------- until -> x1 channels [40,200) ----------------
__global__ void k_until(const float* __restrict__ inp, float* __restrict__ x1){
  int idx = blockIdx.x*blockDim.x + threadIdx.x;
  if (idx >= 128*160*170) return;
  int l = idx % 170; int t = idx / 170; int c = t % 160; int b = t / 160;
  const float* xr = inp + (b*160 + c)*171;
  float runmin = xr[l];
  float outv = 0.f;
  #pragma unroll 5
  for (int d = 1; d <= 25; d++){
    float xs = (l + d < 171) ? xr[l + d] : 0.f;
    outv = fmaxf(outv, fminf(runmin, xs));
    runmin = fminf(runmin, xs);
  }
  x1[((b*200) + 40 + c)*170 + l] = outv;
}

// ---------------- logic stage 1 partials: grid (85, ch=4, v=2) ----------------
// p1 layout: [ch][b][o(40: 20 and, 20 or)][l]; block-uniform (ch,v) => scalar weight loads
__global__ void __launch_bounds__(TPB) k_logic1p(const float* __restrict__ inp, const float* __restrict__ wn,
                                                 float* __restrict__ p1){
  int bl = blockIdx.x*TPB + threadIdx.x;        // 128*170 exactly
  int l = bl % 170; int b = bl / 170;
  int ch = blockIdx.y, v = blockIdx.z;
  const float* W = wn + (v ? 6400 : 0);
  float acc[20];
  #pragma unroll
  for (int o = 0; o < 20; o++) acc[o] = 0.f;
  int c0 = ch*40;
  const float* ir = inp + (b*160 + c0)*171 + l;
  for (int c = 0; c < 40; c++){
    float u0 = clip01(ir[0]);
    float u1 = clip01(ir[1]);
    float g0, g1;
    if (v){ g0 = __logf(1.f - u0 + EPSL); g1 = __logf(1.f - u1 + EPSL); }
    else  { g0 = __logf(u0 + EPSL);       g1 = __logf(u1 + EPSL); }
    const float* wc = W + 2*(c0 + c);
    #pragma unroll
    for (int o = 0; o < 20; o++)
      acc[o] = fmaf(wc[o*320], g0, fmaf(wc[o*320 + 1], g1, acc[o]));
    ir += 171;
  }
  float* pp = p1 + ((ch*128 + b)*40 + v*20)*170 + l;
  #pragma unroll
  for (int o = 0; o < 20; o++) pp[o*170] = acc[o];
}

// ---------------- logic stage 1 finalize -> x1 channels [0,40) ----------------
__global__ void k_fin1(const float* __restrict__ p1, float* __restrict__ x1){
  int idx = blockIdx.x*blockDim.x + threadIdx.x;
  if (idx >= 128*40*170) return;
  int l = idx % 170; int o = (idx/170) % 40; int b = idx / (170*40);
  float s = 0.f;
  #pragma unroll
  for (int ch = 0; ch < 4; ch++) s += p1[((ch*128 + b)*40 + o)*170 + l];
  float e = __expf(s);
  float r = (o < 20) ? e : fmaxf(0.f, 1.f - e);
  x1[(b*200 + o)*170 + l] = r;
}

// ---------------- logic stage 2 partials: grid (85, ch=4, v=2) ----------------
// p2 layout: [ch][b][o(12: 6 and, 6 or)][l]
__global__ void __launch_bounds__(TPB) k_logic2p(const float* __restrict__ x1, const float* __restrict__ wn,
                                                 float* __restrict__ p2){
  int bl = blockIdx.x*TPB + threadIdx.x;
  int l = bl % 170; int b = bl / 170;
  int ch = blockIdx.y, v = blockIdx.z;
  const float* W = wn + 12800 + (v ? 2400 : 0);
  float acc[6] = {0.f,0.f,0.f,0.f,0.f,0.f};
  int c0 = ch*50;
  const float* xr = x1 + (b*200 + c0)*170 + l;
  for (int c = 0; c < 50; c++){
    float g0 = 0.f;                      // left zero-pad (log-domain)
    if (l > 0){
      float u0 = clip01(xr[-1]);
      g0 = v ? __logf(1.f - u0 + EPSL) : __logf(u0 + EPSL);
    }
    float u1 = clip01(xr[0]);
    float g1 = v ? __logf(1.f - u1 + EPSL) : __logf(u1 + EPSL);
    const float* wc = W + 2*(c0 + c);
    #pragma unroll
    for (int o = 0; o < 6; o++)
      acc[o] = fmaf(wc[o*400], g0, fmaf(wc[o*400 + 1], g1, acc[o]));
    xr += 170;
  }
  float* pp = p2 + ((ch*128 + b)*12 + v*6)*170 + l;
  #pragma unroll
  for (int o = 0; o < 6; o++) pp[o*170] = acc[o];
}

// ---------------- logic stage 2 finalize -> x2 (128,12,170) ----------------
__global__ void k_fin2(const float* __restrict__ p2, float* __restrict__ x2){
  int idx = blockIdx.x*blockDim.x + threadIdx.x;
  if (idx >= 128*12*170) return;
  int l = idx % 170; int o = (idx/170) % 12; int b = idx / (170*12);
  float s = 0.f;
  #pragma unroll
  for (int ch = 0; ch < 4; ch++) s += p2[((ch*128 + b)*12 + o)*170 + l];
  float e = __expf(s);
  float r = (o < 6) ? e : fmaxf(0.f, 1.f - e);
  x2[(b*12 + o)*170 + l] = r;
}

// ---------------- fc1: (1536,170)x(1024,170)^T + relu, 4 rows/block ----------------
__global__ void __launch_bounds__(TPB) k_fc1(const float* __restrict__ x2, const float* __restrict__ w,
                                             const float* __restrict__ bias, float* __restrict__ out){
  __shared__ float rows[4][172];
  int bc0 = blockIdx.x * 4;
  for (int i = threadIdx.x; i < 4*172; i += TPB){
    int r = i / 172, l = i % 172;
    rows[r][l] = (l < 170) ? x2[(bc0 + r)*170 + l] : 0.f;
  }
  __syncthreads();
  for (int j = 0; j < 4; j++){
    int o = threadIdx.x + j*TPB;
    float bv = bias[o];
    float acc[4];
    #pragma unroll
    for (int r = 0; r < 4; r++) acc[r] = bv;
    const float* wr = w + o*170;
    for (int l = 0; l < 168; l += 4){
      float w0 = wr[l], w1 = wr[l+1], w2 = wr[l+2], w3 = wr[l+3];
      #pragma unroll
      for (int r = 0; r < 4; r++){
        const float4 rv = *(const float4*)(&rows[r][l]);
        acc[r] = fmaf(rv.x, w0, fmaf(rv.y, w1, fmaf(rv.z, w2, fmaf(rv.w, w3, acc[r]))));
      }
    }
    #pragma unroll
    for (int l = 168; l < 170; l++){
      float wv = wr[l];
      #pragma unroll
      for (int r = 0; r < 4; r++) acc[r] = fmaf(rows[r][l], wv, acc[r]);
    }
    #pragma unroll
    for (int r = 0; r < 4; r++) out[(bc0 + r)*1024 + o] = fmaxf(acc[r], 0.f);
  }
}

// ---------------- fc2: (1536,1024)x(256,1024)^T + relu, 4 rows/block ----------------
__global__ void __launch_bounds__(TPB) k_fc2(const float* __restrict__ h, const float* __restrict__ w,
                                             const float* __restrict__ bias, float* __restrict__ out){
  __shared__ float rows[4][1024];
  int bc0 = blockIdx.x * 4;
  for (int i = threadIdx.x; i < 4*1024; i += TPB){
    int r = i >> 10, l = i & 1023;
    rows[r][l] = h[(bc0 + r)*1024 + l];
  }
  __syncthreads();
  int p = threadIdx.x;
  float bv = bias[p];
  float acc[4];
  #pragma unroll
  for (int r = 0; r < 4; r++) acc[r] = bv;
  const float* wr = w + p*1024;
  for (int o = 0; o < 1024; o += 4){
    const float4 wv = *(const float4*)(wr + o);
    #pragma unroll
    for (int r = 0; r < 4; r++){
      const float4 rv = *(const float4*)(&rows[r][o]);
      acc[r] = fmaf(rv.x, wv.x, fmaf(rv.y, wv.y, fmaf(rv.z, wv.z, fmaf(rv.w, wv.w, acc[r]))));
    }
  }
  #pragma unroll
  for (int r = 0; r < 4; r++) out[(bc0 + r)*256 + p] = fmaxf(acc[r], 0.f);
}

// ---------------- fc3: (1536,256)x(10,256)^T ----------------
__global__ void k_fc3(const float* __restrict__ h, const float* __restrict__ w,
                      const float* __restrict__ bias, float* __restrict__ out){
  int idx = blockIdx.x*blockDim.x + threadIdx.x;
  if (idx >= 1536*10) return;
  int q = idx % 10; int bc = idx / 10;
  const float* hr = h + bc*256;
  const float* wr = w + q*256;
  float s = bias[q];
  for (int p = 0; p < 256; p++) s = fmaf(hr[p], wr[p], s);
  out[idx] = s;
}

extern "C" void kernel_launch(void* const* d_in, const int* in_sizes, int n_in,
                              void* d_out, int out_size, void* d_ws, size_t ws_size,
                              hipStream_t stream) {
  const float* x      = (const float*)d_in[0];
  const float* wave_w = (const float*)d_in[1];
  const float* bn_g   = (const float*)d_in[2];
  const float* bn_b   = (const float*)d_in[3];
  const float* miu_ap = (const float*)d_in[4];
  const float* miu_bp = (const float*)d_in[5];
  const float* miu_an = (const float*)d_in[6];
  const float* miu_bn = (const float*)d_in[7];
  const float* ae_w1  = (const float*)d_in[8];
  const float* ae_b1  = (const float*)d_in[9];
  const float* ae_w2  = (const float*)d_in[10];
  const float* ae_b2  = (const float*)d_in[11];
  const float* ae_w3  = (const float*)d_in[12];
  const float* ae_b3  = (const float*)d_in[13];
  const float* ae_w4  = (const float*)d_in[14];
  const float* ae_b4  = (const float*)d_in[15];
  const float* and2_w = (const float*)d_in[16];
  const float* or2_w  = (const float*)d_in[17];
  const float* and_w  = (const float*)d_in[18];
  const float* or_w   = (const float*)d_in[19];
  const float* fc1_w  = (const float*)d_in[20];
  const float* fc1_b  = (const float*)d_in[21];
  const float* fc2_w  = (const float*)d_in[22];
  const float* fc2_b  = (const float*)d_in[23];
  const float* fc3_w  = (const float*)d_in[24];
  const float* fc3_b  = (const float*)d_in[25];
  float* out = (float*)d_out;
  float* ws  = (float*)d_ws;

  float* y1    = ws + OFF_Y1;
  float* xf    = ws + OFF_XF;
  float* xmiu  = ws + OFF_XMIU;
  float* h1    = ws + OFF_H1;
  float* h2    = ws + OFF_H2;
  float* u1    = ws + OFF_H1;            // reuse (h1 dead)
  float* h3    = ws + OFF_H3;
  float* u2    = ws + OFF_Y1;            // reuse (y1 dead)
  float* h4    = ws + OFF_H1;            // reuse (u1+h2 dead)
  float* inp   = ws + OFF_INP;
  float* x1    = ws + OFF_X1;
  float* p1    = ws + OFF_P1;            // reuse (front buffers dead)
  float* p2    = ws + OFF_P2;            // reuse (p1 dead after fin1)
  float* x2    = ws + OFF_INP;           // reuse (inp dead)
  float* fc1h  = ws + OFF_X1;            // reuse (x1 dead)
  float* fc2h  = ws + OFF_INP + 262144;  // after x2
  float* stats = ws + OFF_STATS;
  double* bnp  = (double*)(ws + OFF_BNP);
  float* wn    = ws + OFF_WN;

  k_softmax  <<<52, TPB, 0, stream>>>(and2_w, or2_w, and_w, or_w, wn);
  k_conv_wave<<<cdiv(128*16*688, TPB), TPB, 0, stream>>>(x, wave_w, y1);
  k_bn_part  <<<128, TPB, 0, stream>>>(y1, bnp);
  k_bn_fin   <<<1, 64, 0, stream>>>(bnp, stats);
  k_xf       <<<cdiv(128*16*343, TPB), TPB, 0, stream>>>(y1, stats, bn_g, bn_b, xf);
  k_xmiu     <<<cdiv(128*32*171, TPB), TPB, 0, stream>>>(xf, miu_ap, miu_bp, miu_an, miu_bn, xmiu);
  k_h1       <<<cdiv(128*64*85,  TPB), TPB, 0, stream>>>(xmiu, ae_w1, ae_b1, h1);
  k_h2       <<<cdiv(128*32*42,  TPB), TPB, 0, stream>>>(h1, ae_w2, ae_b2, h2);
  k_up       <<<cdiv(128*32*84,  TPB), TPB, 0, stream>>>(h2, u1, 128*32, 42);
  k_h3       <<<cdiv(128*64*86,  TPB), TPB, 0, stream>>>(u1, ae_w3, ae_b3, h3);
  k_up       <<<cdiv(128*64*172, TPB), TPB, 0, stream>>>(h3, u2, 128*64, 86);
  k_h4       <<<cdiv(128*32*174, TPB), TPB, 0, stream>>>(u2, ae_w4, ae_b4, h4);
  k_inp      <<<cdiv(128*32*171, TPB), TPB, 0, stream>>>(h4, xmiu, inp);
  k_until    <<<cdiv(128*160*170,TPB), TPB, 0, stream>>>(inp, x1);
  k_logic1p  <<<dim3(85, 4, 2), TPB, 0, stream>>>(inp, wn, p1);
  k_fin1     <<<cdiv(128*40*170, TPB), TPB, 0, stream>>>(p1, x1);
  k_logic2p  <<<dim3(85, 4, 2), TPB, 0, stream>>>(x1, wn, p2);
  k_fin2     <<<cdiv(128*12*170, TPB), TPB, 0, stream>>>(p2, x2);
  k_fc1      <<<384, TPB, 0, stream>>>(x2, fc1_w, fc1_b, fc1h);
  k_fc2      <<<384, TPB, 0, stream>>>(fc1h, fc2_w, fc2_b, fc2h);
  k_fc3      <<<cdiv(1536*10, TPB), TPB, 0, stream>>>(fc2h, fc3_w, fc3_b, out);
}

// Round 4
// 442.015 us; speedup vs baseline: 1.9803x; 1.2877x over previous
//
#include <hip/hip_runtime.h>

#define TPB 256
static inline int cdiv(int a, int b){ return (a + b - 1) / b; }

#define EPSL 1e-6f
#define ACT_TANH 0
#define ACT_RELU 1
#define ACT_SIG  2

__device__ __forceinline__ float sigf(float x){ return 1.0f / (1.0f + __expf(-x)); }
__device__ __forceinline__ float clip01(float x){ return fminf(fmaxf(x, 0.f), 1.f); }

// ---------------- workspace layout (float offsets) ----------------
#define OFF_Y1   0
#define OFF_XF   1409024
#define OFF_XMIU 2111488
#define OFF_H1   2811904
#define OFF_H2   3508224
#define OFF_H3   3680256
#define OFF_INP  4384768
#define OFF_X1   7886848
#define OFF_TAIL 12238848
#define OFF_P1   0
#define OFF_P2   0
#define OFF_STATS OFF_TAIL
#define OFF_BNP  (OFF_TAIL + 64)
#define OFF_WN   (OFF_TAIL + 64 + 512)

// ---------------- softmax prep for logic weights ----------------
__global__ void k_softmax(const float* __restrict__ a2, const float* __restrict__ o2,
                          const float* __restrict__ aw, const float* __restrict__ ow,
                          float* __restrict__ wn){
  int blk = blockIdx.x;
  const float* src; float* dst; int n;
  if (blk < 20)      { src = a2 + blk*320;      dst = wn + blk*320;              n = 320; }
  else if (blk < 40) { src = o2 + (blk-20)*320; dst = wn + 6400 + (blk-20)*320;  n = 320; }
  else if (blk < 46) { src = aw + (blk-40)*400; dst = wn + 12800 + (blk-40)*400; n = 400; }
  else               { src = ow + (blk-46)*400; dst = wn + 15200 + (blk-46)*400; n = 400; }
  __shared__ float sh[TPB];
  float m = -1e30f;
  for (int i = threadIdx.x; i < n; i += TPB) m = fmaxf(m, src[i]);
  sh[threadIdx.x] = m; __syncthreads();
  for (int off = TPB/2; off > 0; off >>= 1){
    if (threadIdx.x < off) sh[threadIdx.x] = fmaxf(sh[threadIdx.x], sh[threadIdx.x+off]);
    __syncthreads();
  }
  m = sh[0]; __syncthreads();
  float s = 0.f;
  for (int i = threadIdx.x; i < n; i += TPB) s += expf(src[i] - m);
  sh[threadIdx.x] = s; __syncthreads();
  for (int off = TPB/2; off > 0; off >>= 1){
    if (threadIdx.x < off) sh[threadIdx.x] += sh[threadIdx.x+off];
    __syncthreads();
  }
  float inv = 1.0f / sh[0];
  __syncthreads();
  for (int i = threadIdx.x; i < n; i += TPB) dst[i] = expf(src[i] - m) * inv;
}

// ---------------- stage 1: wave conv (128,1,719)->(128,16,688) ----------------
__global__ void k_conv_wave(const float* __restrict__ x, const float* __restrict__ ww,
                            float* __restrict__ y){
  int idx = blockIdx.x*blockDim.x + threadIdx.x;
  if (idx >= 128*16*688) return;
  int l = idx % 688; int t = idx / 688; int o = t & 15; int b = t >> 4;
  const float* xr = x + b*719 + l;
  const float* wr = ww + o*32;
  float s = 0.f;
  #pragma unroll
  for (int k = 0; k < 32; k++) s = fmaf(xr[k], wr[k], s);
  y[idx] = s;
}

// ---------------- BN stats ----------------
__global__ void k_bn_part(const float* __restrict__ y, double* __restrict__ bnp){
  int c = blockIdx.x & 15, ch = blockIdx.x >> 4;
  double s = 0.0, s2 = 0.0;
  for (int i = threadIdx.x; i < 16*688; i += TPB){
    int b = ch*16 + i/688, l = i % 688;
    float v = y[(b*16 + c)*688 + l];
    s += (double)v; s2 += (double)v * (double)v;
  }
  __shared__ double sh[TPB], sh2[TPB];
  sh[threadIdx.x] = s; sh2[threadIdx.x] = s2; __syncthreads();
  for (int off = TPB/2; off > 0; off >>= 1){
    if (threadIdx.x < off){ sh[threadIdx.x] += sh[threadIdx.x+off]; sh2[threadIdx.x] += sh2[threadIdx.x+off]; }
    __syncthreads();
  }
  if (threadIdx.x == 0){ bnp[blockIdx.x] = sh[0]; bnp[128 + blockIdx.x] = sh2[0]; }
}

__global__ void k_bn_fin(const double* __restrict__ bnp, float* __restrict__ stats){
  int c = threadIdx.x;
  if (c >= 16) return;
  double s = 0.0, s2 = 0.0;
  for (int j = 0; j < 8; j++){ s += bnp[j*16 + c]; s2 += bnp[128 + j*16 + c]; }
  double n = 128.0*688.0;
  double m = s / n;
  double var = s2 / n - m*m;
  stats[c]      = (float)m;
  stats[16 + c] = (float)(1.0 / sqrt(var + 1e-5));
}

// ---------------- xf = maxpool3s2(relu(bn(y))) -> (128,16,343) ----------------
__global__ void k_xf(const float* __restrict__ y, const float* __restrict__ stats,
                     const float* __restrict__ g, const float* __restrict__ bb,
                     float* __restrict__ xf){
  int idx = blockIdx.x*blockDim.x + threadIdx.x;
  if (idx >= 128*16*343) return;
  int l = idx % 343; int t = idx / 343; int c = t & 15; int b = t >> 4;
  float mean = stats[c], rstd = stats[16 + c];
  float gc = g[c], bc = bb[c];
  const float* yr = y + (b*16 + c)*688 + 2*l;
  float m = -1e30f;
  #pragma unroll
  for (int j = 0; j < 3; j++){
    float v = fmaf(gc*(yr[j] - mean), rstd, bc);
    v = fmaxf(v, 0.f);
    m = fmaxf(m, v);
  }
  xf[idx] = m;
}

// ---------------- x_miu ----------------
__global__ void k_xmiu(const float* __restrict__ xf,
                       const float* __restrict__ ap, const float* __restrict__ bp,
                       const float* __restrict__ an, const float* __restrict__ bn,
                       float* __restrict__ out){
  int idx = blockIdx.x*blockDim.x + threadIdx.x;
  if (idx >= 128*32*171) return;
  int l = idx % 171; int t = idx / 171; int c = t & 31; int b = t >> 5;
  int cc = c & 15;
  float sign = (c < 16) ? 1.f : -1.f;
  float a  = (c < 16) ? ap[cc] : an[cc];
  float bo = (c < 16) ? bp[cc] : bn[cc];
  const float* xr = xf + (b*16 + cc)*343 + 2*l;
  float m = -1e30f;
  #pragma unroll
  for (int j = 0; j < 3; j++){
    float v = sigf(sign * a * (xr[j] - bo));
    m = fmaxf(m, v);
  }
  out[idx] = m;
}

// ---------------- generic LDS-tiled 1D conv (kernel=3), act fused ----------------
// block = (batch, p-segment of LSEG=4*PL). Thread = (o-quad, p-quad): 4x4 register tile.
template<int CIN, int LIN, int COUT, int LOUT, int PAD, int ACT, int PL>
__global__ void __launch_bounds__(256) k_conv(const float* __restrict__ in,
                                              const float* __restrict__ w,
                                              const float* __restrict__ bias,
                                              float* __restrict__ outp){
  constexpr int LSEG = 4*PL;
  constexpr int WL = ((LSEG + 2) + 3) & ~3;       // local staged width (incl. 2 extra taps)
  constexpr int K3 = CIN*3;
  __shared__ float smem[CIN*WL + 8 + K3*COUT];
  float* sin = smem;
  float* wT  = smem + CIN*WL + 8;
  const int b = blockIdx.x;
  const int tid = threadIdx.x;
  const int base = blockIdx.y*LSEG - PAD;         // global input index of local col 0

  const float* gin = in + b*CIN*LIN;
  for (int e = tid; e < CIN*WL; e += 256){
    int i = e / WL, c = e - i*WL;
    int q = base + c;
    sin[e] = (q >= 0 && q < LIN) ? gin[i*LIN + q] : 0.f;
  }
  if (tid < 8) sin[CIN*WL + tid] = 0.f;
  for (int e = tid; e < K3*COUT; e += 256){
    int o = e & (COUT-1), m = e / COUT;
    wT[m*COUT + o] = w[o*K3 + m];
  }
  __syncthreads();

  const int to = tid / PL, tp = tid - (tid/PL)*PL;
  const int o0 = to*4;
  const int pl0 = 4*tp;                            // local p
  float acc[4][4] = {{0,0,0,0},{0,0,0,0},{0,0,0,0},{0,0,0,0}};

  for (int i = 0; i < CIN; i++){
    const float* srow = sin + i*WL + pl0;
    float xv[6];
    *(float4*)&xv[0] = *(const float4*)srow;
    *(float2*)&xv[4] = *(const float2*)(srow + 4);
    const float* wrow = wT + (i*3)*COUT + o0;
    float wv[3][4];
    #pragma unroll
    for (int k = 0; k < 3; k++)
      *(float4*)&wv[k][0] = *(const float4*)(wrow + k*COUT);
    #pragma unroll
    for (int j = 0; j < 4; j++)
      #pragma unroll
      for (int k = 0; k < 3; k++)
        #pragma unroll
        for (int oo = 0; oo < 4; oo++)
          acc[j][oo] = fmaf(xv[j+k], wv[k][oo], acc[j][oo]);
  }

  const int pg0 = blockIdx.y*LSEG + pl0;           // global p
  float bv[4];
  #pragma unroll
  for (int oo = 0; oo < 4; oo++) bv[oo] = bias[o0 + oo];
  #pragma unroll
  for (int oo = 0; oo < 4; oo++){
    float* orow = outp + (b*COUT + o0 + oo)*LOUT;
    #pragma unroll
    for (int j = 0; j < 4; j++){
      int p = pg0 + j;
      if (p < LOUT){
        float s = acc[j][oo] + bv[oo];
        float r;
        if (ACT == ACT_TANH)      r = tanhf(s);
        else if (ACT == ACT_RELU) r = fmaxf(s, 0.f);
        else                      r = sigf(s);
        orow[p] = r;
      }
    }
  }
}

// ---------------- maxpool3 stride2 ----------------
__global__ void k_pool(const float* __restrict__ in, float* __restrict__ out,
                       int rows, int Lc, int Lp){
  int idx = blockIdx.x*blockDim.x + threadIdx.x;
  if (idx >= rows*Lp) return;
  int l = idx % Lp; int r = idx / Lp;
  const float* xr = in + r*Lc + 2*l;
  out[idx] = fmaxf(fmaxf(xr[0], xr[1]), xr[2]);
}

// ---------------- upsample2 (jax linear, half-pixel) ----------------
__global__ void k_up(const float* __restrict__ in, float* __restrict__ out, int rows, int Lin){
  int Lo = 2*Lin;
  int idx = blockIdx.x*blockDim.x + threadIdx.x;
  if (idx >= rows*Lo) return;
  int i = idx % Lo; int r = idx / Lo;
  const float* xr = in + r*Lin;
  float v;
  if (i == 0)            v = xr[0];
  else if (i == Lo - 1)  v = xr[Lin-1];
  else {
    int k = i >> 1;
    if (i & 1) v = 0.75f*xr[k]   + 0.25f*xr[k+1];
    else       v = 0.25f*xr[k-1] + 0.75f*xr[k];
  }
  out[idx] = v;
}

// ---------------- inp: fused maxpool4(h4) + segment masking -> (128,160,171) ----------------
__global__ void k_inp(const float* __restrict__ h4, const float* __restrict__ xmiu,
                      float* __restrict__ inp){
  int idx = blockIdx.x*blockDim.x + threadIdx.x;
  if (idx >= 128*32*171) return;
  int l = idx % 171; int t = idx / 171; int c = t & 31; int b = t >> 5;
  const float* hr = h4 + t*174 + l;
  float wv = fmaxf(fmaxf(hr[0], hr[1]), fmaxf(hr[2], hr[3]));
  float xm = xmiu[idx];
  float prod = wv * xm;
  const float lo[5] = {0.0f, 0.2f, 0.4f, 0.6f, 0.8f};
  const float hi[5] = {0.2f, 0.4f, 0.6f, 0.8f, 2.0f};
  float* op = inp + ((b*160) + c)*171 + l;
  #pragma unroll
  for (int s = 0; s < 5; s++){
    bool m = (wv >= lo[s]) && (wv < hi[s]);
    op[s*32*171] = m ? prod : 0.f;
  }
}

// ---------------- until -> x1 channels [40,200) ----------------
__global__ void k_until(const float* __restrict__ inp, float* __restrict__ x1){
  int idx = blockIdx.x*blockDim.x + threadIdx.x;
  if (idx >= 128*160*170) return;
  int l = idx % 170; int t = idx / 170; int c = t % 160; int b = t / 160;
  const float* xr = inp + (b*160 + c)*171;
  float runmin = xr[l];
  float outv = 0.f;
  #pragma unroll 5
  for (int d = 1; d <= 25; d++){
    float xs = (l + d < 171) ? xr[l + d] : 0.f;
    outv = fmaxf(outv, fminf(runmin, xs));
    runmin = fminf(runmin, xs);
  }
  x1[((b*200) + 40 + c)*170 + l] = outv;
}

// ---------------- logic stage 1 partials: grid (85, ch=4, v=2) ----------------
__global__ void __launch_bounds__(TPB) k_logic1p(const float* __restrict__ inp, const float* __restrict__ wn,
                                                 float* __restrict__ p1){
  int bl = blockIdx.x*TPB + threadIdx.x;
  int l = bl % 170; int b = bl / 170;
  int ch = blockIdx.y, v = blockIdx.z;
  const float* W = wn + (v ? 6400 : 0);
  float acc[20];
  #pragma unroll
  for (int o = 0; o < 20; o++) acc[o] = 0.f;
  int c0 = ch*40;
  const float* ir = inp + (b*160 + c0)*171 + l;
  for (int c = 0; c < 40; c++){
    float u0 = clip01(ir[0]);
    float u1 = clip01(ir[1]);
    float g0, g1;
    if (v){ g0 = __logf(1.f - u0 + EPSL); g1 = __logf(1.f - u1 + EPSL); }
    else  { g0 = __logf(u0 + EPSL);       g1 = __logf(u1 + EPSL); }
    const float* wc = W + 2*(c0 + c);
    #pragma unroll
    for (int o = 0; o < 20; o++)
      acc[o] = fmaf(wc[o*320], g0, fmaf(wc[o*320 + 1], g1, acc[o]));
    ir += 171;
  }
  float* pp = p1 + ((ch*128 + b)*40 + v*20)*170 + l;
  #pragma unroll
  for (int o = 0; o < 20; o++) pp[o*170] = acc[o];
}

__global__ void k_fin1(const float* __restrict__ p1, float* __restrict__ x1){
  int idx = blockIdx.x*blockDim.x + threadIdx.x;
  if (idx >= 128*40*170) return;
  int l = idx % 170; int o = (idx/170) % 40; int b = idx / (170*40);
  float s = 0.f;
  #pragma unroll
  for (int ch = 0; ch < 4; ch++) s += p1[((ch*128 + b)*40 + o)*170 + l];
  float e = __expf(s);
  float r = (o < 20) ? e : fmaxf(0.f, 1.f - e);
  x1[(b*200 + o)*170 + l] = r;
}

// ---------------- logic stage 2 partials ----------------
__global__ void __launch_bounds__(TPB) k_logic2p(const float* __restrict__ x1, const float* __restrict__ wn,
                                                 float* __restrict__ p2){
  int bl = blockIdx.x*TPB + threadIdx.x;
  int l = bl % 170; int b = bl / 170;
  int ch = blockIdx.y, v = blockIdx.z;
  const float* W = wn + 12800 + (v ? 2400 : 0);
  float acc[6] = {0.f,0.f,0.f,0.f,0.f,0.f};
  int c0 = ch*50;
  const float* xr = x1 + (b*200 + c0)*170 + l;
  for (int c = 0; c < 50; c++){
    float g0 = 0.f;
    if (l > 0){
      float u0 = clip01(xr[-1]);
      g0 = v ? __logf(1.f - u0 + EPSL) : __logf(u0 + EPSL);
    }
    float u1 = clip01(xr[0]);
    float g1 = v ? __logf(1.f - u1 + EPSL) : __logf(u1 + EPSL);
    const float* wc = W + 2*(c0 + c);
    #pragma unroll
    for (int o = 0; o < 6; o++)
      acc[o] = fmaf(wc[o*400], g0, fmaf(wc[o*400 + 1], g1, acc[o]));
    xr += 170;
  }
  float* pp = p2 + ((ch*128 + b)*12 + v*6)*170 + l;
  #pragma unroll
  for (int o = 0; o < 6; o++) pp[o*170] = acc[o];
}

__global__ void k_fin2(const float* __restrict__ p2, float* __restrict__ x2){
  int idx = blockIdx.x*blockDim.x + threadIdx.x;
  if (idx >= 128*12*170) return;
  int l = idx % 170; int o = (idx/170) % 12; int b = idx / (170*12);
  float s = 0.f;
  #pragma unroll
  for (int ch = 0; ch < 4; ch++) s += p2[((ch*128 + b)*12 + o)*170 + l];
  float e = __expf(s);
  float r = (o < 6) ? e : fmaxf(0.f, 1.f - e);
  x2[(b*12 + o)*170 + l] = r;
}

// ---------------- fc1 ----------------
__global__ void __launch_bounds__(TPB) k_fc1(const float* __restrict__ x2, const float* __restrict__ w,
                                             const float* __restrict__ bias, float* __restrict__ out){
  __shared__ float rows[4][172];
  int bc0 = blockIdx.x * 4;
  for (int i = threadIdx.x; i < 4*172; i += TPB){
    int r = i / 172, l = i % 172;
    rows[r][l] = (l < 170) ? x2[(bc0 + r)*170 + l] : 0.f;
  }
  __syncthreads();
  for (int j = 0; j < 4; j++){
    int o = threadIdx.x + j*TPB;
    float bv = bias[o];
    float acc[4];
    #pragma unroll
    for (int r = 0; r < 4; r++) acc[r] = bv;
    const float* wr = w + o*170;
    for (int l = 0; l < 168; l += 4){
      float w0 = wr[l], w1 = wr[l+1], w2 = wr[l+2], w3 = wr[l+3];
      #pragma unroll
      for (int r = 0; r < 4; r++){
        const float4 rv = *(const float4*)(&rows[r][l]);
        acc[r] = fmaf(rv.x, w0, fmaf(rv.y, w1, fmaf(rv.z, w2, fmaf(rv.w, w3, acc[r]))));
      }
    }
    #pragma unroll
    for (int l = 168; l < 170; l++){
      float wv = wr[l];
      #pragma unroll
      for (int r = 0; r < 4; r++) acc[r] = fmaf(rows[r][l], wv, acc[r]);
    }
    #pragma unroll
    for (int r = 0; r < 4; r++) out[(bc0 + r)*1024 + o] = fmaxf(acc[r], 0.f);
  }
}

// ---------------- fc2 ----------------
__global__ void __launch_bounds__(TPB) k_fc2(const float* __restrict__ h, const float* __restrict__ w,
                                             const float* __restrict__ bias, float* __restrict__ out){
  __shared__ float rows[4][1024];
  int bc0 = blockIdx.x * 4;
  for (int i = threadIdx.x; i < 4*1024; i += TPB){
    int r = i >> 10, l = i & 1023;
    rows[r][l] = h[(bc0 + r)*1024 + l];
  }
  __syncthreads();
  int p = threadIdx.x;
  float bv = bias[p];
  float acc[4];
  #pragma unroll
  for (int r = 0; r < 4; r++) acc[r] = bv;
  const float* wr = w + p*1024;
  for (int o = 0; o < 1024; o += 4){
    const float4 wv = *(const float4*)(wr + o);
    #pragma unroll
    for (int r = 0; r < 4; r++){
      const float4 rv = *(const float4*)(&rows[r][o]);
      acc[r] = fmaf(rv.x, wv.x, fmaf(rv.y, wv.y, fmaf(rv.z, wv.z, fmaf(rv.w, wv.w, acc[r]))));
    }
  }
  #pragma unroll
  for (int r = 0; r < 4; r++) out[(bc0 + r)*256 + p] = fmaxf(acc[r], 0.f);
}

// ---------------- fc3 ----------------
__global__ void k_fc3(const float* __restrict__ h, const float* __restrict__ w,
                      const float* __restrict__ bias, float* __restrict__ out){
  int idx = blockIdx.x*blockDim.x + threadIdx.x;
  if (idx >= 1536*10) return;
  int q = idx % 10; int bc = idx / 10;
  const float* hr = h + bc*256;
  const float* wr = w + q*256;
  float s = bias[q];
  for (int p = 0; p < 256; p++) s = fmaf(hr[p], wr[p], s);
  out[idx] = s;
}

extern "C" void kernel_launch(void* const* d_in, const int* in_sizes, int n_in,
                              void* d_out, int out_size, void* d_ws, size_t ws_size,
                              hipStream_t stream) {
  const float* x      = (const float*)d_in[0];
  const float* wave_w = (const float*)d_in[1];
  const float* bn_g   = (const float*)d_in[2];
  const float* bn_b   = (const float*)d_in[3];
  const float* miu_ap = (const float*)d_in[4];
  const float* miu_bp = (const float*)d_in[5];
  const float* miu_an = (const float*)d_in[6];
  const float* miu_bn = (const float*)d_in[7];
  const float* ae_w1  = (const float*)d_in[8];
  const float* ae_b1  = (const float*)d_in[9];
  const float* ae_w2  = (const float*)d_in[10];
  const float* ae_b2  = (const float*)d_in[11];
  const float* ae_w3  = (const float*)d_in[12];
  const float* ae_b3  = (const float*)d_in[13];
  const float* ae_w4  = (const float*)d_in[14];
  const float* ae_b4  = (const float*)d_in[15];
  const float* and2_w = (const float*)d_in[16];
  const float* or2_w  = (const float*)d_in[17];
  const float* and_w  = (const float*)d_in[18];
  const float* or_w   = (const float*)d_in[19];
  const float* fc1_w  = (const float*)d_in[20];
  const float* fc1_b  = (const float*)d_in[21];
  const float* fc2_w  = (const float*)d_in[22];
  const float* fc2_b  = (const float*)d_in[23];
  const float* fc3_w  = (const float*)d_in[24];
  const float* fc3_b  = (const float*)d_in[25];
  float* out = (float*)d_out;
  float* ws  = (float*)d_ws;

  float* y1    = ws + OFF_Y1;
  float* xf    = ws + OFF_XF;
  float* xmiu  = ws + OFF_XMIU;
  float* c1    = ws + OFF_Y1;            // conv1 temp (128*64*171=1400832), y1 dead after xf
  float* h1    = ws + OFF_H1;
  float* c2    = ws + OFF_XF;            // conv2 temp (348160), xf dead after xmiu
  float* h2    = ws + OFF_H2;
  float* u1    = ws + OFF_H1;            // reuse (h1 dead after h2 conv)
  float* h3    = ws + OFF_H3;
  float* u2    = ws + OFF_Y1;            // reuse (c1 dead after pool)
  float* h4    = ws + OFF_H1;            // reuse (u1+h2 dead)
  float* inp   = ws + OFF_INP;
  float* x1    = ws + OFF_X1;
  float* p1    = ws + OFF_P1;
  float* p2    = ws + OFF_P2;
  float* x2    = ws + OFF_INP;
  float* fc1h  = ws + OFF_X1;
  float* fc2h  = ws + OFF_INP + 262144;
  float* stats = ws + OFF_STATS;
  double* bnp  = (double*)(ws + OFF_BNP);
  float* wn    = ws + OFF_WN;

  k_softmax  <<<52, TPB, 0, stream>>>(and2_w, or2_w, and_w, or_w, wn);
  k_conv_wave<<<cdiv(128*16*688, TPB), TPB, 0, stream>>>(x, wave_w, y1);
  k_bn_part  <<<128, TPB, 0, stream>>>(y1, bnp);
  k_bn_fin   <<<1, 64, 0, stream>>>(bnp, stats);
  k_xf       <<<cdiv(128*16*343, TPB), TPB, 0, stream>>>(y1, stats, bn_g, bn_b, xf);
  k_xmiu     <<<cdiv(128*32*171, TPB), TPB, 0, stream>>>(xf, miu_ap, miu_bp, miu_an, miu_bn, xmiu);

  // AE stack: LDS-tiled convs
  k_conv<32,171,64,171,1,ACT_TANH,16><<<dim3(128,3), 256, 0, stream>>>(xmiu, ae_w1, ae_b1, c1);
  k_pool     <<<cdiv(128*64*85, TPB), TPB, 0, stream>>>(c1, h1, 128*64, 171, 85);
  k_conv<64,85,32,85,1,ACT_RELU,32><<<dim3(128,1), 256, 0, stream>>>(h1, ae_w2, ae_b2, c2);
  k_pool     <<<cdiv(128*32*42, TPB), TPB, 0, stream>>>(c2, h2, 128*32, 85, 42);
  k_up       <<<cdiv(128*32*84,  TPB), TPB, 0, stream>>>(h2, u1, 128*32, 42);
  k_conv<32,84,64,86,2,ACT_TANH,16><<<dim3(128,2), 256, 0, stream>>>(u1, ae_w3, ae_b3, h3);
  k_up       <<<cdiv(128*64*172, TPB), TPB, 0, stream>>>(h3, u2, 128*64, 86);
  k_conv<64,172,32,174,2,ACT_SIG,32><<<dim3(128,2), 256, 0, stream>>>(u2, ae_w4, ae_b4, h4);

  k_inp      <<<cdiv(128*32*171, TPB), TPB, 0, stream>>>(h4, xmiu, inp);
  k_until    <<<cdiv(128*160*170,TPB), TPB, 0, stream>>>(inp, x1);
  k_logic1p  <<<dim3(85, 4, 2), TPB, 0, stream>>>(inp, wn, p1);
  k_fin1     <<<cdiv(128*40*170, TPB), TPB, 0, stream>>>(p1, x1);
  k_logic2p  <<<dim3(85, 4, 2), TPB, 0, stream>>>(x1, wn, p2);
  k_fin2     <<<cdiv(128*12*170, TPB), TPB, 0, stream>>>(p2, x2);
  k_fc1      <<<384, TPB, 0, stream>>>(x2, fc1_w, fc1_b, fc1h);
  k_fc2      <<<384, TPB, 0, stream>>>(fc1h, fc2_w, fc2_b, fc2h);
  k_fc3      <<<cdiv(1536*10, TPB), TPB, 0, stream>>>(fc2h, fc3_w, fc3_b, out);
}

// Round 5
// 418.778 us; speedup vs baseline: 2.0901x; 1.0555x over previous
//
#include <hip/hip_runtime.h>

#define TPB 256
static inline int cdiv(int a, int b){ return (a + b - 1) / b; }

#define EPSL 1e-6f
#define ACT_TANH 0
#define ACT_RELU 1
#define ACT_SIG  2

__device__ __forceinline__ float sigf(float x){ return 1.0f / (1.0f + __expf(-x)); }
__device__ __forceinline__ float clip01(float x){ return fminf(fmaxf(x, 0.f), 1.f); }

// ---------------- workspace layout (float offsets) ----------------
#define OFF_Y1   0
#define OFF_XF   1409024
#define OFF_XMIU 2111488
#define OFF_H1   2811904
#define OFF_H2   3508224
#define OFF_H3   3680256
#define OFF_INP  4384768
#define OFF_X1   7886848
#define OFF_TAIL 12238848
#define OFF_P1   0
#define OFF_P2   0
#define OFF_FC1H OFF_X1                   // 1536*1024 = 1572864
#define OFF_FC2P (OFF_X1 + 1572864)       // 4*1536*256 = 1572864 -> ends 11032576 < OFF_TAIL
#define OFF_STATS OFF_TAIL
#define OFF_BNP  (OFF_TAIL + 64)
#define OFF_WN   (OFF_TAIL + 64 + 512)

// ---------------- softmax prep for logic weights ----------------
__global__ void k_softmax(const float* __restrict__ a2, const float* __restrict__ o2,
                          const float* __restrict__ aw, const float* __restrict__ ow,
                          float* __restrict__ wn){
  int blk = blockIdx.x;
  const float* src; float* dst; int n;
  if (blk < 20)      { src = a2 + blk*320;      dst = wn + blk*320;              n = 320; }
  else if (blk < 40) { src = o2 + (blk-20)*320; dst = wn + 6400 + (blk-20)*320;  n = 320; }
  else if (blk < 46) { src = aw + (blk-40)*400; dst = wn + 12800 + (blk-40)*400; n = 400; }
  else               { src = ow + (blk-46)*400; dst = wn + 15200 + (blk-46)*400; n = 400; }
  __shared__ float sh[TPB];
  float m = -1e30f;
  for (int i = threadIdx.x; i < n; i += TPB) m = fmaxf(m, src[i]);
  sh[threadIdx.x] = m; __syncthreads();
  for (int off = TPB/2; off > 0; off >>= 1){
    if (threadIdx.x < off) sh[threadIdx.x] = fmaxf(sh[threadIdx.x], sh[threadIdx.x+off]);
    __syncthreads();
  }
  m = sh[0]; __syncthreads();
  float s = 0.f;
  for (int i = threadIdx.x; i < n; i += TPB) s += expf(src[i] - m);
  sh[threadIdx.x] = s; __syncthreads();
  for (int off = TPB/2; off > 0; off >>= 1){
    if (threadIdx.x < off) sh[threadIdx.x] += sh[threadIdx.x+off];
    __syncthreads();
  }
  float inv = 1.0f / sh[0];
  __syncthreads();
  for (int i = threadIdx.x; i < n; i += TPB) dst[i] = expf(src[i] - m) * inv;
}

// ---------------- stage 1: wave conv (128,1,719)->(128,16,688) ----------------
__global__ void k_conv_wave(const float* __restrict__ x, const float* __restrict__ ww,
                            float* __restrict__ y){
  int idx = blockIdx.x*blockDim.x + threadIdx.x;
  if (idx >= 128*16*688) return;
  int l = idx % 688; int t = idx / 688; int o = t & 15; int b = t >> 4;
  const float* xr = x + b*719 + l;
  const float* wr = ww + o*32;
  float s = 0.f;
  #pragma unroll
  for (int k = 0; k < 32; k++) s = fmaf(xr[k], wr[k], s);
  y[idx] = s;
}

// ---------------- BN stats ----------------
__global__ void k_bn_part(const float* __restrict__ y, double* __restrict__ bnp){
  int c = blockIdx.x & 15, ch = blockIdx.x >> 4;
  double s = 0.0, s2 = 0.0;
  for (int i = threadIdx.x; i < 16*688; i += TPB){
    int b = ch*16 + i/688, l = i % 688;
    float v = y[(b*16 + c)*688 + l];
    s += (double)v; s2 += (double)v * (double)v;
  }
  __shared__ double sh[TPB], sh2[TPB];
  sh[threadIdx.x] = s; sh2[threadIdx.x] = s2; __syncthreads();
  for (int off = TPB/2; off > 0; off >>= 1){
    if (threadIdx.x < off){ sh[threadIdx.x] += sh[threadIdx.x+off]; sh2[threadIdx.x] += sh2[threadIdx.x+off]; }
    __syncthreads();
  }
  if (threadIdx.x == 0){ bnp[blockIdx.x] = sh[0]; bnp[128 + blockIdx.x] = sh2[0]; }
}

__global__ void k_bn_fin(const double* __restrict__ bnp, float* __restrict__ stats){
  int c = threadIdx.x;
  if (c >= 16) return;
  double s = 0.0, s2 = 0.0;
  for (int j = 0; j < 8; j++){ s += bnp[j*16 + c]; s2 += bnp[128 + j*16 + c]; }
  double n = 128.0*688.0;
  double m = s / n;
  double var = s2 / n - m*m;
  stats[c]      = (float)m;
  stats[16 + c] = (float)(1.0 / sqrt(var + 1e-5));
}

// ---------------- xf = maxpool3s2(relu(bn(y))) -> (128,16,343) ----------------
__global__ void k_xf(const float* __restrict__ y, const float* __restrict__ stats,
                     const float* __restrict__ g, const float* __restrict__ bb,
                     float* __restrict__ xf){
  int idx = blockIdx.x*blockDim.x + threadIdx.x;
  if (idx >= 128*16*343) return;
  int l = idx % 343; int t = idx / 343; int c = t & 15; int b = t >> 4;
  float mean = stats[c], rstd = stats[16 + c];
  float gc = g[c], bc = bb[c];
  const float* yr = y + (b*16 + c)*688 + 2*l;
  float m = -1e30f;
  #pragma unroll
  for (int j = 0; j < 3; j++){
    float v = fmaf(gc*(yr[j] - mean), rstd, bc);
    v = fmaxf(v, 0.f);
    m = fmaxf(m, v);
  }
  xf[idx] = m;
}

// ---------------- x_miu ----------------
__global__ void k_xmiu(const float* __restrict__ xf,
                       const float* __restrict__ ap, const float* __restrict__ bp,
                       const float* __restrict__ an, const float* __restrict__ bn,
                       float* __restrict__ out){
  int idx = blockIdx.x*blockDim.x + threadIdx.x;
  if (idx >= 128*32*171) return;
  int l = idx % 171; int t = idx / 171; int c = t & 31; int b = t >> 5;
  int cc = c & 15;
  float sign = (c < 16) ? 1.f : -1.f;
  float a  = (c < 16) ? ap[cc] : an[cc];
  float bo = (c < 16) ? bp[cc] : bn[cc];
  const float* xr = xf + (b*16 + cc)*343 + 2*l;
  float m = -1e30f;
  #pragma unroll
  for (int j = 0; j < 3; j++){
    float v = sigf(sign * a * (xr[j] - bo));
    m = fmaxf(m, v);
  }
  out[idx] = m;
}

// ---------------- generic LDS-tiled 1D conv (kernel=3), act fused ----------------
template<int CIN, int LIN, int COUT, int LOUT, int PAD, int ACT, int PL>
__global__ void __launch_bounds__(256) k_conv(const float* __restrict__ in,
                                              const float* __restrict__ w,
                                              const float* __restrict__ bias,
                                              float* __restrict__ outp){
  constexpr int LSEG = 4*PL;
  constexpr int WL = ((LSEG + 2) + 3) & ~3;
  constexpr int K3 = CIN*3;
  __shared__ float smem[CIN*WL + 8 + K3*COUT];
  float* sin = smem;
  float* wT  = smem + CIN*WL + 8;
  const int b = blockIdx.x;
  const int tid = threadIdx.x;
  const int base = blockIdx.y*LSEG - PAD;

  const float* gin = in + b*CIN*LIN;
  for (int e = tid; e < CIN*WL; e += 256){
    int i = e / WL, c = e - i*WL;
    int q = base + c;
    sin[e] = (q >= 0 && q < LIN) ? gin[i*LIN + q] : 0.f;
  }
  if (tid < 8) sin[CIN*WL + tid] = 0.f;
  for (int e = tid; e < K3*COUT; e += 256){
    int o = e & (COUT-1), m = e / COUT;
    wT[m*COUT + o] = w[o*K3 + m];
  }
  __syncthreads();

  const int to = tid / PL, tp = tid - (tid/PL)*PL;
  const int o0 = to*4;
  const int pl0 = 4*tp;
  float acc[4][4] = {{0,0,0,0},{0,0,0,0},{0,0,0,0},{0,0,0,0}};

  for (int i = 0; i < CIN; i++){
    const float* srow = sin + i*WL + pl0;
    float xv[6];
    *(float4*)&xv[0] = *(const float4*)srow;
    *(float2*)&xv[4] = *(const float2*)(srow + 4);
    const float* wrow = wT + (i*3)*COUT + o0;
    float wv[3][4];
    #pragma unroll
    for (int k = 0; k < 3; k++)
      *(float4*)&wv[k][0] = *(const float4*)(wrow + k*COUT);
    #pragma unroll
    for (int j = 0; j < 4; j++)
      #pragma unroll
      for (int k = 0; k < 3; k++)
        #pragma unroll
        for (int oo = 0; oo < 4; oo++)
          acc[j][oo] = fmaf(xv[j+k], wv[k][oo], acc[j][oo]);
  }

  const int pg0 = blockIdx.y*LSEG + pl0;
  float bv[4];
  #pragma unroll
  for (int oo = 0; oo < 4; oo++) bv[oo] = bias[o0 + oo];
  #pragma unroll
  for (int oo = 0; oo < 4; oo++){
    float* orow = outp + (b*COUT + o0 + oo)*LOUT;
    #pragma unroll
    for (int j = 0; j < 4; j++){
      int p = pg0 + j;
      if (p < LOUT){
        float s = acc[j][oo] + bv[oo];
        float r;
        if (ACT == ACT_TANH)      r = tanhf(s);
        else if (ACT == ACT_RELU) r = fmaxf(s, 0.f);
        else                      r = sigf(s);
        orow[p] = r;
      }
    }
  }
}

// ---------------- maxpool3 stride2 ----------------
__global__ void k_pool(const float* __restrict__ in, float* __restrict__ out,
                       int rows, int Lc, int Lp){
  int idx = blockIdx.x*blockDim.x + threadIdx.x;
  if (idx >= rows*Lp) return;
  int l = idx % Lp; int r = idx / Lp;
  const float* xr = in + r*Lc + 2*l;
  out[idx] = fmaxf(fmaxf(xr[0], xr[1]), xr[2]);
}

// ---------------- upsample2 (jax linear, half-pixel) ----------------
__global__ void k_up(const float* __restrict__ in, float* __restrict__ out, int rows, int Lin){
  int Lo = 2*Lin;
  int idx = blockIdx.x*blockDim.x + threadIdx.x;
  if (idx >= rows*Lo) return;
  int i = idx % Lo; int r = idx / Lo;
  const float* xr = in + r*Lin;
  float v;
  if (i == 0)            v = xr[0];
  else if (i == Lo - 1)  v = xr[Lin-1];
  else {
    int k = i >> 1;
    if (i & 1) v = 0.75f*xr[k]   + 0.25f*xr[k+1];
    else       v = 0.25f*xr[k-1] + 0.75f*xr[k];
  }
  out[idx] = v;
}

// ---------------- inp: fused maxpool4(h4) + segment masking -> (128,160,171) ----------------
__global__ void k_inp(const float* __restrict__ h4, const float* __restrict__ xmiu,
                      float* __restrict__ inp){
  int idx = blockIdx.x*blockDim.x + threadIdx.x;
  if (idx >= 128*32*171) return;
  int l = idx % 171; int t = idx / 171; int c = t & 31; int b = t >> 5;
  const float* hr = h4 + t*174 + l;
  float wv = fmaxf(fmaxf(hr[0], hr[1]), fmaxf(hr[2], hr[3]));
  float xm = xmiu[idx];
  float prod = wv * xm;
  const float lo[5] = {0.0f, 0.2f, 0.4f, 0.6f, 0.8f};
  const float hi[5] = {0.2f, 0.4f, 0.6f, 0.8f, 2.0f};
  float* op = inp + ((b*160) + c)*171 + l;
  #pragma unroll
  for (int s = 0; s < 5; s++){
    bool m = (wv >= lo[s]) && (wv < hi[s]);
    op[s*32*171] = m ? prod : 0.f;
  }
}

// ---------------- until -> x1 channels [40,200) ----------------
__global__ void k_until(const float* __restrict__ inp, float* __restrict__ x1){
  int idx = blockIdx.x*blockDim.x + threadIdx.x;
  if (idx >= 128*160*170) return;
  int l = idx % 170; int t = idx / 170; int c = t % 160; int b = t / 160;
  const float* xr = inp + (b*160 + c)*171;
  float runmin = xr[l];
  float outv = 0.f;
  #pragma unroll 5
  for (int d = 1; d <= 25; d++){
    float xs = (l + d < 171) ? xr[l + d] : 0.f;
    outv = fmaxf(outv, fminf(runmin, xs));
    runmin = fminf(runmin, xs);
  }
  x1[((b*200) + 40 + c)*170 + l] = outv;
}

// ---------------- logic stage 1 partials: grid (85, ch=4, v=2) ----------------
__global__ void __launch_bounds__(TPB) k_logic1p(const float* __restrict__ inp, const float* __restrict__ wn,
                                                 float* __restrict__ p1){
  int bl = blockIdx.x*TPB + threadIdx.x;
  int l = bl % 170; int b = bl / 170;
  int ch = blockIdx.y, v = blockIdx.z;
  const float* W = wn + (v ? 6400 : 0);
  float acc[20];
  #pragma unroll
  for (int o = 0; o < 20; o++) acc[o] = 0.f;
  int c0 = ch*40;
  const float* ir = inp + (b*160 + c0)*171 + l;
  for (int c = 0; c < 40; c++){
    float u0 = clip01(ir[0]);
    float u1 = clip01(ir[1]);
    float g0, g1;
    if (v){ g0 = __logf(1.f - u0 + EPSL); g1 = __logf(1.f - u1 + EPSL); }
    else  { g0 = __logf(u0 + EPSL);       g1 = __logf(u1 + EPSL); }
    const float* wc = W + 2*(c0 + c);
    #pragma unroll
    for (int o = 0; o < 20; o++)
      acc[o] = fmaf(wc[o*320], g0, fmaf(wc[o*320 + 1], g1, acc[o]));
    ir += 171;
  }
  float* pp = p1 + ((ch*128 + b)*40 + v*20)*170 + l;
  #pragma unroll
  for (int o = 0; o < 20; o++) pp[o*170] = acc[o];
}

__global__ void k_fin1(const float* __restrict__ p1, float* __restrict__ x1){
  int idx = blockIdx.x*blockDim.x + threadIdx.x;
  if (idx >= 128*40*170) return;
  int l = idx % 170; int o = (idx/170) % 40; int b = idx / (170*40);
  float s = 0.f;
  #pragma unroll
  for (int ch = 0; ch < 4; ch++) s += p1[((ch*128 + b)*40 + o)*170 + l];
  float e = __expf(s);
  float r = (o < 20) ? e : fmaxf(0.f, 1.f - e);
  x1[(b*200 + o)*170 + l] = r;
}

// ---------------- logic stage 2 partials ----------------
__global__ void __launch_bounds__(TPB) k_logic2p(const float* __restrict__ x1, const float* __restrict__ wn,
                                                 float* __restrict__ p2){
  int bl = blockIdx.x*TPB + threadIdx.x;
  int l = bl % 170; int b = bl / 170;
  int ch = blockIdx.y, v = blockIdx.z;
  const float* W = wn + 12800 + (v ? 2400 : 0);
  float acc[6] = {0.f,0.f,0.f,0.f,0.f,0.f};
  int c0 = ch*50;
  const float* xr = x1 + (b*200 + c0)*170 + l;
  for (int c = 0; c < 50; c++){
    float g0 = 0.f;
    if (l > 0){
      float u0 = clip01(xr[-1]);
      g0 = v ? __logf(1.f - u0 + EPSL) : __logf(u0 + EPSL);
    }
    float u1 = clip01(xr[0]);
    float g1 = v ? __logf(1.f - u1 + EPSL) : __logf(u1 + EPSL);
    const float* wc = W + 2*(c0 + c);
    #pragma unroll
    for (int o = 0; o < 6; o++)
      acc[o] = fmaf(wc[o*400], g0, fmaf(wc[o*400 + 1], g1, acc[o]));
    xr += 170;
  }
  float* pp = p2 + ((ch*128 + b)*12 + v*6)*170 + l;
  #pragma unroll
  for (int o = 0; o < 6; o++) pp[o*170] = acc[o];
}

__global__ void k_fin2(const float* __restrict__ p2, float* __restrict__ x2){
  int idx = blockIdx.x*blockDim.x + threadIdx.x;
  if (idx >= 128*12*170) return;
  int l = idx % 170; int o = (idx/170) % 12; int b = idx / (170*12);
  float s = 0.f;
  #pragma unroll
  for (int ch = 0; ch < 4; ch++) s += p2[((ch*128 + b)*12 + o)*170 + l];
  float e = __expf(s);
  float r = (o < 6) ? e : fmaxf(0.f, 1.f - e);
  x2[(b*12 + o)*170 + l] = r;
}

// ---------------- tiled GEMM: C = act(A[M][K] · W[N][K]^T + bias) ----------------
// BM=BN=64, BK=32, 256 threads, 4x4 register tile. KSPLIT via grid.z -> partials.
template<int M, int N, int K, int KSPLIT, int ACT>
__global__ void __launch_bounds__(256) k_gemm(const float* __restrict__ A,
                                              const float* __restrict__ W,
                                              const float* __restrict__ bias,
                                              float* __restrict__ C){
  __shared__ float As[32][64];
  __shared__ float Bs[32][64];
  const int m0 = blockIdx.x*64, n0 = blockIdx.y*64;
  constexpr int KC = ((K + KSPLIT - 1)/KSPLIT + 31) & ~31;
  const int kbeg = blockIdx.z*KC;
  const int kend = (kbeg + KC < K) ? (kbeg + KC) : K;
  const int tid = threadIdx.x;
  const int row = tid >> 2;
  const int c0  = (tid & 3)*8;
  const int tm  = (tid & 15)*4;
  const int tn  = (tid >> 4)*4;

  float acc[4][4] = {{0,0,0,0},{0,0,0,0},{0,0,0,0},{0,0,0,0}};
  const float* Ar = A + (m0 + row)*K;
  const float* Wr = W + (n0 + row)*K;

  for (int kb = kbeg; kb < kend; kb += 32){
    #pragma unroll
    for (int j = 0; j < 8; j++){
      int kk = kb + c0 + j;
      As[c0 + j][row] = (kk < kend) ? Ar[kk] : 0.f;
      Bs[c0 + j][row] = (kk < kend) ? Wr[kk] : 0.f;
    }
    __syncthreads();
    #pragma unroll
    for (int k = 0; k < 32; k++){
      const float4 a = *(const float4*)&As[k][tm];
      const float4 b = *(const float4*)&Bs[k][tn];
      acc[0][0] = fmaf(a.x, b.x, acc[0][0]); acc[0][1] = fmaf(a.x, b.y, acc[0][1]);
      acc[0][2] = fmaf(a.x, b.z, acc[0][2]); acc[0][3] = fmaf(a.x, b.w, acc[0][3]);
      acc[1][0] = fmaf(a.y, b.x, acc[1][0]); acc[1][1] = fmaf(a.y, b.y, acc[1][1]);
      acc[1][2] = fmaf(a.y, b.z, acc[1][2]); acc[1][3] = fmaf(a.y, b.w, acc[1][3]);
      acc[2][0] = fmaf(a.z, b.x, acc[2][0]); acc[2][1] = fmaf(a.z, b.y, acc[2][1]);
      acc[2][2] = fmaf(a.z, b.z, acc[2][2]); acc[2][3] = fmaf(a.z, b.w, acc[2][3]);
      acc[3][0] = fmaf(a.w, b.x, acc[3][0]); acc[3][1] = fmaf(a.w, b.y, acc[3][1]);
      acc[3][2] = fmaf(a.w, b.z, acc[3][2]); acc[3][3] = fmaf(a.w, b.w, acc[3][3]);
    }
    __syncthreads();
  }

  if (KSPLIT == 1){
    #pragma unroll
    for (int i = 0; i < 4; i++){
      float4 v;
      v.x = acc[i][0] + bias[n0 + tn];
      v.y = acc[i][1] + bias[n0 + tn + 1];
      v.z = acc[i][2] + bias[n0 + tn + 2];
      v.w = acc[i][3] + bias[n0 + tn + 3];
      if (ACT == ACT_RELU){
        v.x = fmaxf(v.x, 0.f); v.y = fmaxf(v.y, 0.f);
        v.z = fmaxf(v.z, 0.f); v.w = fmaxf(v.w, 0.f);
      }
      *(float4*)&C[(m0 + tm + i)*N + n0 + tn] = v;
    }
  } else {
    #pragma unroll
    for (int i = 0; i < 4; i++){
      float4 v = {acc[i][0], acc[i][1], acc[i][2], acc[i][3]};
      *(float4*)&C[(blockIdx.z*M + m0 + tm + i)*N + n0 + tn] = v;
    }
  }
}

// ---------------- combine K-split partials + bias + relu ----------------
template<int MN, int M, int N, int KS>
__global__ void k_comb(const float* __restrict__ part, const float* __restrict__ bias,
                       float* __restrict__ out){
  int idx = blockIdx.x*blockDim.x + threadIdx.x;
  if (idx >= MN) return;
  int n = idx % N;
  float s = bias[n];
  #pragma unroll
  for (int z = 0; z < KS; z++) s += part[z*MN + idx];
  out[idx] = fmaxf(s, 0.f);
}

// ---------------- fc3 ----------------
__global__ void k_fc3(const float* __restrict__ h, const float* __restrict__ w,
                      const float* __restrict__ bias, float* __restrict__ out){
  int idx = blockIdx.x*blockDim.x + threadIdx.x;
  if (idx >= 1536*10) return;
  int q = idx % 10; int bc = idx / 10;
  const float* hr = h + bc*256;
  const float* wr = w + q*256;
  float s = bias[q];
  for (int p = 0; p < 256; p++) s = fmaf(hr[p], wr[p], s);
  out[idx] = s;
}

extern "C" void kernel_launch(void* const* d_in, const int* in_sizes, int n_in,
                              void* d_out, int out_size, void* d_ws, size_t ws_size,
                              hipStream_t stream) {
  const float* x      = (const float*)d_in[0];
  const float* wave_w = (const float*)d_in[1];
  const float* bn_g   = (const float*)d_in[2];
  const float* bn_b   = (const float*)d_in[3];
  const float* miu_ap = (const float*)d_in[4];
  const float* miu_bp = (const float*)d_in[5];
  const float* miu_an = (const float*)d_in[6];
  const float* miu_bn = (const float*)d_in[7];
  const float* ae_w1  = (const float*)d_in[8];
  const float* ae_b1  = (const float*)d_in[9];
  const float* ae_w2  = (const float*)d_in[10];
  const float* ae_b2  = (const float*)d_in[11];
  const float* ae_w3  = (const float*)d_in[12];
  const float* ae_b3  = (const float*)d_in[13];
  const float* ae_w4  = (const float*)d_in[14];
  const float* ae_b4  = (const float*)d_in[15];
  const float* and2_w = (const float*)d_in[16];
  const float* or2_w  = (const float*)d_in[17];
  const float* and_w  = (const float*)d_in[18];
  const float* or_w   = (const float*)d_in[19];
  const float* fc1_w  = (const float*)d_in[20];
  const float* fc1_b  = (const float*)d_in[21];
  const float* fc2_w  = (const float*)d_in[22];
  const float* fc2_b  = (const float*)d_in[23];
  const float* fc3_w  = (const float*)d_in[24];
  const float* fc3_b  = (const float*)d_in[25];
  float* out = (float*)d_out;
  float* ws  = (float*)d_ws;

  float* y1    = ws + OFF_Y1;
  float* xf    = ws + OFF_XF;
  float* xmiu  = ws + OFF_XMIU;
  float* c1    = ws + OFF_Y1;
  float* h1    = ws + OFF_H1;
  float* c2    = ws + OFF_XF;
  float* h2    = ws + OFF_H2;
  float* u1    = ws + OFF_H1;
  float* h3    = ws + OFF_H3;
  float* u2    = ws + OFF_Y1;
  float* h4    = ws + OFF_H1;
  float* inp   = ws + OFF_INP;
  float* x1    = ws + OFF_X1;
  float* p1    = ws + OFF_P1;
  float* p2    = ws + OFF_P2;
  float* x2    = ws + OFF_INP;
  float* fc1h  = ws + OFF_FC1H;
  float* fc2p  = ws + OFF_FC2P;
  float* fc2h  = ws + OFF_INP + 262144;
  float* stats = ws + OFF_STATS;
  double* bnp  = (double*)(ws + OFF_BNP);
  float* wn    = ws + OFF_WN;

  k_softmax  <<<52, TPB, 0, stream>>>(and2_w, or2_w, and_w, or_w, wn);
  k_conv_wave<<<cdiv(128*16*688, TPB), TPB, 0, stream>>>(x, wave_w, y1);
  k_bn_part  <<<128, TPB, 0, stream>>>(y1, bnp);
  k_bn_fin   <<<1, 64, 0, stream>>>(bnp, stats);
  k_xf       <<<cdiv(128*16*343, TPB), TPB, 0, stream>>>(y1, stats, bn_g, bn_b, xf);
  k_xmiu     <<<cdiv(128*32*171, TPB), TPB, 0, stream>>>(xf, miu_ap, miu_bp, miu_an, miu_bn, xmiu);

  k_conv<32,171,64,171,1,ACT_TANH,16><<<dim3(128,3), 256, 0, stream>>>(xmiu, ae_w1, ae_b1, c1);
  k_pool     <<<cdiv(128*64*85, TPB), TPB, 0, stream>>>(c1, h1, 128*64, 171, 85);
  k_conv<64,85,32,85,1,ACT_RELU,32><<<dim3(128,1), 256, 0, stream>>>(h1, ae_w2, ae_b2, c2);
  k_pool     <<<cdiv(128*32*42, TPB), TPB, 0, stream>>>(c2, h2, 128*32, 85, 42);
  k_up       <<<cdiv(128*32*84,  TPB), TPB, 0, stream>>>(h2, u1, 128*32, 42);
  k_conv<32,84,64,86,2,ACT_TANH,16><<<dim3(128,2), 256, 0, stream>>>(u1, ae_w3, ae_b3, h3);
  k_up       <<<cdiv(128*64*172, TPB), TPB, 0, stream>>>(h3, u2, 128*64, 86);
  k_conv<64,172,32,174,2,ACT_SIG,32><<<dim3(128,2), 256, 0, stream>>>(u2, ae_w4, ae_b4, h4);

  k_inp      <<<cdiv(128*32*171, TPB), TPB, 0, stream>>>(h4, xmiu, inp);
  k_until    <<<cdiv(128*160*170,TPB), TPB, 0, stream>>>(inp, x1);
  k_logic1p  <<<dim3(85, 4, 2), TPB, 0, stream>>>(inp, wn, p1);
  k_fin1     <<<cdiv(128*40*170, TPB), TPB, 0, stream>>>(p1, x1);
  k_logic2p  <<<dim3(85, 4, 2), TPB, 0, stream>>>(x1, wn, p2);
  k_fin2     <<<cdiv(128*12*170, TPB), TPB, 0, stream>>>(p2, x2);

  k_gemm<1536,1024,170,1,ACT_RELU><<<dim3(24,16,1), 256, 0, stream>>>(x2, fc1_w, fc1_b, fc1h);
  k_gemm<1536,256,1024,4,ACT_RELU><<<dim3(24,4,4), 256, 0, stream>>>(fc1h, fc2_w, fc2_b, fc2p);
  k_comb<1536*256,1536,256,4><<<cdiv(1536*256, TPB), TPB, 0, stream>>>(fc2p, fc2_b, fc2h);
  k_fc3      <<<cdiv(1536*10, TPB), TPB, 0, stream>>>(fc2h, fc3_w, fc3_b, out);
}

// Round 6
// 382.574 us; speedup vs baseline: 2.2879x; 1.0946x over previous
//
#include <hip/hip_runtime.h>

#define TPB 256
static inline int cdiv(int a, int b){ return (a + b - 1) / b; }

#define EPSL 1e-6f
#define ACT_TANH 0
#define ACT_RELU 1
#define ACT_SIG  2

__device__ __forceinline__ float sigf(float x){ return 1.0f / (1.0f + __expf(-x)); }
__device__ __forceinline__ float clip01(float x){ return fminf(fmaxf(x, 0.f), 1.f); }

// ---------------- workspace layout (float offsets) ----------------
#define OFF_Y1   0
#define OFF_XF   1409024
#define OFF_XMIU 2111488
#define OFF_H1   2811904
#define OFF_H2   3508224
#define OFF_H3   3680256
#define OFF_INP  4384768
#define OFF_X1   7886848
#define OFF_TAIL 12238848
#define OFF_P1   0
#define OFF_P2   0
// FC stage (all prior front-region buffers dead):
#define OFF_GP   0                        // gemm partials: max 8*1536*256 = 3145728 (< OFF_INP)
#define OFF_X2P  OFF_INP                  // 1536*192 = 294912
#define OFF_FC2H (OFF_INP + 294912)      // 1536*256 = 393216
#define OFF_W1P  (OFF_INP + 294912 + 393216)  // 1024*192 = 196608
#define OFF_FC1H OFF_X1                   // 1536*1024 = 1572864 (x1 dead)
#define OFF_STATS OFF_TAIL
#define OFF_BNP  (OFF_TAIL + 64)
#define OFF_WN   (OFF_TAIL + 64 + 512)

// ---------------- softmax prep for logic weights ----------------
__global__ void k_softmax(const float* __restrict__ a2, const float* __restrict__ o2,
                          const float* __restrict__ aw, const float* __restrict__ ow,
                          float* __restrict__ wn){
  int blk = blockIdx.x;
  const float* src; float* dst; int n;
  if (blk < 20)      { src = a2 + blk*320;      dst = wn + blk*320;              n = 320; }
  else if (blk < 40) { src = o2 + (blk-20)*320; dst = wn + 6400 + (blk-20)*320;  n = 320; }
  else if (blk < 46) { src = aw + (blk-40)*400; dst = wn + 12800 + (blk-40)*400; n = 400; }
  else               { src = ow + (blk-46)*400; dst = wn + 15200 + (blk-46)*400; n = 400; }
  __shared__ float sh[TPB];
  float m = -1e30f;
  for (int i = threadIdx.x; i < n; i += TPB) m = fmaxf(m, src[i]);
  sh[threadIdx.x] = m; __syncthreads();
  for (int off = TPB/2; off > 0; off >>= 1){
    if (threadIdx.x < off) sh[threadIdx.x] = fmaxf(sh[threadIdx.x], sh[threadIdx.x+off]);
    __syncthreads();
  }
  m = sh[0]; __syncthreads();
  float s = 0.f;
  for (int i = threadIdx.x; i < n; i += TPB) s += expf(src[i] - m);
  sh[threadIdx.x] = s; __syncthreads();
  for (int off = TPB/2; off > 0; off >>= 1){
    if (threadIdx.x < off) sh[threadIdx.x] += sh[threadIdx.x+off];
    __syncthreads();
  }
  float inv = 1.0f / sh[0];
  __syncthreads();
  for (int i = threadIdx.x; i < n; i += TPB) dst[i] = expf(src[i] - m) * inv;
}

// ---------------- stage 1: wave conv (128,1,719)->(128,16,688) ----------------
__global__ void k_conv_wave(const float* __restrict__ x, const float* __restrict__ ww,
                            float* __restrict__ y){
  int idx = blockIdx.x*blockDim.x + threadIdx.x;
  if (idx >= 128*16*688) return;
  int l = idx % 688; int t = idx / 688; int o = t & 15; int b = t >> 4;
  const float* xr = x + b*719 + l;
  const float* wr = ww + o*32;
  float s = 0.f;
  #pragma unroll
  for (int k = 0; k < 32; k++) s = fmaf(xr[k], wr[k], s);
  y[idx] = s;
}

// ---------------- BN stats ----------------
__global__ void k_bn_part(const float* __restrict__ y, double* __restrict__ bnp){
  int c = blockIdx.x & 15, ch = blockIdx.x >> 4;
  double s = 0.0, s2 = 0.0;
  for (int i = threadIdx.x; i < 16*688; i += TPB){
    int b = ch*16 + i/688, l = i % 688;
    float v = y[(b*16 + c)*688 + l];
    s += (double)v; s2 += (double)v * (double)v;
  }
  __shared__ double sh[TPB], sh2[TPB];
  sh[threadIdx.x] = s; sh2[threadIdx.x] = s2; __syncthreads();
  for (int off = TPB/2; off > 0; off >>= 1){
    if (threadIdx.x < off){ sh[threadIdx.x] += sh[threadIdx.x+off]; sh2[threadIdx.x] += sh2[threadIdx.x+off]; }
    __syncthreads();
  }
  if (threadIdx.x == 0){ bnp[blockIdx.x] = sh[0]; bnp[128 + blockIdx.x] = sh2[0]; }
}

__global__ void k_bn_fin(const double* __restrict__ bnp, float* __restrict__ stats){
  int c = threadIdx.x;
  if (c >= 16) return;
  double s = 0.0, s2 = 0.0;
  for (int j = 0; j < 8; j++){ s += bnp[j*16 + c]; s2 += bnp[128 + j*16 + c]; }
  double n = 128.0*688.0;
  double m = s / n;
  double var = s2 / n - m*m;
  stats[c]      = (float)m;
  stats[16 + c] = (float)(1.0 / sqrt(var + 1e-5));
}

// ---------------- xf = maxpool3s2(relu(bn(y))) -> (128,16,343) ----------------
__global__ void k_xf(const float* __restrict__ y, const float* __restrict__ stats,
                     const float* __restrict__ g, const float* __restrict__ bb,
                     float* __restrict__ xf){
  int idx = blockIdx.x*blockDim.x + threadIdx.x;
  if (idx >= 128*16*343) return;
  int l = idx % 343; int t = idx / 343; int c = t & 15; int b = t >> 4;
  float mean = stats[c], rstd = stats[16 + c];
  float gc = g[c], bc = bb[c];
  const float* yr = y + (b*16 + c)*688 + 2*l;
  float m = -1e30f;
  #pragma unroll
  for (int j = 0; j < 3; j++){
    float v = fmaf(gc*(yr[j] - mean), rstd, bc);
    v = fmaxf(v, 0.f);
    m = fmaxf(m, v);
  }
  xf[idx] = m;
}

// ---------------- x_miu ----------------
__global__ void k_xmiu(const float* __restrict__ xf,
                       const float* __restrict__ ap, const float* __restrict__ bp,
                       const float* __restrict__ an, const float* __restrict__ bn,
                       float* __restrict__ out){
  int idx = blockIdx.x*blockDim.x + threadIdx.x;
  if (idx >= 128*32*171) return;
  int l = idx % 171; int t = idx / 171; int c = t & 31; int b = t >> 5;
  int cc = c & 15;
  float sign = (c < 16) ? 1.f : -1.f;
  float a  = (c < 16) ? ap[cc] : an[cc];
  float bo = (c < 16) ? bp[cc] : bn[cc];
  const float* xr = xf + (b*16 + cc)*343 + 2*l;
  float m = -1e30f;
  #pragma unroll
  for (int j = 0; j < 3; j++){
    float v = sigf(sign * a * (xr[j] - bo));
    m = fmaxf(m, v);
  }
  out[idx] = m;
}

// ---------------- generic LDS-tiled 1D conv (kernel=3), act fused ----------------
template<int CIN, int LIN, int COUT, int LOUT, int PAD, int ACT, int PL>
__global__ void __launch_bounds__(256) k_conv(const float* __restrict__ in,
                                              const float* __restrict__ w,
                                              const float* __restrict__ bias,
                                              float* __restrict__ outp){
  constexpr int LSEG = 4*PL;
  constexpr int WL = ((LSEG + 2) + 3) & ~3;
  constexpr int K3 = CIN*3;
  __shared__ float smem[CIN*WL + 8 + K3*COUT];
  float* sin = smem;
  float* wT  = smem + CIN*WL + 8;
  const int b = blockIdx.x;
  const int tid = threadIdx.x;
  const int base = blockIdx.y*LSEG - PAD;

  const float* gin = in + b*CIN*LIN;
  for (int e = tid; e < CIN*WL; e += 256){
    int i = e / WL, c = e - i*WL;
    int q = base + c;
    sin[e] = (q >= 0 && q < LIN) ? gin[i*LIN + q] : 0.f;
  }
  if (tid < 8) sin[CIN*WL + tid] = 0.f;
  for (int e = tid; e < K3*COUT; e += 256){
    int o = e & (COUT-1), m = e / COUT;
    wT[m*COUT + o] = w[o*K3 + m];
  }
  __syncthreads();

  const int to = tid / PL, tp = tid - (tid/PL)*PL;
  const int o0 = to*4;
  const int pl0 = 4*tp;
  float acc[4][4] = {{0,0,0,0},{0,0,0,0},{0,0,0,0},{0,0,0,0}};

  for (int i = 0; i < CIN; i++){
    const float* srow = sin + i*WL + pl0;
    float xv[6];
    *(float4*)&xv[0] = *(const float4*)srow;
    *(float2*)&xv[4] = *(const float2*)(srow + 4);
    const float* wrow = wT + (i*3)*COUT + o0;
    float wv[3][4];
    #pragma unroll
    for (int k = 0; k < 3; k++)
      *(float4*)&wv[k][0] = *(const float4*)(wrow + k*COUT);
    #pragma unroll
    for (int j = 0; j < 4; j++)
      #pragma unroll
      for (int k = 0; k < 3; k++)
        #pragma unroll
        for (int oo = 0; oo < 4; oo++)
          acc[j][oo] = fmaf(xv[j+k], wv[k][oo], acc[j][oo]);
  }

  const int pg0 = blockIdx.y*LSEG + pl0;
  float bv[4];
  #pragma unroll
  for (int oo = 0; oo < 4; oo++) bv[oo] = bias[o0 + oo];
  #pragma unroll
  for (int oo = 0; oo < 4; oo++){
    float* orow = outp + (b*COUT + o0 + oo)*LOUT;
    #pragma unroll
    for (int j = 0; j < 4; j++){
      int p = pg0 + j;
      if (p < LOUT){
        float s = acc[j][oo] + bv[oo];
        float r;
        if (ACT == ACT_TANH)      r = tanhf(s);
        else if (ACT == ACT_RELU) r = fmaxf(s, 0.f);
        else                      r = sigf(s);
        orow[p] = r;
      }
    }
  }
}

// ---------------- maxpool3 stride2 ----------------
__global__ void k_pool(const float* __restrict__ in, float* __restrict__ out,
                       int rows, int Lc, int Lp){
  int idx = blockIdx.x*blockDim.x + threadIdx.x;
  if (idx >= rows*Lp) return;
  int l = idx % Lp; int r = idx / Lp;
  const float* xr = in + r*Lc + 2*l;
  out[idx] = fmaxf(fmaxf(xr[0], xr[1]), xr[2]);
}

// ---------------- upsample2 (jax linear, half-pixel) ----------------
__global__ void k_up(const float* __restrict__ in, float* __restrict__ out, int rows, int Lin){
  int Lo = 2*Lin;
  int idx = blockIdx.x*blockDim.x + threadIdx.x;
  if (idx >= rows*Lo) return;
  int i = idx % Lo; int r = idx / Lo;
  const float* xr = in + r*Lin;
  float v;
  if (i == 0)            v = xr[0];
  else if (i == Lo - 1)  v = xr[Lin-1];
  else {
    int k = i >> 1;
    if (i & 1) v = 0.75f*xr[k]   + 0.25f*xr[k+1];
    else       v = 0.25f*xr[k-1] + 0.75f*xr[k];
  }
  out[idx] = v;
}

// ---------------- inp: fused maxpool4(h4) + segment masking -> (128,160,171) ----------------
__global__ void k_inp(const float* __restrict__ h4, const float* __restrict__ xmiu,
                      float* __restrict__ inp){
  int idx = blockIdx.x*blockDim.x + threadIdx.x;
  if (idx >= 128*32*171) return;
  int l = idx % 171; int t = idx / 171; int c = t & 31; int b = t >> 5;
  const float* hr = h4 + t*174 + l;
  float wv = fmaxf(fmaxf(hr[0], hr[1]), fmaxf(hr[2], hr[3]));
  float xm = xmiu[idx];
  float prod = wv * xm;
  const float lo[5] = {0.0f, 0.2f, 0.4f, 0.6f, 0.8f};
  const float hi[5] = {0.2f, 0.4f, 0.6f, 0.8f, 2.0f};
  float* op = inp + ((b*160) + c)*171 + l;
  #pragma unroll
  for (int s = 0; s < 5; s++){
    bool m = (wv >= lo[s]) && (wv < hi[s]);
    op[s*32*171] = m ? prod : 0.f;
  }
}

// ---------------- until -> x1 channels [40,200) ----------------
__global__ void k_until(const float* __restrict__ inp, float* __restrict__ x1){
  int idx = blockIdx.x*blockDim.x + threadIdx.x;
  if (idx >= 128*160*170) return;
  int l = idx % 170; int t = idx / 170; int c = t % 160; int b = t / 160;
  const float* xr = inp + (b*160 + c)*171;
  float runmin = xr[l];
  float outv = 0.f;
  #pragma unroll 5
  for (int d = 1; d <= 25; d++){
    float xs = (l + d < 171) ? xr[l + d] : 0.f;
    outv = fmaxf(outv, fminf(runmin, xs));
    runmin = fminf(runmin, xs);
  }
  x1[((b*200) + 40 + c)*170 + l] = outv;
}

// ---------------- logic stage 1 partials: grid (85, ch=4, v=2) ----------------
__global__ void __launch_bounds__(TPB) k_logic1p(const float* __restrict__ inp, const float* __restrict__ wn,
                                                 float* __restrict__ p1){
  int bl = blockIdx.x*TPB + threadIdx.x;
  int l = bl % 170; int b = bl / 170;
  int ch = blockIdx.y, v = blockIdx.z;
  const float* W = wn + (v ? 6400 : 0);
  float acc[20];
  #pragma unroll
  for (int o = 0; o < 20; o++) acc[o] = 0.f;
  int c0 = ch*40;
  const float* ir = inp + (b*160 + c0)*171 + l;
  for (int c = 0; c < 40; c++){
    float u0 = clip01(ir[0]);
    float u1 = clip01(ir[1]);
    float g0, g1;
    if (v){ g0 = __logf(1.f - u0 + EPSL); g1 = __logf(1.f - u1 + EPSL); }
    else  { g0 = __logf(u0 + EPSL);       g1 = __logf(u1 + EPSL); }
    const float* wc = W + 2*(c0 + c);
    #pragma unroll
    for (int o = 0; o < 20; o++)
      acc[o] = fmaf(wc[o*320], g0, fmaf(wc[o*320 + 1], g1, acc[o]));
    ir += 171;
  }
  float* pp = p1 + ((ch*128 + b)*40 + v*20)*170 + l;
  #pragma unroll
  for (int o = 0; o < 20; o++) pp[o*170] = acc[o];
}

__global__ void k_fin1(const float* __restrict__ p1, float* __restrict__ x1){
  int idx = blockIdx.x*blockDim.x + threadIdx.x;
  if (idx >= 128*40*170) return;
  int l = idx % 170; int o = (idx/170) % 40; int b = idx / (170*40);
  float s = 0.f;
  #pragma unroll
  for (int ch = 0; ch < 4; ch++) s += p1[((ch*128 + b)*40 + o)*170 + l];
  float e = __expf(s);
  float r = (o < 20) ? e : fmaxf(0.f, 1.f - e);
  x1[(b*200 + o)*170 + l] = r;
}

// ---------------- logic stage 2 partials ----------------
__global__ void __launch_bounds__(TPB) k_logic2p(const float* __restrict__ x1, const float* __restrict__ wn,
                                                 float* __restrict__ p2){
  int bl = blockIdx.x*TPB + threadIdx.x;
  int l = bl % 170; int b = bl / 170;
  int ch = blockIdx.y, v = blockIdx.z;
  const float* W = wn + 12800 + (v ? 2400 : 0);
  float acc[6] = {0.f,0.f,0.f,0.f,0.f,0.f};
  int c0 = ch*50;
  const float* xr = x1 + (b*200 + c0)*170 + l;
  for (int c = 0; c < 50; c++){
    float g0 = 0.f;
    if (l > 0){
      float u0 = clip01(xr[-1]);
      g0 = v ? __logf(1.f - u0 + EPSL) : __logf(u0 + EPSL);
    }
    float u1 = clip01(xr[0]);
    float g1 = v ? __logf(1.f - u1 + EPSL) : __logf(u1 + EPSL);
    const float* wc = W + 2*(c0 + c);
    #pragma unroll
    for (int o = 0; o < 6; o++)
      acc[o] = fmaf(wc[o*400], g0, fmaf(wc[o*400 + 1], g1, acc[o]));
    xr += 170;
  }
  float* pp = p2 + ((ch*128 + b)*12 + v*6)*170 + l;
  #pragma unroll
  for (int o = 0; o < 6; o++) pp[o*170] = acc[o];
}

// finalize logic2 -> x2 padded to stride 192 (zero pad cols 170..191) for aligned GEMM
__global__ void k_fin2(const float* __restrict__ p2, float* __restrict__ x2p){
  int idx = blockIdx.x*blockDim.x + threadIdx.x;
  if (idx >= 128*12*192) return;
  int l = idx % 192; int ro = idx / 192;          // ro = b*12+o
  if (l >= 170){ x2p[ro*192 + l] = 0.f; return; }
  int o = ro % 12; int b = ro / 12;
  float s = 0.f;
  #pragma unroll
  for (int ch = 0; ch < 4; ch++) s += p2[((ch*128 + b)*12 + o)*170 + l];
  float e = __expf(s);
  float r = (o < 6) ? e : fmaxf(0.f, 1.f - e);
  x2p[ro*192 + l] = r;
}

// repack fc1_w [1024][170] -> [1024][192] zero-padded
__global__ void k_wpad(const float* __restrict__ w, float* __restrict__ wp){
  int idx = blockIdx.x*blockDim.x + threadIdx.x;
  if (idx >= 1024*192) return;
  int k = idx % 192; int o = idx / 192;
  wp[idx] = (k < 170) ? w[o*170 + k] : 0.f;
}

// ---------------- pipelined tiled GEMM: partials of A[M][K] · W[N][K]^T ----------------
// BM=BN=64, BK=32, 256 thr, 4x4 tile. Double-buffered LDS, register prefetch.
// Requires K % (KSPLIT*32) == 0. Writes partials C[z][M][N].
template<int M, int N, int K, int KSPLIT>
__global__ void __launch_bounds__(256) k_gemm(const float* __restrict__ A,
                                              const float* __restrict__ W,
                                              float* __restrict__ C){
  static_assert(K % (KSPLIT*32) == 0, "K split");
  constexpr int KC = K / KSPLIT;
  constexpr int NT = KC / 32;
  constexpr int S = 68;                        // row stride: 68%32=4 -> 2-way max (free)
  __shared__ float As[2][32*S];
  __shared__ float Bs[2][32*S];
  const int m0 = blockIdx.x*64, n0 = blockIdx.y*64;
  const int kbeg = blockIdx.z*KC;
  const int tid = threadIdx.x;
  const int row = tid >> 2;                    // 0..63
  const int c4  = (tid & 3)*4;                 // 0,4,8,12
  const int tm  = (tid & 15)*4;
  const int tn  = (tid >> 4)*4;

  const float* Ar = A + (m0 + row)*K + kbeg + c4;
  const float* Wr = W + (n0 + row)*K + kbeg + c4;

  float4 ra0 = *(const float4*)(Ar);
  float4 ra1 = *(const float4*)(Ar + 16);
  float4 rb0 = *(const float4*)(Wr);
  float4 rb1 = *(const float4*)(Wr + 16);

  float acc[4][4] = {{0,0,0,0},{0,0,0,0},{0,0,0,0},{0,0,0,0}};
  int buf = 0;
  {
    float* a = As[0]; float* b = Bs[0];
    #pragma unroll
    for (int i = 0; i < 4; i++){
      a[(c4 + i)*S + row]      = ((const float*)&ra0)[i];
      a[(c4 + 16 + i)*S + row] = ((const float*)&ra1)[i];
      b[(c4 + i)*S + row]      = ((const float*)&rb0)[i];
      b[(c4 + 16 + i)*S + row] = ((const float*)&rb1)[i];
    }
  }
  __syncthreads();

  for (int t = 0; t < NT; t++){
    if (t + 1 < NT){
      Ar += 32; Wr += 32;
      ra0 = *(const float4*)(Ar);
      ra1 = *(const float4*)(Ar + 16);
      rb0 = *(const float4*)(Wr);
      rb1 = *(const float4*)(Wr + 16);
    }
    const float* a = As[buf]; const float* b = Bs[buf];
    #pragma unroll
    for (int k = 0; k < 32; k++){
      const float4 av = *(const float4*)(a + k*S + tm);
      const float4 bv = *(const float4*)(b + k*S + tn);
      acc[0][0] = fmaf(av.x, bv.x, acc[0][0]); acc[0][1] = fmaf(av.x, bv.y, acc[0][1]);
      acc[0][2] = fmaf(av.x, bv.z, acc[0][2]); acc[0][3] = fmaf(av.x, bv.w, acc[0][3]);
      acc[1][0] = fmaf(av.y, bv.x, acc[1][0]); acc[1][1] = fmaf(av.y, bv.y, acc[1][1]);
      acc[1][2] = fmaf(av.y, bv.z, acc[1][2]); acc[1][3] = fmaf(av.y, bv.w, acc[1][3]);
      acc[2][0] = fmaf(av.z, bv.x, acc[2][0]); acc[2][1] = fmaf(av.z, bv.y, acc[2][1]);
      acc[2][2] = fmaf(av.z, bv.z, acc[2][2]); acc[2][3] = fmaf(av.z, bv.w, acc[2][3]);
      acc[3][0] = fmaf(av.w, bv.x, acc[3][0]); acc[3][1] = fmaf(av.w, bv.y, acc[3][1]);
      acc[3][2] = fmaf(av.w, bv.z, acc[3][2]); acc[3][3] = fmaf(av.w, bv.w, acc[3][3]);
    }
    if (t + 1 < NT){
      int nb = buf ^ 1;
      float* an = As[nb]; float* bn = Bs[nb];
      #pragma unroll
      for (int i = 0; i < 4; i++){
        an[(c4 + i)*S + row]      = ((const float*)&ra0)[i];
        an[(c4 + 16 + i)*S + row] = ((const float*)&ra1)[i];
        bn[(c4 + i)*S + row]      = ((const float*)&rb0)[i];
        bn[(c4 + 16 + i)*S + row] = ((const float*)&rb1)[i];
      }
      __syncthreads();
      buf = nb;
    }
  }

  float* Cz = C + (size_t)blockIdx.z*M*N;
  #pragma unroll
  for (int i = 0; i < 4; i++){
    float4 v = {acc[i][0], acc[i][1], acc[i][2], acc[i][3]};
    *(float4*)&Cz[(m0 + tm + i)*N + n0 + tn] = v;
  }
}

// ---------------- combine K-split partials + bias + relu ----------------
template<int MN, int N, int KS>
__global__ void k_comb(const float* __restrict__ part, const float* __restrict__ bias,
                       float* __restrict__ out){
  int idx = blockIdx.x*blockDim.x + threadIdx.x;
  if (idx >= MN) return;
  int n = idx % N;
  float s = bias[n];
  #pragma unroll
  for (int z = 0; z < KS; z++) s += part[(size_t)z*MN + idx];
  out[idx] = fmaxf(s, 0.f);
}

// ---------------- fc3 ----------------
__global__ void k_fc3(const float* __restrict__ h, const float* __restrict__ w,
                      const float* __restrict__ bias, float* __restrict__ out){
  int idx = blockIdx.x*blockDim.x + threadIdx.x;
  if (idx >= 1536*10) return;
  int q = idx % 10; int bc = idx / 10;
  const float* hr = h + bc*256;
  const float* wr = w + q*256;
  float s = bias[q];
  for (int p = 0; p < 256; p++) s = fmaf(hr[p], wr[p], s);
  out[idx] = s;
}

extern "C" void kernel_launch(void* const* d_in, const int* in_sizes, int n_in,
                              void* d_out, int out_size, void* d_ws, size_t ws_size,
                              hipStream_t stream) {
  const float* x      = (const float*)d_in[0];
  const float* wave_w = (const float*)d_in[1];
  const float* bn_g   = (const float*)d_in[2];
  const float* bn_b   = (const float*)d_in[3];
  const float* miu_ap = (const float*)d_in[4];
  const float* miu_bp = (const float*)d_in[5];
  const float* miu_an = (const float*)d_in[6];
  const float* miu_bn = (const float*)d_in[7];
  const float* ae_w1  = (const float*)d_in[8];
  const float* ae_b1  = (const float*)d_in[9];
  const float* ae_w2  = (const float*)d_in[10];
  const float* ae_b2  = (const float*)d_in[11];
  const float* ae_w3  = (const float*)d_in[12];
  const float* ae_b3  = (const float*)d_in[13];
  const float* ae_w4  = (const float*)d_in[14];
  const float* ae_b4  = (const float*)d_in[15];
  const float* and2_w = (const float*)d_in[16];
  const float* or2_w  = (const float*)d_in[17];
  const float* and_w  = (const float*)d_in[18];
  const float* or_w   = (const float*)d_in[19];
  const float* fc1_w  = (const float*)d_in[20];
  const float* fc1_b  = (const float*)d_in[21];
  const float* fc2_w  = (const float*)d_in[22];
  const float* fc2_b  = (const float*)d_in[23];
  const float* fc3_w  = (const float*)d_in[24];
  const float* fc3_b  = (const float*)d_in[25];
  float* out = (float*)d_out;
  float* ws  = (float*)d_ws;

  float* y1    = ws + OFF_Y1;
  float* xf    = ws + OFF_XF;
  float* xmiu  = ws + OFF_XMIU;
  float* c1    = ws + OFF_Y1;
  float* h1    = ws + OFF_H1;
  float* c2    = ws + OFF_XF;
  float* h2    = ws + OFF_H2;
  float* u1    = ws + OFF_H1;
  float* h3    = ws + OFF_H3;
  float* u2    = ws + OFF_Y1;
  float* h4    = ws + OFF_H1;
  float* inp   = ws + OFF_INP;
  float* x1    = ws + OFF_X1;
  float* p1    = ws + OFF_P1;
  float* p2    = ws + OFF_P2;
  float* gp    = ws + OFF_GP;
  float* x2p   = ws + OFF_X2P;
  float* fc2h  = ws + OFF_FC2H;
  float* w1p   = ws + OFF_W1P;
  float* fc1h  = ws + OFF_FC1H;
  float* stats = ws + OFF_STATS;
  double* bnp  = (double*)(ws + OFF_BNP);
  float* wn    = ws + OFF_WN;

  k_softmax  <<<52, TPB, 0, stream>>>(and2_w, or2_w, and_w, or_w, wn);
  k_conv_wave<<<cdiv(128*16*688, TPB), TPB, 0, stream>>>(x, wave_w, y1);
  k_bn_part  <<<128, TPB, 0, stream>>>(y1, bnp);
  k_bn_fin   <<<1, 64, 0, stream>>>(bnp, stats);
  k_xf       <<<cdiv(128*16*343, TPB), TPB, 0, stream>>>(y1, stats, bn_g, bn_b, xf);
  k_xmiu     <<<cdiv(128*32*171, TPB), TPB, 0, stream>>>(xf, miu_ap, miu_bp, miu_an, miu_bn, xmiu);

  k_conv<32,171,64,171,1,ACT_TANH,16><<<dim3(128,3), 256, 0, stream>>>(xmiu, ae_w1, ae_b1, c1);
  k_pool     <<<cdiv(128*64*85, TPB), TPB, 0, stream>>>(c1, h1, 128*64, 171, 85);
  k_conv<64,85,32,85,1,ACT_RELU,32><<<dim3(128,1), 256, 0, stream>>>(h1, ae_w2, ae_b2, c2);
  k_pool     <<<cdiv(128*32*42, TPB), TPB, 0, stream>>>(c2, h2, 128*32, 85, 42);
  k_up       <<<cdiv(128*32*84,  TPB), TPB, 0, stream>>>(h2, u1, 128*32, 42);
  k_conv<32,84,64,86,2,ACT_TANH,16><<<dim3(128,2), 256, 0, stream>>>(u1, ae_w3, ae_b3, h3);
  k_up       <<<cdiv(128*64*172, TPB), TPB, 0, stream>>>(h3, u2, 128*64, 86);
  k_conv<64,172,32,174,2,ACT_SIG,32><<<dim3(128,2), 256, 0, stream>>>(u2, ae_w4, ae_b4, h4);

  k_inp      <<<cdiv(128*32*171, TPB), TPB, 0, stream>>>(h4, xmiu, inp);
  k_until    <<<cdiv(128*160*170,TPB), TPB, 0, stream>>>(inp, x1);
  k_logic1p  <<<dim3(85, 4, 2), TPB, 0, stream>>>(inp, wn, p1);
  k_fin1     <<<cdiv(128*40*170, TPB), TPB, 0, stream>>>(p1, x1);
  k_logic2p  <<<dim3(85, 4, 2), TPB, 0, stream>>>(x1, wn, p2);
  k_wpad     <<<cdiv(1024*192, TPB), TPB, 0, stream>>>(fc1_w, w1p);
  k_fin2     <<<cdiv(128*12*192, TPB), TPB, 0, stream>>>(p2, x2p);

  // fc1: (1536,192)x(1024,192)^T, KSPLIT=2 -> 24*16*2 = 768 blocks
  k_gemm<1536,1024,192,2><<<dim3(24,16,2), 256, 0, stream>>>(x2p, w1p, gp);
  k_comb<1536*1024,1024,2><<<cdiv(1536*1024, TPB), TPB, 0, stream>>>(gp, fc1_b, fc1h);
  // fc2: (1536,1024)x(256,1024)^T, KSPLIT=8 -> 24*4*8 = 768 blocks
  k_gemm<1536,256,1024,8><<<dim3(24,4,8), 256, 0, stream>>>(fc1h, fc2_w, gp);
  k_comb<1536*256,256,8><<<cdiv(1536*256, TPB), TPB, 0, stream>>>(gp, fc2_b, fc2h);
  k_fc3      <<<cdiv(1536*10, TPB), TPB, 0, stream>>>(fc2h, fc3_w, fc3_b, out);
}

// Round 7
// 358.659 us; speedup vs baseline: 2.4405x; 1.0667x over previous
//
#include <hip/hip_runtime.h>

#define TPB 256
static inline int cdiv(int a, int b){ return (a + b - 1) / b; }

#define EPSL 1e-6f
#define ACT_TANH 0
#define ACT_RELU 1
#define ACT_SIG  2
#define ACT_NONE 3

__device__ __forceinline__ float sigf(float x){ return 1.0f / (1.0f + __expf(-x)); }
__device__ __forceinline__ float clip01(float x){ return fminf(fmaxf(x, 0.f), 1.f); }

// ---------------- workspace layout (float offsets) ----------------
#define OFF_Y1   0
#define OFF_XF   1409024
#define OFF_XMIU 2111488
#define OFF_H1   2811904
#define OFF_INP  4384768
#define OFF_X1   7886848
#define OFF_TAIL 12238848
// c1 @H1 (1400832 <= 1572864); c2 @XF (348160); h3 @Y1 (704512, y1 dead after xmiu2);
// h4 @H1 (712704, c1 dead); p1 @0 (3481600, y1/c2/h4 consumers all done before logic1p);
// p2 @0; gp @0 (3145728 < OFF_INP); x2p @INP (294912); w1p after; fc1h @X1.
#define OFF_P1   0
#define OFF_P2   0
#define OFF_GP   0
#define OFF_X2P  OFF_INP
#define OFF_W1P  (OFF_INP + 294912 + 393216)
#define OFF_FC1H OFF_X1
#define OFF_STATS OFF_TAIL
#define OFF_BNP  (OFF_TAIL + 64)
#define OFF_WN   (OFF_TAIL + 64 + 512)

// ---------------- softmax prep for logic weights ----------------
__global__ void k_softmax(const float* __restrict__ a2, const float* __restrict__ o2,
                          const float* __restrict__ aw, const float* __restrict__ ow,
                          float* __restrict__ wn){
  int blk = blockIdx.x;
  const float* src; float* dst; int n;
  if (blk < 20)      { src = a2 + blk*320;      dst = wn + blk*320;              n = 320; }
  else if (blk < 40) { src = o2 + (blk-20)*320; dst = wn + 6400 + (blk-20)*320;  n = 320; }
  else if (blk < 46) { src = aw + (blk-40)*400; dst = wn + 12800 + (blk-40)*400; n = 400; }
  else               { src = ow + (blk-46)*400; dst = wn + 15200 + (blk-46)*400; n = 400; }
  __shared__ float sh[TPB];
  float m = -1e30f;
  for (int i = threadIdx.x; i < n; i += TPB) m = fmaxf(m, src[i]);
  sh[threadIdx.x] = m; __syncthreads();
  for (int off = TPB/2; off > 0; off >>= 1){
    if (threadIdx.x < off) sh[threadIdx.x] = fmaxf(sh[threadIdx.x], sh[threadIdx.x+off]);
    __syncthreads();
  }
  m = sh[0]; __syncthreads();
  float s = 0.f;
  for (int i = threadIdx.x; i < n; i += TPB) s += expf(src[i] - m);
  sh[threadIdx.x] = s; __syncthreads();
  for (int off = TPB/2; off > 0; off >>= 1){
    if (threadIdx.x < off) sh[threadIdx.x] += sh[threadIdx.x+off];
    __syncthreads();
  }
  float inv = 1.0f / sh[0];
  __syncthreads();
  for (int i = threadIdx.x; i < n; i += TPB) dst[i] = expf(src[i] - m) * inv;
}

// ---------------- stage 1: wave conv (128,1,719)->(128,16,688) ----------------
__global__ void k_conv_wave(const float* __restrict__ x, const float* __restrict__ ww,
                            float* __restrict__ y){
  int idx = blockIdx.x*blockDim.x + threadIdx.x;
  if (idx >= 128*16*688) return;
  int l = idx % 688; int t = idx / 688; int o = t & 15; int b = t >> 4;
  const float* xr = x + b*719 + l;
  const float* wr = ww + o*32;
  float s = 0.f;
  #pragma unroll
  for (int k = 0; k < 32; k++) s = fmaf(xr[k], wr[k], s);
  y[idx] = s;
}

// ---------------- BN stats ----------------
__global__ void k_bn_part(const float* __restrict__ y, double* __restrict__ bnp){
  int c = blockIdx.x & 15, ch = blockIdx.x >> 4;
  double s = 0.0, s2 = 0.0;
  for (int i = threadIdx.x; i < 16*688; i += TPB){
    int b = ch*16 + i/688, l = i % 688;
    float v = y[(b*16 + c)*688 + l];
    s += (double)v; s2 += (double)v * (double)v;
  }
  __shared__ double sh[TPB], sh2[TPB];
  sh[threadIdx.x] = s; sh2[threadIdx.x] = s2; __syncthreads();
  for (int off = TPB/2; off > 0; off >>= 1){
    if (threadIdx.x < off){ sh[threadIdx.x] += sh[threadIdx.x+off]; sh2[threadIdx.x] += sh2[threadIdx.x+off]; }
    __syncthreads();
  }
  if (threadIdx.x == 0){ bnp[blockIdx.x] = sh[0]; bnp[128 + blockIdx.x] = sh2[0]; }
}

__global__ void k_bn_fin(const double* __restrict__ bnp, float* __restrict__ stats){
  int c = threadIdx.x;
  if (c >= 16) return;
  double s = 0.0, s2 = 0.0;
  for (int j = 0; j < 8; j++){ s += bnp[j*16 + c]; s2 += bnp[128 + j*16 + c]; }
  double n = 128.0*688.0;
  double m = s / n;
  double var = s2 / n - m*m;
  stats[c]      = (float)m;
  stats[16 + c] = (float)(1.0 / sqrt(var + 1e-5));
}

// ---------------- fused xf+miu: y -> x_miu (128,32,171) ----------------
// xf(m) = max_{i<3} relu(bn(y[2m+i])); xmiu(l) = max_{j<3} sig(±a(xf(2l+j)-b))
__global__ void k_xmiu2(const float* __restrict__ y, const float* __restrict__ stats,
                        const float* __restrict__ g, const float* __restrict__ bb,
                        const float* __restrict__ ap, const float* __restrict__ bp,
                        const float* __restrict__ an, const float* __restrict__ bn,
                        float* __restrict__ out){
  int idx = blockIdx.x*blockDim.x + threadIdx.x;
  if (idx >= 128*32*171) return;
  int l = idx % 171; int t = idx / 171; int c = t & 31; int b = t >> 5;
  int cc = c & 15;
  float mean = stats[cc], rstd = stats[16 + cc];
  float gc = g[cc], bc = bb[cc];
  float sign = (c < 16) ? 1.f : -1.f;
  float a  = (c < 16) ? ap[cc] : an[cc];
  float bo = (c < 16) ? bp[cc] : bn[cc];
  const float* yr = y + (b*16 + cc)*688 + 4*l;
  float v[7];
  #pragma unroll
  for (int i = 0; i < 7; i++)
    v[i] = fmaxf(fmaf(gc*(yr[i] - mean), rstd, bc), 0.f);
  float m = -1e30f;
  #pragma unroll
  for (int j = 0; j < 3; j++){
    float xf = fmaxf(fmaxf(v[2*j], v[2*j+1]), v[2*j+2]);
    m = fmaxf(m, sigf(sign * a * (xf - bo)));
  }
  out[idx] = m;
}

// ---------------- staging value generators ----------------
// SMODE 0: plain copy. 1: tanh(maxpool3s2). 2: upsample2(relu(maxpool3s2)). 3: upsample2.
template<int SMODE, int LSRC, int LEFF>
__device__ __forceinline__ float stage_val(const float* __restrict__ src, int q){
  if (q < 0 || q >= LEFF) return 0.f;
  if constexpr (SMODE == 0){
    return src[q];
  } else if constexpr (SMODE == 1){
    float m = fmaxf(fmaxf(src[2*q], src[2*q+1]), src[2*q+2]);
    return tanhf(m);
  } else if constexpr (SMODE == 2){
    auto P = [&](int k){
      float m = fmaxf(fmaxf(src[2*k], src[2*k+1]), src[2*k+2]);
      return fmaxf(m, 0.f);
    };
    if (q == 0) return P(0);
    if (q == LEFF - 1) return P(LEFF/2 - 1);
    int k = q >> 1;
    return (q & 1) ? 0.75f*P(k) + 0.25f*P(k+1) : 0.25f*P(k-1) + 0.75f*P(k);
  } else {
    if (q == 0) return src[0];
    if (q == LEFF - 1) return src[LSRC - 1];
    int k = q >> 1;
    return (q & 1) ? 0.75f*src[k] + 0.25f*src[k+1] : 0.25f*src[k-1] + 0.75f*src[k];
  }
}

// ---------------- generic LDS-tiled 1D conv (kernel=3), staged input transform ----------------
template<int CIN, int LSRC, int LEFF, int COUT, int LOUT, int PAD, int ACT, int PL, int SMODE>
__global__ void __launch_bounds__(256) k_conv(const float* __restrict__ in,
                                              const float* __restrict__ w,
                                              const float* __restrict__ bias,
                                              float* __restrict__ outp){
  constexpr int LSEG = 4*PL;
  constexpr int WL = ((LSEG + 2) + 3) & ~3;
  constexpr int K3 = CIN*3;
  __shared__ float smem[CIN*WL + 8 + K3*COUT];
  float* sin = smem;
  float* wT  = smem + CIN*WL + 8;
  const int b = blockIdx.x;
  const int tid = threadIdx.x;
  const int base = blockIdx.y*LSEG - PAD;

  const float* gin = in + b*CIN*LSRC;
  for (int e = tid; e < CIN*WL; e += 256){
    int i = e / WL, c = e - i*WL;
    sin[e] = stage_val<SMODE, LSRC, LEFF>(gin + i*LSRC, base + c);
  }
  if (tid < 8) sin[CIN*WL + tid] = 0.f;
  for (int e = tid; e < K3*COUT; e += 256){
    int o = e & (COUT-1), m = e / COUT;
    wT[m*COUT + o] = w[o*K3 + m];
  }
  __syncthreads();

  const int to = tid / PL, tp = tid - (tid/PL)*PL;
  const int o0 = to*4;
  const int pl0 = 4*tp;
  float acc[4][4] = {{0,0,0,0},{0,0,0,0},{0,0,0,0},{0,0,0,0}};

  for (int i = 0; i < CIN; i++){
    const float* srow = sin + i*WL + pl0;
    float xv[6];
    *(float4*)&xv[0] = *(const float4*)srow;
    *(float2*)&xv[4] = *(const float2*)(srow + 4);
    const float* wrow = wT + (i*3)*COUT + o0;
    float wv[3][4];
    #pragma unroll
    for (int k = 0; k < 3; k++)
      *(float4*)&wv[k][0] = *(const float4*)(wrow + k*COUT);
    #pragma unroll
    for (int j = 0; j < 4; j++)
      #pragma unroll
      for (int k = 0; k < 3; k++)
        #pragma unroll
        for (int oo = 0; oo < 4; oo++)
          acc[j][oo] = fmaf(xv[j+k], wv[k][oo], acc[j][oo]);
  }

  const int pg0 = blockIdx.y*LSEG + pl0;
  float bv[4];
  #pragma unroll
  for (int oo = 0; oo < 4; oo++) bv[oo] = bias[o0 + oo];
  #pragma unroll
  for (int oo = 0; oo < 4; oo++){
    float* orow = outp + (b*COUT + o0 + oo)*LOUT;
    #pragma unroll
    for (int j = 0; j < 4; j++){
      int p = pg0 + j;
      if (p < LOUT){
        float s = acc[j][oo] + bv[oo];
        float r;
        if (ACT == ACT_TANH)      r = tanhf(s);
        else if (ACT == ACT_RELU) r = fmaxf(s, 0.f);
        else if (ACT == ACT_SIG)  r = sigf(s);
        else                      r = s;
        orow[p] = r;
      }
    }
  }
}

// ---------------- inp: fused maxpool4(h4) + segment masking -> (128,160,171) ----------------
__global__ void k_inp(const float* __restrict__ h4, const float* __restrict__ xmiu,
                      float* __restrict__ inp){
  int idx = blockIdx.x*blockDim.x + threadIdx.x;
  if (idx >= 128*32*171) return;
  int l = idx % 171; int t = idx / 171; int c = t & 31; int b = t >> 5;
  const float* hr = h4 + t*174 + l;
  float wv = fmaxf(fmaxf(hr[0], hr[1]), fmaxf(hr[2], hr[3]));
  float xm = xmiu[idx];
  float prod = wv * xm;
  const float lo[5] = {0.0f, 0.2f, 0.4f, 0.6f, 0.8f};
  const float hi[5] = {0.2f, 0.4f, 0.6f, 0.8f, 2.0f};
  float* op = inp + ((b*160) + c)*171 + l;
  #pragma unroll
  for (int s = 0; s < 5; s++){
    bool m = (wv >= lo[s]) && (wv < hi[s]);
    op[s*32*171] = m ? prod : 0.f;
  }
}

// ---------------- until -> x1 channels [40,200) ----------------
__global__ void k_until(const float* __restrict__ inp, float* __restrict__ x1){
  int idx = blockIdx.x*blockDim.x + threadIdx.x;
  if (idx >= 128*160*170) return;
  int l = idx % 170; int t = idx / 170; int c = t % 160; int b = t / 160;
  const float* xr = inp + (b*160 + c)*171;
  float runmin = xr[l];
  float outv = 0.f;
  #pragma unroll 5
  for (int d = 1; d <= 25; d++){
    float xs = (l + d < 171) ? xr[l + d] : 0.f;
    outv = fmaxf(outv, fminf(runmin, xs));
    runmin = fminf(runmin, xs);
  }
  x1[((b*200) + 40 + c)*170 + l] = outv;
}

// ---------------- logic stage 1 partials: grid (85, ch=4, v=2) ----------------
__global__ void __launch_bounds__(TPB) k_logic1p(const float* __restrict__ inp, const float* __restrict__ wn,
                                                 float* __restrict__ p1){
  int bl = blockIdx.x*TPB + threadIdx.x;
  int l = bl % 170; int b = bl / 170;
  int ch = blockIdx.y, v = blockIdx.z;
  const float* W = wn + (v ? 6400 : 0);
  float acc[20];
  #pragma unroll
  for (int o = 0; o < 20; o++) acc[o] = 0.f;
  int c0 = ch*40;
  const float* ir = inp + (b*160 + c0)*171 + l;
  for (int c = 0; c < 40; c++){
    float u0 = clip01(ir[0]);
    float u1 = clip01(ir[1]);
    float g0, g1;
    if (v){ g0 = __logf(1.f - u0 + EPSL); g1 = __logf(1.f - u1 + EPSL); }
    else  { g0 = __logf(u0 + EPSL);       g1 = __logf(u1 + EPSL); }
    const float* wc = W + 2*(c0 + c);
    #pragma unroll
    for (int o = 0; o < 20; o++)
      acc[o] = fmaf(wc[o*320], g0, fmaf(wc[o*320 + 1], g1, acc[o]));
    ir += 171;
  }
  float* pp = p1 + ((ch*128 + b)*40 + v*20)*170 + l;
  #pragma unroll
  for (int o = 0; o < 20; o++) pp[o*170] = acc[o];
}

__global__ void k_fin1(const float* __restrict__ p1, float* __restrict__ x1){
  int idx = blockIdx.x*blockDim.x + threadIdx.x;
  if (idx >= 128*40*170) return;
  int l = idx % 170; int o = (idx/170) % 40; int b = idx / (170*40);
  float s = 0.f;
  #pragma unroll
  for (int ch = 0; ch < 4; ch++) s += p1[((ch*128 + b)*40 + o)*170 + l];
  float e = __expf(s);
  float r = (o < 20) ? e : fmaxf(0.f, 1.f - e);
  x1[(b*200 + o)*170 + l] = r;
}

// ---------------- logic stage 2 partials ----------------
__global__ void __launch_bounds__(TPB) k_logic2p(const float* __restrict__ x1, const float* __restrict__ wn,
                                                 float* __restrict__ p2){
  int bl = blockIdx.x*TPB + threadIdx.x;
  int l = bl % 170; int b = bl / 170;
  int ch = blockIdx.y, v = blockIdx.z;
  const float* W = wn + 12800 + (v ? 2400 : 0);
  float acc[6] = {0.f,0.f,0.f,0.f,0.f,0.f};
  int c0 = ch*50;
  const float* xr = x1 + (b*200 + c0)*170 + l;
  for (int c = 0; c < 50; c++){
    float g0 = 0.f;
    if (l > 0){
      float u0 = clip01(xr[-1]);
      g0 = v ? __logf(1.f - u0 + EPSL) : __logf(u0 + EPSL);
    }
    float u1 = clip01(xr[0]);
    float g1 = v ? __logf(1.f - u1 + EPSL) : __logf(u1 + EPSL);
    const float* wc = W + 2*(c0 + c);
    #pragma unroll
    for (int o = 0; o < 6; o++)
      acc[o] = fmaf(wc[o*400], g0, fmaf(wc[o*400 + 1], g1, acc[o]));
    xr += 170;
  }
  float* pp = p2 + ((ch*128 + b)*12 + v*6)*170 + l;
  #pragma unroll
  for (int o = 0; o < 6; o++) pp[o*170] = acc[o];
}

// ---------------- prep: fin2 (x2 padded to 192) + fc1_w pad, one kernel ----------------
__global__ void k_prep(const float* __restrict__ p2, const float* __restrict__ w,
                       float* __restrict__ x2p, float* __restrict__ wp){
  int idx = blockIdx.x*blockDim.x + threadIdx.x;
  if (idx < 1024*192){
    int k = idx % 192; int o = idx / 192;
    wp[idx] = (k < 170) ? w[o*170 + k] : 0.f;
    return;
  }
  idx -= 1024*192;
  if (idx >= 128*12*192) return;
  int l = idx % 192; int ro = idx / 192;
  if (l >= 170){ x2p[ro*192 + l] = 0.f; return; }
  int o = ro % 12; int b = ro / 12;
  float s = 0.f;
  #pragma unroll
  for (int ch = 0; ch < 4; ch++) s += p2[((ch*128 + b)*12 + o)*170 + l];
  float e = __expf(s);
  float r = (o < 6) ? e : fmaxf(0.f, 1.f - e);
  x2p[ro*192 + l] = r;
}

// ---------------- pipelined tiled GEMM: partials of A[M][K] · W[N][K]^T ----------------
template<int M, int N, int K, int KSPLIT>
__global__ void __launch_bounds__(256) k_gemm(const float* __restrict__ A,
                                              const float* __restrict__ W,
                                              float* __restrict__ C){
  static_assert(K % (KSPLIT*32) == 0, "K split");
  constexpr int KC = K / KSPLIT;
  constexpr int NT = KC / 32;
  constexpr int S = 68;
  __shared__ float As[2][32*S];
  __shared__ float Bs[2][32*S];
  const int m0 = blockIdx.x*64, n0 = blockIdx.y*64;
  const int kbeg = blockIdx.z*KC;
  const int tid = threadIdx.x;
  const int row = tid >> 2;
  const int c4  = (tid & 3)*4;
  const int tm  = (tid & 15)*4;
  const int tn  = (tid >> 4)*4;

  const float* Ar = A + (m0 + row)*K + kbeg + c4;
  const float* Wr = W + (n0 + row)*K + kbeg + c4;

  float4 ra0 = *(const float4*)(Ar);
  float4 ra1 = *(const float4*)(Ar + 16);
  float4 rb0 = *(const float4*)(Wr);
  float4 rb1 = *(const float4*)(Wr + 16);

  float acc[4][4] = {{0,0,0,0},{0,0,0,0},{0,0,0,0},{0,0,0,0}};
  int buf = 0;
  {
    float* a = As[0]; float* b = Bs[0];
    #pragma unroll
    for (int i = 0; i < 4; i++){
      a[(c4 + i)*S + row]      = ((const float*)&ra0)[i];
      a[(c4 + 16 + i)*S + row] = ((const float*)&ra1)[i];
      b[(c4 + i)*S + row]      = ((const float*)&rb0)[i];
      b[(c4 + 16 + i)*S + row] = ((const float*)&rb1)[i];
    }
  }
  __syncthreads();

  for (int t = 0; t < NT; t++){
    if (t + 1 < NT){
      Ar += 32; Wr += 32;
      ra0 = *(const float4*)(Ar);
      ra1 = *(const float4*)(Ar + 16);
      rb0 = *(const float4*)(Wr);
      rb1 = *(const float4*)(Wr + 16);
    }
    const float* a = As[buf]; const float* b = Bs[buf];
    #pragma unroll
    for (int k = 0; k < 32; k++){
      const float4 av = *(const float4*)(a + k*S + tm);
      const float4 bv = *(const float4*)(b + k*S + tn);
      acc[0][0] = fmaf(av.x, bv.x, acc[0][0]); acc[0][1] = fmaf(av.x, bv.y, acc[0][1]);
      acc[0][2] = fmaf(av.x, bv.z, acc[0][2]); acc[0][3] = fmaf(av.x, bv.w, acc[0][3]);
      acc[1][0] = fmaf(av.y, bv.x, acc[1][0]); acc[1][1] = fmaf(av.y, bv.y, acc[1][1]);
      acc[1][2] = fmaf(av.y, bv.z, acc[1][2]); acc[1][3] = fmaf(av.y, bv.w, acc[1][3]);
      acc[2][0] = fmaf(av.z, bv.x, acc[2][0]); acc[2][1] = fmaf(av.z, bv.y, acc[2][1]);
      acc[2][2] = fmaf(av.z, bv.z, acc[2][2]); acc[2][3] = fmaf(av.z, bv.w, acc[2][3]);
      acc[3][0] = fmaf(av.w, bv.x, acc[3][0]); acc[3][1] = fmaf(av.w, bv.y, acc[3][1]);
      acc[3][2] = fmaf(av.w, bv.z, acc[3][2]); acc[3][3] = fmaf(av.w, bv.w, acc[3][3]);
    }
    if (t + 1 < NT){
      int nb = buf ^ 1;
      float* an = As[nb]; float* bn = Bs[nb];
      #pragma unroll
      for (int i = 0; i < 4; i++){
        an[(c4 + i)*S + row]      = ((const float*)&ra0)[i];
        an[(c4 + 16 + i)*S + row] = ((const float*)&ra1)[i];
        bn[(c4 + i)*S + row]      = ((const float*)&rb0)[i];
        bn[(c4 + 16 + i)*S + row] = ((const float*)&rb1)[i];
      }
      __syncthreads();
      buf = nb;
    }
  }

  float* Cz = C + (size_t)blockIdx.z*M*N;
  #pragma unroll
  for (int i = 0; i < 4; i++){
    float4 v = {acc[i][0], acc[i][1], acc[i][2], acc[i][3]};
    *(float4*)&Cz[(m0 + tm + i)*N + n0 + tn] = v;
  }
}

// ---------------- combine K-split partials + bias + relu ----------------
template<int MN, int N, int KS>
__global__ void k_comb(const float* __restrict__ part, const float* __restrict__ bias,
                       float* __restrict__ out){
  int idx = blockIdx.x*blockDim.x + threadIdx.x;
  if (idx >= MN) return;
  int n = idx % N;
  float s = bias[n];
  #pragma unroll
  for (int z = 0; z < KS; z++) s += part[(size_t)z*MN + idx];
  out[idx] = fmaxf(s, 0.f);
}

// ---------------- tail: fc2 combine(8) + bias + relu + fc3 -> out (1536,10) ----------------
__global__ void __launch_bounds__(256) k_tail(const float* __restrict__ gp,
                                              const float* __restrict__ b2,
                                              const float* __restrict__ w3,
                                              const float* __restrict__ b3,
                                              float* __restrict__ out){
  constexpr int MN = 1536*256;
  __shared__ float sh[256];
  __shared__ float ps[160];
  const int row = blockIdx.x;
  const int t = threadIdx.x;
  float s = b2[t];
  #pragma unroll
  for (int z = 0; z < 8; z++) s += gp[(size_t)z*MN + row*256 + t];
  sh[t] = fmaxf(s, 0.f);
  __syncthreads();
  if (t < 160){
    int q = t >> 4, j = t & 15;
    const float* wr = w3 + q*256 + j*16;
    const float* hr = sh + j*16;
    float p = 0.f;
    #pragma unroll
    for (int i = 0; i < 16; i++) p = fmaf(hr[i], wr[i], p);
    ps[t] = p;
  }
  __syncthreads();
  if (t < 10){
    float s3 = b3[t];
    #pragma unroll
    for (int j = 0; j < 16; j++) s3 += ps[t*16 + j];
    out[row*10 + t] = s3;
  }
}

extern "C" void kernel_launch(void* const* d_in, const int* in_sizes, int n_in,
                              void* d_out, int out_size, void* d_ws, size_t ws_size,
                              hipStream_t stream) {
  const float* x      = (const float*)d_in[0];
  const float* wave_w = (const float*)d_in[1];
  const float* bn_g   = (const float*)d_in[2];
  const float* bn_b   = (const float*)d_in[3];
  const float* miu_ap = (const float*)d_in[4];
  const float* miu_bp = (const float*)d_in[5];
  const float* miu_an = (const float*)d_in[6];
  const float* miu_bn = (const float*)d_in[7];
  const float* ae_w1  = (const float*)d_in[8];
  const float* ae_b1  = (const float*)d_in[9];
  const float* ae_w2  = (const float*)d_in[10];
  const float* ae_b2  = (const float*)d_in[11];
  const float* ae_w3  = (const float*)d_in[12];
  const float* ae_b3  = (const float*)d_in[13];
  const float* ae_w4  = (const float*)d_in[14];
  const float* ae_b4  = (const float*)d_in[15];
  const float* and2_w = (const float*)d_in[16];
  const float* or2_w  = (const float*)d_in[17];
  const float* and_w  = (const float*)d_in[18];
  const float* or_w   = (const float*)d_in[19];
  const float* fc1_w  = (const float*)d_in[20];
  const float* fc1_b  = (const float*)d_in[21];
  const float* fc2_w  = (const float*)d_in[22];
  const float* fc2_b  = (const float*)d_in[23];
  const float* fc3_w  = (const float*)d_in[24];
  const float* fc3_b  = (const float*)d_in[25];
  float* out = (float*)d_out;
  float* ws  = (float*)d_ws;

  float* y1    = ws + OFF_Y1;
  float* xmiu  = ws + OFF_XMIU;
  float* c1    = ws + OFF_H1;            // conv1 raw (1400832)
  float* c2    = ws + OFF_XF;            // conv2 raw (348160)
  float* h3    = ws + OFF_Y1;            // tanh out (704512), y1 dead after xmiu2
  float* h4    = ws + OFF_H1;            // sig out (712704), c1 dead after conv2
  float* inp   = ws + OFF_INP;
  float* x1    = ws + OFF_X1;
  float* p1    = ws + OFF_P1;
  float* p2    = ws + OFF_P2;
  float* gp    = ws + OFF_GP;
  float* x2p   = ws + OFF_X2P;
  float* w1p   = ws + OFF_W1P;
  float* fc1h  = ws + OFF_FC1H;
  float* stats = ws + OFF_STATS;
  double* bnp  = (double*)(ws + OFF_BNP);
  float* wn    = ws + OFF_WN;

  k_softmax  <<<52, TPB, 0, stream>>>(and2_w, or2_w, and_w, or_w, wn);
  k_conv_wave<<<cdiv(128*16*688, TPB), TPB, 0, stream>>>(x, wave_w, y1);
  k_bn_part  <<<128, TPB, 0, stream>>>(y1, bnp);
  k_bn_fin   <<<1, 64, 0, stream>>>(bnp, stats);
  k_xmiu2    <<<cdiv(128*32*171, TPB), TPB, 0, stream>>>(y1, stats, bn_g, bn_b,
                                                         miu_ap, miu_bp, miu_an, miu_bn, xmiu);

  // AE stack: conv1 raw -> conv2 (stages tanh∘pool) raw -> conv3 (stages up∘relu∘pool) tanh
  //           -> conv4 (stages up) sigmoid
  k_conv<32,171,171,64,171,1,ACT_NONE,16,0><<<dim3(128,3), 256, 0, stream>>>(xmiu, ae_w1, ae_b1, c1);
  k_conv<64,171, 85,32, 85,1,ACT_NONE,32,1><<<dim3(128,1), 256, 0, stream>>>(c1, ae_w2, ae_b2, c2);
  k_conv<32, 85, 84,64, 86,2,ACT_TANH,16,2><<<dim3(128,2), 256, 0, stream>>>(c2, ae_w3, ae_b3, h3);
  k_conv<64, 86,172,32,174,2,ACT_SIG ,32,3><<<dim3(128,2), 256, 0, stream>>>(h3, ae_w4, ae_b4, h4);

  k_inp      <<<cdiv(128*32*171, TPB), TPB, 0, stream>>>(h4, xmiu, inp);
  k_until    <<<cdiv(128*160*170,TPB), TPB, 0, stream>>>(inp, x1);
  k_logic1p  <<<dim3(85, 4, 2), TPB, 0, stream>>>(inp, wn, p1);
  k_fin1     <<<cdiv(128*40*170, TPB), TPB, 0, stream>>>(p1, x1);
  k_logic2p  <<<dim3(85, 4, 2), TPB, 0, stream>>>(x1, wn, p2);
  k_prep     <<<cdiv(1024*192 + 128*12*192, TPB), TPB, 0, stream>>>(p2, fc1_w, x2p, w1p);

  k_gemm<1536,1024,192,2><<<dim3(24,16,2), 256, 0, stream>>>(x2p, w1p, gp);
  k_comb<1536*1024,1024,2><<<cdiv(1536*1024, TPB), TPB, 0, stream>>>(gp, fc1_b, fc1h);
  k_gemm<1536,256,1024,8><<<dim3(24,4,8), 256, 0, stream>>>(fc1h, fc2_w, gp);
  k_tail     <<<1536, 256, 0, stream>>>(gp, fc2_b, fc3_w, fc3_b, out);
}

// Round 8
// 345.046 us; speedup vs baseline: 2.5368x; 1.0395x over previous
//
#include <hip/hip_runtime.h>

#define TPB 256
static inline int cdiv(int a, int b){ return (a + b - 1) / b; }

#define EPSL 1e-6f
#define ACT_TANH 0
#define ACT_RELU 1
#define ACT_SIG  2
#define ACT_NONE 3

__device__ __forceinline__ float sigf(float x){ return 1.0f / (1.0f + __expf(-x)); }
__device__ __forceinline__ float clip01(float x){ return fminf(fmaxf(x, 0.f), 1.f); }

// ---------------- workspace layout (float offsets) ----------------
#define OFF_Y1   0
#define OFF_XF   1409024
#define OFF_XMIU 2111488
#define OFF_H1   2811904
#define OFF_INP  4384768
#define OFF_X1   7886848
#define OFF_TAIL 12238848
// liveness: y1@Y1 -> xmiu@XMIU -> c1@H1 -> c2@XF -> h3@Y1 -> h4@H1 -> inp@INP
// p1@0 (3481600; y1/c2/xmiu/c1/h3/h4 all dead when written)
// p2 @ INP+400000 (1044480; inp dead; clear of x2p)
// x2p @ INP (294912); gp@0 (4*1536*256=1572864; p1 dead after logic2p)
// fc1h @ X1 (x1 dead after logic2p); w1p in tail region after wn
#define OFF_P1   0
#define OFF_P2   (OFF_INP + 400000)
#define OFF_GP   0
#define OFF_X2P  OFF_INP
#define OFF_FC1H OFF_X1
#define OFF_STATS OFF_TAIL
#define OFF_BNP  (OFF_TAIL + 64)
#define OFF_WN   (OFF_TAIL + 64 + 512)
#define OFF_W1P  (OFF_TAIL + 64 + 512 + 17600)

// ---------------- misc: softmax(52) + conv_wave(5504) + fc1 wpad(768) ----------------
// wn layout: [0,6400) and2; [6400,12800) or2; [12800,15200) and; [15200,17600) or
__global__ void __launch_bounds__(TPB) k_misc(const float* __restrict__ a2, const float* __restrict__ o2,
                     const float* __restrict__ aw, const float* __restrict__ ow,
                     float* __restrict__ wn,
                     const float* __restrict__ x, const float* __restrict__ ww,
                     float* __restrict__ y,
                     const float* __restrict__ w1, float* __restrict__ wp){
  int bid = blockIdx.x;
  if (bid < 52){
    const float* src; float* dst; int n;
    if (bid < 20)      { src = a2 + bid*320;      dst = wn + bid*320;              n = 320; }
    else if (bid < 40) { src = o2 + (bid-20)*320; dst = wn + 6400 + (bid-20)*320;  n = 320; }
    else if (bid < 46) { src = aw + (bid-40)*400; dst = wn + 12800 + (bid-40)*400; n = 400; }
    else               { src = ow + (bid-46)*400; dst = wn + 15200 + (bid-46)*400; n = 400; }
    __shared__ float sh[TPB];
    float m = -1e30f;
    for (int i = threadIdx.x; i < n; i += TPB) m = fmaxf(m, src[i]);
    sh[threadIdx.x] = m; __syncthreads();
    for (int off = TPB/2; off > 0; off >>= 1){
      if (threadIdx.x < off) sh[threadIdx.x] = fmaxf(sh[threadIdx.x], sh[threadIdx.x+off]);
      __syncthreads();
    }
    m = sh[0]; __syncthreads();
    float s = 0.f;
    for (int i = threadIdx.x; i < n; i += TPB) s += expf(src[i] - m);
    sh[threadIdx.x] = s; __syncthreads();
    for (int off = TPB/2; off > 0; off >>= 1){
      if (threadIdx.x < off) sh[threadIdx.x] += sh[threadIdx.x+off];
      __syncthreads();
    }
    float inv = 1.0f / sh[0];
    __syncthreads();
    for (int i = threadIdx.x; i < n; i += TPB) dst[i] = expf(src[i] - m) * inv;
  } else if (bid < 52 + 5504){
    int idx = (bid - 52)*TPB + threadIdx.x;
    int l = idx % 688; int t = idx / 688; int o = t & 15; int b = t >> 4;
    const float* xr = x + b*719 + l;
    const float* wr = ww + o*32;
    float s = 0.f;
    #pragma unroll
    for (int k = 0; k < 32; k++) s = fmaf(xr[k], wr[k], s);
    y[idx] = s;
  } else {
    int idx = (bid - 5556)*TPB + threadIdx.x;     // 1024*192 = 196608
    int k = idx % 192; int o = idx / 192;
    wp[idx] = (k < 170) ? w1[o*170 + k] : 0.f;
  }
}

// ---------------- BN stats partials ----------------
__global__ void k_bn_part(const float* __restrict__ y, double* __restrict__ bnp){
  int c = blockIdx.x & 15, ch = blockIdx.x >> 4;
  double s = 0.0, s2 = 0.0;
  for (int i = threadIdx.x; i < 16*688; i += TPB){
    int b = ch*16 + i/688, l = i % 688;
    float v = y[(b*16 + c)*688 + l];
    s += (double)v; s2 += (double)v * (double)v;
  }
  __shared__ double sh[TPB], sh2[TPB];
  sh[threadIdx.x] = s; sh2[threadIdx.x] = s2; __syncthreads();
  for (int off = TPB/2; off > 0; off >>= 1){
    if (threadIdx.x < off){ sh[threadIdx.x] += sh[threadIdx.x+off]; sh2[threadIdx.x] += sh2[threadIdx.x+off]; }
    __syncthreads();
  }
  if (threadIdx.x == 0){ bnp[blockIdx.x] = sh[0]; bnp[128 + blockIdx.x] = sh2[0]; }
}

// ---------------- fused bn-finalize + xf + miu: y -> x_miu (128,32,171) ----------------
__global__ void k_xmiu2(const float* __restrict__ y, const double* __restrict__ bnp,
                        const float* __restrict__ g, const float* __restrict__ bb,
                        const float* __restrict__ ap, const float* __restrict__ bp,
                        const float* __restrict__ an, const float* __restrict__ bn,
                        float* __restrict__ out){
  __shared__ float smean[16], srstd[16];
  if (threadIdx.x < 16){
    int cc = threadIdx.x;
    double s = 0.0, s2 = 0.0;
    #pragma unroll
    for (int j = 0; j < 8; j++){ s += bnp[j*16 + cc]; s2 += bnp[128 + j*16 + cc]; }
    double n = 128.0*688.0;
    double m = s / n;
    double var = s2 / n - m*m;
    smean[cc] = (float)m;
    srstd[cc] = (float)(1.0 / sqrt(var + 1e-5));
  }
  __syncthreads();
  int idx = blockIdx.x*blockDim.x + threadIdx.x;
  if (idx >= 128*32*171) return;
  int l = idx % 171; int t = idx / 171; int c = t & 31; int b = t >> 5;
  int cc = c & 15;
  float mean = smean[cc], rstd = srstd[cc];
  float gc = g[cc], bc = bb[cc];
  float sign = (c < 16) ? 1.f : -1.f;
  float a  = (c < 16) ? ap[cc] : an[cc];
  float bo = (c < 16) ? bp[cc] : bn[cc];
  const float* yr = y + (b*16 + cc)*688 + 4*l;
  float v[7];
  #pragma unroll
  for (int i = 0; i < 7; i++)
    v[i] = fmaxf(fmaf(gc*(yr[i] - mean), rstd, bc), 0.f);
  float m = -1e30f;
  #pragma unroll
  for (int j = 0; j < 3; j++){
    float xf = fmaxf(fmaxf(v[2*j], v[2*j+1]), v[2*j+2]);
    m = fmaxf(m, sigf(sign * a * (xf - bo)));
  }
  out[idx] = m;
}

// ---------------- staging value generators ----------------
template<int SMODE, int LSRC, int LEFF>
__device__ __forceinline__ float stage_val(const float* __restrict__ src, int q){
  if (q < 0 || q >= LEFF) return 0.f;
  if constexpr (SMODE == 0){
    return src[q];
  } else if constexpr (SMODE == 1){
    float m = fmaxf(fmaxf(src[2*q], src[2*q+1]), src[2*q+2]);
    return tanhf(m);
  } else if constexpr (SMODE == 2){
    auto P = [&](int k){
      float m = fmaxf(fmaxf(src[2*k], src[2*k+1]), src[2*k+2]);
      return fmaxf(m, 0.f);
    };
    if (q == 0) return P(0);
    if (q == LEFF - 1) return P(LEFF/2 - 1);
    int k = q >> 1;
    return (q & 1) ? 0.75f*P(k) + 0.25f*P(k+1) : 0.25f*P(k-1) + 0.75f*P(k);
  } else {
    if (q == 0) return src[0];
    if (q == LEFF - 1) return src[LSRC - 1];
    int k = q >> 1;
    return (q & 1) ? 0.75f*src[k] + 0.25f*src[k+1] : 0.25f*src[k-1] + 0.75f*src[k];
  }
}

// ---------------- generic LDS-tiled 1D conv (kernel=3), staged input transform ----------------
template<int CIN, int LSRC, int LEFF, int COUT, int LOUT, int PAD, int ACT, int PL, int SMODE>
__global__ void __launch_bounds__(256) k_conv(const float* __restrict__ in,
                                              const float* __restrict__ w,
                                              const float* __restrict__ bias,
                                              float* __restrict__ outp){
  constexpr int LSEG = 4*PL;
  constexpr int WL = ((LSEG + 2) + 3) & ~3;
  constexpr int K3 = CIN*3;
  __shared__ float smem[CIN*WL + 8 + K3*COUT];
  float* sin = smem;
  float* wT  = smem + CIN*WL + 8;
  const int b = blockIdx.x;
  const int tid = threadIdx.x;
  const int base = blockIdx.y*LSEG - PAD;

  const float* gin = in + b*CIN*LSRC;
  for (int e = tid; e < CIN*WL; e += 256){
    int i = e / WL, c = e - i*WL;
    sin[e] = stage_val<SMODE, LSRC, LEFF>(gin + i*LSRC, base + c);
  }
  if (tid < 8) sin[CIN*WL + tid] = 0.f;
  for (int e = tid; e < K3*COUT; e += 256){
    int o = e & (COUT-1), m = e / COUT;
    wT[m*COUT + o] = w[o*K3 + m];
  }
  __syncthreads();

  const int to = tid / PL, tp = tid - (tid/PL)*PL;
  const int o0 = to*4;
  const int pl0 = 4*tp;
  float acc[4][4] = {{0,0,0,0},{0,0,0,0},{0,0,0,0},{0,0,0,0}};

  for (int i = 0; i < CIN; i++){
    const float* srow = sin + i*WL + pl0;
    float xv[6];
    *(float4*)&xv[0] = *(const float4*)srow;
    *(float2*)&xv[4] = *(const float2*)(srow + 4);
    const float* wrow = wT + (i*3)*COUT + o0;
    float wv[3][4];
    #pragma unroll
    for (int k = 0; k < 3; k++)
      *(float4*)&wv[k][0] = *(const float4*)(wrow + k*COUT);
    #pragma unroll
    for (int j = 0; j < 4; j++)
      #pragma unroll
      for (int k = 0; k < 3; k++)
        #pragma unroll
        for (int oo = 0; oo < 4; oo++)
          acc[j][oo] = fmaf(xv[j+k], wv[k][oo], acc[j][oo]);
  }

  const int pg0 = blockIdx.y*LSEG + pl0;
  float bv[4];
  #pragma unroll
  for (int oo = 0; oo < 4; oo++) bv[oo] = bias[o0 + oo];
  #pragma unroll
  for (int oo = 0; oo < 4; oo++){
    float* orow = outp + (b*COUT + o0 + oo)*LOUT;
    #pragma unroll
    for (int j = 0; j < 4; j++){
      int p = pg0 + j;
      if (p < LOUT){
        float s = acc[j][oo] + bv[oo];
        float r;
        if (ACT == ACT_TANH)      r = tanhf(s);
        else if (ACT == ACT_RELU) r = fmaxf(s, 0.f);
        else if (ACT == ACT_SIG)  r = sigf(s);
        else                      r = s;
        orow[p] = r;
      }
    }
  }
}

// ---------------- inp: fused maxpool4(h4) + segment masking -> (128,160,171) ----------------
__global__ void k_inp(const float* __restrict__ h4, const float* __restrict__ xmiu,
                      float* __restrict__ inp){
  int idx = blockIdx.x*blockDim.x + threadIdx.x;
  if (idx >= 128*32*171) return;
  int l = idx % 171; int t = idx / 171; int c = t & 31; int b = t >> 5;
  const float* hr = h4 + t*174 + l;
  float wv = fmaxf(fmaxf(hr[0], hr[1]), fmaxf(hr[2], hr[3]));
  float xm = xmiu[idx];
  float prod = wv * xm;
  const float lo[5] = {0.0f, 0.2f, 0.4f, 0.6f, 0.8f};
  const float hi[5] = {0.2f, 0.4f, 0.6f, 0.8f, 2.0f};
  float* op = inp + ((b*160) + c)*171 + l;
  #pragma unroll
  for (int s = 0; s < 5; s++){
    bool m = (wv >= lo[s]) && (wv < hi[s]);
    op[s*32*171] = m ? prod : 0.f;
  }
}

// ---------------- fused until (blocks 0..13599) + logic1 partials (13600..14279) ----------------
__global__ void __launch_bounds__(TPB) k_ul1(const float* __restrict__ inp, const float* __restrict__ wn,
                                             float* __restrict__ x1, float* __restrict__ p1){
  int bid = blockIdx.x;
  if (bid < 13600){
    int idx = bid*TPB + threadIdx.x;             // 128*160*170 exactly
    int l = idx % 170; int t = idx / 170; int c = t % 160; int b = t / 160;
    const float* xr = inp + (b*160 + c)*171;
    float runmin = xr[l];
    float outv = 0.f;
    #pragma unroll 5
    for (int d = 1; d <= 25; d++){
      float xs = (l + d < 171) ? xr[l + d] : 0.f;
      outv = fmaxf(outv, fminf(runmin, xs));
      runmin = fminf(runmin, xs);
    }
    x1[((b*200) + 40 + c)*170 + l] = outv;
  } else {
    int r = bid - 13600;                          // (85, ch=4, v=2)
    int xb = r % 85; int rr = r / 85; int ch = rr & 3; int v = rr >> 2;
    int bl = xb*TPB + threadIdx.x;
    int l = bl % 170; int b = bl / 170;
    const float* W = wn + (v ? 6400 : 0);
    float acc[20];
    #pragma unroll
    for (int o = 0; o < 20; o++) acc[o] = 0.f;
    int c0 = ch*40;
    const float* ir = inp + (b*160 + c0)*171 + l;
    for (int c = 0; c < 40; c++){
      float u0 = clip01(ir[0]);
      float u1 = clip01(ir[1]);
      float g0, g1;
      if (v){ g0 = __logf(1.f - u0 + EPSL); g1 = __logf(1.f - u1 + EPSL); }
      else  { g0 = __logf(u0 + EPSL);       g1 = __logf(u1 + EPSL); }
      const float* wc = W + 2*(c0 + c);
      #pragma unroll
      for (int o = 0; o < 20; o++)
        acc[o] = fmaf(wc[o*320], g0, fmaf(wc[o*320 + 1], g1, acc[o]));
      ir += 171;
    }
    float* pp = p1 + ((ch*128 + b)*40 + v*20)*170 + l;
    #pragma unroll
    for (int o = 0; o < 20; o++) pp[o*170] = acc[o];
  }
}

// ---------------- logic stage 2 partials; logic1 channels computed inline from p1 ----------------
__global__ void __launch_bounds__(TPB) k_logic2p(const float* __restrict__ x1, const float* __restrict__ p1,
                                                 const float* __restrict__ wn, float* __restrict__ p2){
  int bl = blockIdx.x*TPB + threadIdx.x;
  int l = bl % 170; int b = bl / 170;
  int ch = blockIdx.y, v = blockIdx.z;
  const float* W = wn + 12800 + (v ? 2400 : 0);
  float acc[6] = {0.f,0.f,0.f,0.f,0.f,0.f};
  int c0 = ch*50;
  bool have0 = (l > 0);
  for (int c = c0; c < c0 + 50; c++){
    float u0 = 0.f, u1;
    if (c < 40){                                  // logic1 channel (only ch==0 blocks)
      float s1 = 0.f;
      #pragma unroll
      for (int q = 0; q < 4; q++) s1 += p1[((q*128 + b)*40 + c)*170 + l];
      float e = __expf(s1);
      u1 = (c < 20) ? e : fmaxf(0.f, 1.f - e);
      if (have0){
        float s0 = 0.f;
        #pragma unroll
        for (int q = 0; q < 4; q++) s0 += p1[((q*128 + b)*40 + c)*170 + l - 1];
        float e0 = __expf(s0);
        u0 = (c < 20) ? e0 : fmaxf(0.f, 1.f - e0);
      }
    } else {
      const float* xr = x1 + (b*200 + c)*170 + l;
      u1 = xr[0];
      if (have0) u0 = xr[-1];
    }
    float g0 = 0.f;
    if (have0){
      float uc = clip01(u0);
      g0 = v ? __logf(1.f - uc + EPSL) : __logf(uc + EPSL);
    }
    float uc1 = clip01(u1);
    float g1 = v ? __logf(1.f - uc1 + EPSL) : __logf(uc1 + EPSL);
    const float* wc = W + 2*c;
    #pragma unroll
    for (int o = 0; o < 6; o++)
      acc[o] = fmaf(wc[o*400], g0, fmaf(wc[o*400 + 1], g1, acc[o]));
  }
  float* pp = p2 + ((ch*128 + b)*12 + v*6)*170 + l;
  #pragma unroll
  for (int o = 0; o < 6; o++) pp[o*170] = acc[o];
}

// ---------------- fin2: combine p2 -> x2 padded to K=192 ----------------
__global__ void k_fin2(const float* __restrict__ p2, float* __restrict__ x2p){
  int idx = blockIdx.x*blockDim.x + threadIdx.x;
  if (idx >= 128*12*192) return;
  int l = idx % 192; int ro = idx / 192;
  if (l >= 170){ x2p[ro*192 + l] = 0.f; return; }
  int o = ro % 12; int b = ro / 12;
  float s = 0.f;
  #pragma unroll
  for (int ch = 0; ch < 4; ch++) s += p2[((ch*128 + b)*12 + o)*170 + l];
  float e = __expf(s);
  float r = (o < 6) ? e : fmaxf(0.f, 1.f - e);
  x2p[ro*192 + l] = r;
}

// ---------------- pipelined tiled GEMM ----------------
// KSPLIT==1: C = act(A·W^T + bias) [M][N].  KSPLIT>1: partials C[z][M][N] (bias unused).
template<int M, int N, int K, int KSPLIT, int ACT>
__global__ void __launch_bounds__(256) k_gemm(const float* __restrict__ A,
                                              const float* __restrict__ W,
                                              const float* __restrict__ bias,
                                              float* __restrict__ C){
  static_assert(K % (KSPLIT*32) == 0, "K split");
  constexpr int KC = K / KSPLIT;
  constexpr int NT = KC / 32;
  constexpr int S = 68;
  __shared__ float As[2][32*S];
  __shared__ float Bs[2][32*S];
  const int m0 = blockIdx.x*64, n0 = blockIdx.y*64;
  const int kbeg = blockIdx.z*KC;
  const int tid = threadIdx.x;
  const int row = tid >> 2;
  const int c4  = (tid & 3)*4;
  const int tm  = (tid & 15)*4;
  const int tn  = (tid >> 4)*4;

  const float* Ar = A + (m0 + row)*K + kbeg + c4;
  const float* Wr = W + (n0 + row)*K + kbeg + c4;

  float4 ra0 = *(const float4*)(Ar);
  float4 ra1 = *(const float4*)(Ar + 16);
  float4 rb0 = *(const float4*)(Wr);
  float4 rb1 = *(const float4*)(Wr + 16);

  float acc[4][4] = {{0,0,0,0},{0,0,0,0},{0,0,0,0},{0,0,0,0}};
  int buf = 0;
  {
    float* a = As[0]; float* b = Bs[0];
    #pragma unroll
    for (int i = 0; i < 4; i++){
      a[(c4 + i)*S + row]      = ((const float*)&ra0)[i];
      a[(c4 + 16 + i)*S + row] = ((const float*)&ra1)[i];
      b[(c4 + i)*S + row]      = ((const float*)&rb0)[i];
      b[(c4 + 16 + i)*S + row] = ((const float*)&rb1)[i];
    }
  }
  __syncthreads();

  for (int t = 0; t < NT; t++){
    if (t + 1 < NT){
      Ar += 32; Wr += 32;
      ra0 = *(const float4*)(Ar);
      ra1 = *(const float4*)(Ar + 16);
      rb0 = *(const float4*)(Wr);
      rb1 = *(const float4*)(Wr + 16);
    }
    const float* a = As[buf]; const float* b = Bs[buf];
    #pragma unroll
    for (int k = 0; k < 32; k++){
      const float4 av = *(const float4*)(a + k*S + tm);
      const float4 bv = *(const float4*)(b + k*S + tn);
      acc[0][0] = fmaf(av.x, bv.x, acc[0][0]); acc[0][1] = fmaf(av.x, bv.y, acc[0][1]);
      acc[0][2] = fmaf(av.x, bv.z, acc[0][2]); acc[0][3] = fmaf(av.x, bv.w, acc[0][3]);
      acc[1][0] = fmaf(av.y, bv.x, acc[1][0]); acc[1][1] = fmaf(av.y, bv.y, acc[1][1]);
      acc[1][2] = fmaf(av.y, bv.z, acc[1][2]); acc[1][3] = fmaf(av.y, bv.w, acc[1][3]);
      acc[2][0] = fmaf(av.z, bv.x, acc[2][0]); acc[2][1] = fmaf(av.z, bv.y, acc[2][1]);
      acc[2][2] = fmaf(av.z, bv.z, acc[2][2]); acc[2][3] = fmaf(av.z, bv.w, acc[2][3]);
      acc[3][0] = fmaf(av.w, bv.x, acc[3][0]); acc[3][1] = fmaf(av.w, bv.y, acc[3][1]);
      acc[3][2] = fmaf(av.w, bv.z, acc[3][2]); acc[3][3] = fmaf(av.w, bv.w, acc[3][3]);
    }
    if (t + 1 < NT){
      int nb = buf ^ 1;
      float* an = As[nb]; float* bn = Bs[nb];
      #pragma unroll
      for (int i = 0; i < 4; i++){
        an[(c4 + i)*S + row]      = ((const float*)&ra0)[i];
        an[(c4 + 16 + i)*S + row] = ((const float*)&ra1)[i];
        bn[(c4 + i)*S + row]      = ((const float*)&rb0)[i];
        bn[(c4 + 16 + i)*S + row] = ((const float*)&rb1)[i];
      }
      __syncthreads();
      buf = nb;
    }
  }

  if (KSPLIT == 1){
    #pragma unroll
    for (int i = 0; i < 4; i++){
      float4 vv;
      vv.x = acc[i][0] + bias[n0 + tn];
      vv.y = acc[i][1] + bias[n0 + tn + 1];
      vv.z = acc[i][2] + bias[n0 + tn + 2];
      vv.w = acc[i][3] + bias[n0 + tn + 3];
      if (ACT == ACT_RELU){
        vv.x = fmaxf(vv.x, 0.f); vv.y = fmaxf(vv.y, 0.f);
        vv.z = fmaxf(vv.z, 0.f); vv.w = fmaxf(vv.w, 0.f);
      }
      *(float4*)&C[(m0 + tm + i)*N + n0 + tn] = vv;
    }
  } else {
    float* Cz = C + (size_t)blockIdx.z*M*N;
    #pragma unroll
    for (int i = 0; i < 4; i++){
      float4 vv = {acc[i][0], acc[i][1], acc[i][2], acc[i][3]};
      *(float4*)&Cz[(m0 + tm + i)*N + n0 + tn] = vv;
    }
  }
}

// ---------------- tail: fc2 combine(4) + bias + relu + fc3 -> out (1536,10) ----------------
__global__ void __launch_bounds__(256) k_tail(const float* __restrict__ gp,
                                              const float* __restrict__ b2,
                                              const float* __restrict__ w3,
                                              const float* __restrict__ b3,
                                              float* __restrict__ out){
  constexpr int MN = 1536*256;
  __shared__ float sh[256];
  __shared__ float ps[160];
  const int row = blockIdx.x;
  const int t = threadIdx.x;
  float s = b2[t];
  #pragma unroll
  for (int z = 0; z < 4; z++) s += gp[(size_t)z*MN + row*256 + t];
  sh[t] = fmaxf(s, 0.f);
  __syncthreads();
  if (t < 160){
    int q = t >> 4, j = t & 15;
    const float* wr = w3 + q*256 + j*16;
    const float* hr = sh + j*16;
    float p = 0.f;
    #pragma unroll
    for (int i = 0; i < 16; i++) p = fmaf(hr[i], wr[i], p);
    ps[t] = p;
  }
  __syncthreads();
  if (t < 10){
    float s3 = b3[t];
    #pragma unroll
    for (int j = 0; j < 16; j++) s3 += ps[t*16 + j];
    out[row*10 + t] = s3;
  }
}

extern "C" void kernel_launch(void* const* d_in, const int* in_sizes, int n_in,
                              void* d_out, int out_size, void* d_ws, size_t ws_size,
                              hipStream_t stream) {
  const float* x      = (const float*)d_in[0];
  const float* wave_w = (const float*)d_in[1];
  const float* bn_g   = (const float*)d_in[2];
  const float* bn_b   = (const float*)d_in[3];
  const float* miu_ap = (const float*)d_in[4];
  const float* miu_bp = (const float*)d_in[5];
  const float* miu_an = (const float*)d_in[6];
  const float* miu_bn = (const float*)d_in[7];
  const float* ae_w1  = (const float*)d_in[8];
  const float* ae_b1  = (const float*)d_in[9];
  const float* ae_w2  = (const float*)d_in[10];
  const float* ae_b2  = (const float*)d_in[11];
  const float* ae_w3  = (const float*)d_in[12];
  const float* ae_b3  = (const float*)d_in[13];
  const float* ae_w4  = (const float*)d_in[14];
  const float* ae_b4  = (const float*)d_in[15];
  const float* and2_w = (const float*)d_in[16];
  const float* or2_w  = (const float*)d_in[17];
  const float* and_w  = (const float*)d_in[18];
  const float* or_w   = (const float*)d_in[19];
  const float* fc1_w  = (const float*)d_in[20];
  const float* fc1_b  = (const float*)d_in[21];
  const float* fc2_w  = (const float*)d_in[22];
  const float* fc2_b  = (const float*)d_in[23];
  const float* fc3_w  = (const float*)d_in[24];
  const float* fc3_b  = (const float*)d_in[25];
  float* out = (float*)d_out;
  float* ws  = (float*)d_ws;

  float* y1    = ws + OFF_Y1;
  float* xmiu  = ws + OFF_XMIU;
  float* c1    = ws + OFF_H1;
  float* c2    = ws + OFF_XF;
  float* h3    = ws + OFF_Y1;
  float* h4    = ws + OFF_H1;
  float* inp   = ws + OFF_INP;
  float* x1    = ws + OFF_X1;
  float* p1    = ws + OFF_P1;
  float* p2    = ws + OFF_P2;
  float* gp    = ws + OFF_GP;
  float* x2p   = ws + OFF_X2P;
  float* w1p   = ws + OFF_W1P;
  float* fc1h  = ws + OFF_FC1H;
  double* bnp  = (double*)(ws + OFF_BNP);
  float* wn    = ws + OFF_WN;

  k_misc     <<<52 + 5504 + 768, TPB, 0, stream>>>(and2_w, or2_w, and_w, or_w, wn,
                                                   x, wave_w, y1, fc1_w, w1p);
  k_bn_part  <<<128, TPB, 0, stream>>>(y1, bnp);
  k_xmiu2    <<<cdiv(128*32*171, TPB), TPB, 0, stream>>>(y1, bnp, bn_g, bn_b,
                                                         miu_ap, miu_bp, miu_an, miu_bn, xmiu);

  k_conv<32,171,171,64,171,1,ACT_NONE,16,0><<<dim3(128,3), 256, 0, stream>>>(xmiu, ae_w1, ae_b1, c1);
  k_conv<64,171, 85,32, 85,1,ACT_NONE,32,1><<<dim3(128,1), 256, 0, stream>>>(c1, ae_w2, ae_b2, c2);
  k_conv<32, 85, 84,64, 86,2,ACT_TANH,16,2><<<dim3(128,2), 256, 0, stream>>>(c2, ae_w3, ae_b3, h3);
  k_conv<64, 86,172,32,174,2,ACT_SIG ,32,3><<<dim3(128,2), 256, 0, stream>>>(h3, ae_w4, ae_b4, h4);

  k_inp      <<<cdiv(128*32*171, TPB), TPB, 0, stream>>>(h4, xmiu, inp);
  k_ul1      <<<13600 + 680, TPB, 0, stream>>>(inp, wn, x1, p1);
  k_logic2p  <<<dim3(85, 4, 2), TPB, 0, stream>>>(x1, p1, wn, p2);
  k_fin2     <<<cdiv(128*12*192, TPB), TPB, 0, stream>>>(p2, x2p);

  k_gemm<1536,1024,192,1,ACT_RELU><<<dim3(24,16,1), 256, 0, stream>>>(x2p, w1p, fc1_b, fc1h);
  k_gemm<1536,256,1024,4,ACT_NONE><<<dim3(24,4,4), 256, 0, stream>>>(fc1h, fc2_w, fc2_b, gp);
  k_tail     <<<1536, 256, 0, stream>>>(gp, fc2_b, fc3_w, fc3_b, out);
}

// Round 9
// 317.185 us; speedup vs baseline: 2.7596x; 1.0878x over previous
//
#include <hip/hip_runtime.h>

#define TPB 256
static inline int cdiv(int a, int b){ return (a + b - 1) / b; }

#define EPSL 1e-6f
#define ACT_TANH 0
#define ACT_RELU 1
#define ACT_SIG  2
#define ACT_NONE 3

__device__ __forceinline__ float sigf(float x){ return 1.0f / (1.0f + __expf(-x)); }
__device__ __forceinline__ float clip01(float x){ return fminf(fmaxf(x, 0.f), 1.f); }

// ---------------- workspace layout (float offsets) ----------------
#define OFF_Y1   0
#define OFF_XF   1409024
#define OFF_XMIU 2111488
#define OFF_H1   2811904
#define OFF_INP  4384768
#define OFF_X1   7886848
#define OFF_TAIL 12238848
// p1@0 (4*128*40*170=3481600 < OFF_INP). p2 @ INP+400000 (8*128*12*170=2088960; ends 6873728 < OFF_X1).
// x2p @ INP (294912, clear of p2). gp@0 (4*1536*256=1572864; p1 dead after logic2p). fc1h @ X1.
#define OFF_P1   0
#define OFF_P2   (OFF_INP + 400000)
#define OFF_GP   0
#define OFF_X2P  OFF_INP
#define OFF_FC1H OFF_X1
#define OFF_BNP  (OFF_TAIL + 64)
#define OFF_WN   (OFF_TAIL + 64 + 512)
#define OFF_W1P  (OFF_TAIL + 64 + 512 + 17600)

// ---------------- misc: softmax(52) + conv_wave(5504) + fc1 wpad(768) ----------------
__global__ void __launch_bounds__(TPB) k_misc(const float* __restrict__ a2, const float* __restrict__ o2,
                     const float* __restrict__ aw, const float* __restrict__ ow,
                     float* __restrict__ wn,
                     const float* __restrict__ x, const float* __restrict__ ww,
                     float* __restrict__ y,
                     const float* __restrict__ w1, float* __restrict__ wp){
  int bid = blockIdx.x;
  if (bid < 52){
    const float* src; float* dst; int n;
    if (bid < 20)      { src = a2 + bid*320;      dst = wn + bid*320;              n = 320; }
    else if (bid < 40) { src = o2 + (bid-20)*320; dst = wn + 6400 + (bid-20)*320;  n = 320; }
    else if (bid < 46) { src = aw + (bid-40)*400; dst = wn + 12800 + (bid-40)*400; n = 400; }
    else               { src = ow + (bid-46)*400; dst = wn + 15200 + (bid-46)*400; n = 400; }
    __shared__ float sh[TPB];
    float m = -1e30f;
    for (int i = threadIdx.x; i < n; i += TPB) m = fmaxf(m, src[i]);
    sh[threadIdx.x] = m; __syncthreads();
    for (int off = TPB/2; off > 0; off >>= 1){
      if (threadIdx.x < off) sh[threadIdx.x] = fmaxf(sh[threadIdx.x], sh[threadIdx.x+off]);
      __syncthreads();
    }
    m = sh[0]; __syncthreads();
    float s = 0.f;
    for (int i = threadIdx.x; i < n; i += TPB) s += expf(src[i] - m);
    sh[threadIdx.x] = s; __syncthreads();
    for (int off = TPB/2; off > 0; off >>= 1){
      if (threadIdx.x < off) sh[threadIdx.x] += sh[threadIdx.x+off];
      __syncthreads();
    }
    float inv = 1.0f / sh[0];
    __syncthreads();
    for (int i = threadIdx.x; i < n; i += TPB) dst[i] = expf(src[i] - m) * inv;
  } else if (bid < 52 + 5504){
    int idx = (bid - 52)*TPB + threadIdx.x;
    int l = idx % 688; int t = idx / 688; int o = t & 15; int b = t >> 4;
    const float* xr = x + b*719 + l;
    const float* wr = ww + o*32;
    float s = 0.f;
    #pragma unroll
    for (int k = 0; k < 32; k++) s = fmaf(xr[k], wr[k], s);
    y[idx] = s;
  } else {
    int idx = (bid - 5556)*TPB + threadIdx.x;
    int k = idx % 192; int o = idx / 192;
    wp[idx] = (k < 170) ? w1[o*170 + k] : 0.f;
  }
}

// ---------------- BN stats partials ----------------
__global__ void k_bn_part(const float* __restrict__ y, double* __restrict__ bnp){
  int c = blockIdx.x & 15, ch = blockIdx.x >> 4;
  double s = 0.0, s2 = 0.0;
  for (int i = threadIdx.x; i < 16*688; i += TPB){
    int b = ch*16 + i/688, l = i % 688;
    float v = y[(b*16 + c)*688 + l];
    s += (double)v; s2 += (double)v * (double)v;
  }
  __shared__ double sh[TPB], sh2[TPB];
  sh[threadIdx.x] = s; sh2[threadIdx.x] = s2; __syncthreads();
  for (int off = TPB/2; off > 0; off >>= 1){
    if (threadIdx.x < off){ sh[threadIdx.x] += sh[threadIdx.x+off]; sh2[threadIdx.x] += sh2[threadIdx.x+off]; }
    __syncthreads();
  }
  if (threadIdx.x == 0){ bnp[blockIdx.x] = sh[0]; bnp[128 + blockIdx.x] = sh2[0]; }
}

// ---------------- fused bn-finalize + xf + miu: y -> x_miu (128,32,171) ----------------
__global__ void k_xmiu2(const float* __restrict__ y, const double* __restrict__ bnp,
                        const float* __restrict__ g, const float* __restrict__ bb,
                        const float* __restrict__ ap, const float* __restrict__ bp,
                        const float* __restrict__ an, const float* __restrict__ bn,
                        float* __restrict__ out){
  __shared__ float smean[16], srstd[16];
  if (threadIdx.x < 16){
    int cc = threadIdx.x;
    double s = 0.0, s2 = 0.0;
    #pragma unroll
    for (int j = 0; j < 8; j++){ s += bnp[j*16 + cc]; s2 += bnp[128 + j*16 + cc]; }
    double n = 128.0*688.0;
    double m = s / n;
    double var = s2 / n - m*m;
    smean[cc] = (float)m;
    srstd[cc] = (float)(1.0 / sqrt(var + 1e-5));
  }
  __syncthreads();
  int idx = blockIdx.x*blockDim.x + threadIdx.x;
  if (idx >= 128*32*171) return;
  int l = idx % 171; int t = idx / 171; int c = t & 31; int b = t >> 5;
  int cc = c & 15;
  float mean = smean[cc], rstd = srstd[cc];
  float gc = g[cc], bc = bb[cc];
  float sign = (c < 16) ? 1.f : -1.f;
  float a  = (c < 16) ? ap[cc] : an[cc];
  float bo = (c < 16) ? bp[cc] : bn[cc];
  const float* yr = y + (b*16 + cc)*688 + 4*l;
  float v[7];
  #pragma unroll
  for (int i = 0; i < 7; i++)
    v[i] = fmaxf(fmaf(gc*(yr[i] - mean), rstd, bc), 0.f);
  float m = -1e30f;
  #pragma unroll
  for (int j = 0; j < 3; j++){
    float xf = fmaxf(fmaxf(v[2*j], v[2*j+1]), v[2*j+2]);
    m = fmaxf(m, sigf(sign * a * (xf - bo)));
  }
  out[idx] = m;
}

// ---------------- staging value generators ----------------
template<int SMODE, int LSRC, int LEFF>
__device__ __forceinline__ float stage_val(const float* __restrict__ src, int q){
  if (q < 0 || q >= LEFF) return 0.f;
  if constexpr (SMODE == 0){
    return src[q];
  } else if constexpr (SMODE == 1){
    float m = fmaxf(fmaxf(src[2*q], src[2*q+1]), src[2*q+2]);
    return tanhf(m);
  } else if constexpr (SMODE == 2){
    auto P = [&](int k){
      float m = fmaxf(fmaxf(src[2*k], src[2*k+1]), src[2*k+2]);
      return fmaxf(m, 0.f);
    };
    if (q == 0) return P(0);
    if (q == LEFF - 1) return P(LEFF/2 - 1);
    int k = q >> 1;
    return (q & 1) ? 0.75f*P(k) + 0.25f*P(k+1) : 0.25f*P(k-1) + 0.75f*P(k);
  } else {
    if (q == 0) return src[0];
    if (q == LEFF - 1) return src[LSRC - 1];
    int k = q >> 1;
    return (q & 1) ? 0.75f*src[k] + 0.25f*src[k+1] : 0.25f*src[k-1] + 0.75f*src[k];
  }
}

// ---------------- generic LDS-tiled 1D conv (kernel=3), staged input transform ----------------
template<int CIN, int LSRC, int LEFF, int COUT, int LOUT, int PAD, int ACT, int PL, int SMODE>
__global__ void __launch_bounds__(256) k_conv(const float* __restrict__ in,
                                              const float* __restrict__ w,
                                              const float* __restrict__ bias,
                                              float* __restrict__ outp){
  constexpr int LSEG = 4*PL;
  constexpr int WL = ((LSEG + 2) + 3) & ~3;
  constexpr int K3 = CIN*3;
  __shared__ float smem[CIN*WL + 8 + K3*COUT];
  float* sin = smem;
  float* wT  = smem + CIN*WL + 8;
  const int b = blockIdx.x;
  const int tid = threadIdx.x;
  const int base = blockIdx.y*LSEG - PAD;

  const float* gin = in + b*CIN*LSRC;
  for (int e = tid; e < CIN*WL; e += 256){
    int i = e / WL, c = e - i*WL;
    sin[e] = stage_val<SMODE, LSRC, LEFF>(gin + i*LSRC, base + c);
  }
  if (tid < 8) sin[CIN*WL + tid] = 0.f;
  for (int e = tid; e < K3*COUT; e += 256){
    int o = e & (COUT-1), m = e / COUT;
    wT[m*COUT + o] = w[o*K3 + m];
  }
  __syncthreads();

  const int to = tid / PL, tp = tid - (tid/PL)*PL;
  const int o0 = to*4;
  const int pl0 = 4*tp;
  float acc[4][4] = {{0,0,0,0},{0,0,0,0},{0,0,0,0},{0,0,0,0}};

  for (int i = 0; i < CIN; i++){
    const float* srow = sin + i*WL + pl0;
    float xv[6];
    *(float4*)&xv[0] = *(const float4*)srow;
    *(float2*)&xv[4] = *(const float2*)(srow + 4);
    const float* wrow = wT + (i*3)*COUT + o0;
    float wv[3][4];
    #pragma unroll
    for (int k = 0; k < 3; k++)
      *(float4*)&wv[k][0] = *(const float4*)(wrow + k*COUT);
    #pragma unroll
    for (int j = 0; j < 4; j++)
      #pragma unroll
      for (int k = 0; k < 3; k++)
        #pragma unroll
        for (int oo = 0; oo < 4; oo++)
          acc[j][oo] = fmaf(xv[j+k], wv[k][oo], acc[j][oo]);
  }

  const int pg0 = blockIdx.y*LSEG + pl0;
  float bv[4];
  #pragma unroll
  for (int oo = 0; oo < 4; oo++) bv[oo] = bias[o0 + oo];
  #pragma unroll
  for (int oo = 0; oo < 4; oo++){
    float* orow = outp + (b*COUT + o0 + oo)*LOUT;
    #pragma unroll
    for (int j = 0; j < 4; j++){
      int p = pg0 + j;
      if (p < LOUT){
        float s = acc[j][oo] + bv[oo];
        float r;
        if (ACT == ACT_TANH)      r = tanhf(s);
        else if (ACT == ACT_RELU) r = fmaxf(s, 0.f);
        else if (ACT == ACT_SIG)  r = sigf(s);
        else                      r = s;
        orow[p] = r;
      }
    }
  }
}

// ---------------- inp: fused maxpool4(h4) + segment masking -> (128,160,171) ----------------
__global__ void k_inp(const float* __restrict__ h4, const float* __restrict__ xmiu,
                      float* __restrict__ inp){
  int idx = blockIdx.x*blockDim.x + threadIdx.x;
  if (idx >= 128*32*171) return;
  int l = idx % 171; int t = idx / 171; int c = t & 31; int b = t >> 5;
  const float* hr = h4 + t*174 + l;
  float wv = fmaxf(fmaxf(hr[0], hr[1]), fmaxf(hr[2], hr[3]));
  float xm = xmiu[idx];
  float prod = wv * xm;
  const float lo[5] = {0.0f, 0.2f, 0.4f, 0.6f, 0.8f};
  const float hi[5] = {0.2f, 0.4f, 0.6f, 0.8f, 2.0f};
  float* op = inp + ((b*160) + c)*171 + l;
  #pragma unroll
  for (int s = 0; s < 5; s++){
    bool m = (wv >= lo[s]) && (wv < hi[s]);
    op[s*32*171] = m ? prod : 0.f;
  }
}

// ---------------- fused logic1 partials (blocks 0..679) + until 2-per-thread (680..7479) ----------------
__global__ void __launch_bounds__(TPB) k_ul1(const float* __restrict__ inp, const float* __restrict__ wn,
                                             float* __restrict__ x1, float* __restrict__ p1){
  int bid = blockIdx.x;
  if (bid < 680){                                 // logic1p: (85, ch=4, v=2), heavy -> first
    int xb = bid % 85; int rr = bid / 85; int ch = rr & 3; int v = rr >> 2;
    int bl = xb*TPB + threadIdx.x;
    int l = bl % 170; int b = bl / 170;
    const float* W = wn + (v ? 6400 : 0);
    float acc[20];
    #pragma unroll
    for (int o = 0; o < 20; o++) acc[o] = 0.f;
    int c0 = ch*40;
    const float* ir = inp + (b*160 + c0)*171 + l;
    for (int c = 0; c < 40; c++){
      float u0 = clip01(ir[0]);
      float u1 = clip01(ir[1]);
      float g0, g1;
      if (v){ g0 = __logf(1.f - u0 + EPSL); g1 = __logf(1.f - u1 + EPSL); }
      else  { g0 = __logf(u0 + EPSL);       g1 = __logf(u1 + EPSL); }
      const float* wc = W + 2*(c0 + c);
      #pragma unroll
      for (int o = 0; o < 20; o++)
        acc[o] = fmaf(wc[o*320], g0, fmaf(wc[o*320 + 1], g1, acc[o]));
      ir += 171;
    }
    float* pp = p1 + ((ch*128 + b)*40 + v*20)*170 + l;
    #pragma unroll
    for (int o = 0; o < 20; o++) pp[o*170] = acc[o];
  } else {                                        // until: 2 outputs per thread
    int idx = (bid - 680)*TPB + threadIdx.x;      // 128*160*85 exactly
    int lh = idx % 85; int t = idx / 85; int c = t % 160; int b = t / 160;
    int l0 = 2*lh;
    const float* xr = inp + (b*160 + c)*171;
    float v[27];
    #pragma unroll
    for (int i = 0; i < 27; i++){
      int q = l0 + i;
      v[i] = (q < 171) ? xr[q] : 0.f;
    }
    float rm0 = v[0], o0 = 0.f;
    float rm1 = v[1], o1 = 0.f;
    #pragma unroll
    for (int d = 1; d <= 25; d++){
      o0 = fmaxf(o0, fminf(rm0, v[d]));     rm0 = fminf(rm0, v[d]);
      o1 = fmaxf(o1, fminf(rm1, v[d+1]));   rm1 = fminf(rm1, v[d+1]);
    }
    float2 ov = {o0, o1};
    *(float2*)&x1[((b*200) + 40 + c)*170 + l0] = ov;
  }
}

// ---------------- logic stage 2 partials: grid (85, ch=8, v=2); logic1 inline from p1 ----------------
__global__ void __launch_bounds__(TPB) k_logic2p(const float* __restrict__ x1, const float* __restrict__ p1,
                                                 const float* __restrict__ wn, float* __restrict__ p2){
  int bl = blockIdx.x*TPB + threadIdx.x;
  int l = bl % 170; int b = bl / 170;
  int ch = blockIdx.y, v = blockIdx.z;
  const float* W = wn + 12800 + (v ? 2400 : 0);
  float acc[6] = {0.f,0.f,0.f,0.f,0.f,0.f};
  int c0 = ch*25;
  bool have0 = (l > 0);
  for (int c = c0; c < c0 + 25; c++){
    float u0 = 0.f, u1;
    if (c < 40){
      float s1 = 0.f;
      #pragma unroll
      for (int q = 0; q < 4; q++) s1 += p1[((q*128 + b)*40 + c)*170 + l];
      float e = __expf(s1);
      u1 = (c < 20) ? e : fmaxf(0.f, 1.f - e);
      if (have0){
        float s0 = 0.f;
        #pragma unroll
        for (int q = 0; q < 4; q++) s0 += p1[((q*128 + b)*40 + c)*170 + l - 1];
        float e0 = __expf(s0);
        u0 = (c < 20) ? e0 : fmaxf(0.f, 1.f - e0);
      }
    } else {
      const float* xr = x1 + (b*200 + c)*170 + l;
      u1 = xr[0];
      if (have0) u0 = xr[-1];
    }
    float g0 = 0.f;
    if (have0){
      float uc = clip01(u0);
      g0 = v ? __logf(1.f - uc + EPSL) : __logf(uc + EPSL);
    }
    float uc1 = clip01(u1);
    float g1 = v ? __logf(1.f - uc1 + EPSL) : __logf(uc1 + EPSL);
    const float* wc = W + 2*c;
    #pragma unroll
    for (int o = 0; o < 6; o++)
      acc[o] = fmaf(wc[o*400], g0, fmaf(wc[o*400 + 1], g1, acc[o]));
  }
  float* pp = p2 + ((ch*128 + b)*12 + v*6)*170 + l;
  #pragma unroll
  for (int o = 0; o < 6; o++) pp[o*170] = acc[o];
}

// ---------------- fin2: combine 8 p2 chunks -> x2 padded to K=192 ----------------
__global__ void k_fin2(const float* __restrict__ p2, float* __restrict__ x2p){
  int idx = blockIdx.x*blockDim.x + threadIdx.x;
  if (idx >= 128*12*192) return;
  int l = idx % 192; int ro = idx / 192;
  if (l >= 170){ x2p[ro*192 + l] = 0.f; return; }
  int o = ro % 12; int b = ro / 12;
  float s = 0.f;
  #pragma unroll
  for (int ch = 0; ch < 8; ch++) s += p2[((ch*128 + b)*12 + o)*170 + l];
  float e = __expf(s);
  float r = (o < 6) ? e : fmaxf(0.f, 1.f - e);
  x2p[ro*192 + l] = r;
}

// ---------------- pipelined tiled GEMM ----------------
template<int M, int N, int K, int KSPLIT, int ACT>
__global__ void __launch_bounds__(256) k_gemm(const float* __restrict__ A,
                                              const float* __restrict__ W,
                                              const float* __restrict__ bias,
                                              float* __restrict__ C){
  static_assert(K % (KSPLIT*32) == 0, "K split");
  constexpr int KC = K / KSPLIT;
  constexpr int NT = KC / 32;
  constexpr int S = 68;
  __shared__ float As[2][32*S];
  __shared__ float Bs[2][32*S];
  const int m0 = blockIdx.x*64, n0 = blockIdx.y*64;
  const int kbeg = blockIdx.z*KC;
  const int tid = threadIdx.x;
  const int row = tid >> 2;
  const int c4  = (tid & 3)*4;
  const int tm  = (tid & 15)*4;
  const int tn  = (tid >> 4)*4;

  const float* Ar = A + (m0 + row)*K + kbeg + c4;
  const float* Wr = W + (n0 + row)*K + kbeg + c4;

  float4 ra0 = *(const float4*)(Ar);
  float4 ra1 = *(const float4*)(Ar + 16);
  float4 rb0 = *(const float4*)(Wr);
  float4 rb1 = *(const float4*)(Wr + 16);

  float acc[4][4] = {{0,0,0,0},{0,0,0,0},{0,0,0,0},{0,0,0,0}};
  int buf = 0;
  {
    float* a = As[0]; float* b = Bs[0];
    #pragma unroll
    for (int i = 0; i < 4; i++){
      a[(c4 + i)*S + row]      = ((const float*)&ra0)[i];
      a[(c4 + 16 + i)*S + row] = ((const float*)&ra1)[i];
      b[(c4 + i)*S + row]      = ((const float*)&rb0)[i];
      b[(c4 + 16 + i)*S + row] = ((const float*)&rb1)[i];
    }
  }
  __syncthreads();

  for (int t = 0; t < NT; t++){
    if (t + 1 < NT){
      Ar += 32; Wr += 32;
      ra0 = *(const float4*)(Ar);
      ra1 = *(const float4*)(Ar + 16);
      rb0 = *(const float4*)(Wr);
      rb1 = *(const float4*)(Wr + 16);
    }
    const float* a = As[buf]; const float* b = Bs[buf];
    #pragma unroll
    for (int k = 0; k < 32; k++){
      const float4 av = *(const float4*)(a + k*S + tm);
      const float4 bv = *(const float4*)(b + k*S + tn);
      acc[0][0] = fmaf(av.x, bv.x, acc[0][0]); acc[0][1] = fmaf(av.x, bv.y, acc[0][1]);
      acc[0][2] = fmaf(av.x, bv.z, acc[0][2]); acc[0][3] = fmaf(av.x, bv.w, acc[0][3]);
      acc[1][0] = fmaf(av.y, bv.x, acc[1][0]); acc[1][1] = fmaf(av.y, bv.y, acc[1][1]);
      acc[1][2] = fmaf(av.y, bv.z, acc[1][2]); acc[1][3] = fmaf(av.y, bv.w, acc[1][3]);
      acc[2][0] = fmaf(av.z, bv.x, acc[2][0]); acc[2][1] = fmaf(av.z, bv.y, acc[2][1]);
      acc[2][2] = fmaf(av.z, bv.z, acc[2][2]); acc[2][3] = fmaf(av.z, bv.w, acc[2][3]);
      acc[3][0] = fmaf(av.w, bv.x, acc[3][0]); acc[3][1] = fmaf(av.w, bv.y, acc[3][1]);
      acc[3][2] = fmaf(av.w, bv.z, acc[3][2]); acc[3][3] = fmaf(av.w, bv.w, acc[3][3]);
    }
    if (t + 1 < NT){
      int nb = buf ^ 1;
      float* an = As[nb]; float* bn = Bs[nb];
      #pragma unroll
      for (int i = 0; i < 4; i++){
        an[(c4 + i)*S + row]      = ((const float*)&ra0)[i];
        an[(c4 + 16 + i)*S + row] = ((const float*)&ra1)[i];
        bn[(c4 + i)*S + row]      = ((const float*)&rb0)[i];
        bn[(c4 + 16 + i)*S + row] = ((const float*)&rb1)[i];
      }
      __syncthreads();
      buf = nb;
    }
  }

  if (KSPLIT == 1){
    #pragma unroll
    for (int i = 0; i < 4; i++){
      float4 vv;
      vv.x = acc[i][0] + bias[n0 + tn];
      vv.y = acc[i][1] + bias[n0 + tn + 1];
      vv.z = acc[i][2] + bias[n0 + tn + 2];
      vv.w = acc[i][3] + bias[n0 + tn + 3];
      if (ACT == ACT_RELU){
        vv.x = fmaxf(vv.x, 0.f); vv.y = fmaxf(vv.y, 0.f);
        vv.z = fmaxf(vv.z, 0.f); vv.w = fmaxf(vv.w, 0.f);
      }
      *(float4*)&C[(m0 + tm + i)*N + n0 + tn] = vv;
    }
  } else {
    float* Cz = C + (size_t)blockIdx.z*M*N;
    #pragma unroll
    for (int i = 0; i < 4; i++){
      float4 vv = {acc[i][0], acc[i][1], acc[i][2], acc[i][3]};
      *(float4*)&Cz[(m0 + tm + i)*N + n0 + tn] = vv;
    }
  }
}

// ---------------- tail: fc2 combine(4) + bias + relu + fc3 -> out (1536,10) ----------------
__global__ void __launch_bounds__(256) k_tail(const float* __restrict__ gp,
                                              const float* __restrict__ b2,
                                              const float* __restrict__ w3,
                                              const float* __restrict__ b3,
                                              float* __restrict__ out){
  constexpr int MN = 1536*256;
  __shared__ float sh[256];
  __shared__ float ps[160];
  const int row = blockIdx.x;
  const int t = threadIdx.x;
  float s = b2[t];
  #pragma unroll
  for (int z = 0; z < 4; z++) s += gp[(size_t)z*MN + row*256 + t];
  sh[t] = fmaxf(s, 0.f);
  __syncthreads();
  if (t < 160){
    int q = t >> 4, j = t & 15;
    const float* wr = w3 + q*256 + j*16;
    const float* hr = sh + j*16;
    float p = 0.f;
    #pragma unroll
    for (int i = 0; i < 16; i++) p = fmaf(hr[i], wr[i], p);
    ps[t] = p;
  }
  __syncthreads();
  if (t < 10){
    float s3 = b3[t];
    #pragma unroll
    for (int j = 0; j < 16; j++) s3 += ps[t*16 + j];
    out[row*10 + t] = s3;
  }
}

extern "C" void kernel_launch(void* const* d_in, const int* in_sizes, int n_in,
                              void* d_out, int out_size, void* d_ws, size_t ws_size,
                              hipStream_t stream) {
  const float* x      = (const float*)d_in[0];
  const float* wave_w = (const float*)d_in[1];
  const float* bn_g   = (const float*)d_in[2];
  const float* bn_b   = (const float*)d_in[3];
  const float* miu_ap = (const float*)d_in[4];
  const float* miu_bp = (const float*)d_in[5];
  const float* miu_an = (const float*)d_in[6];
  const float* miu_bn = (const float*)d_in[7];
  const float* ae_w1  = (const float*)d_in[8];
  const float* ae_b1  = (const float*)d_in[9];
  const float* ae_w2  = (const float*)d_in[10];
  const float* ae_b2  = (const float*)d_in[11];
  const float* ae_w3  = (const float*)d_in[12];
  const float* ae_b3  = (const float*)d_in[13];
  const float* ae_w4  = (const float*)d_in[14];
  const float* ae_b4  = (const float*)d_in[15];
  const float* and2_w = (const float*)d_in[16];
  const float* or2_w  = (const float*)d_in[17];
  const float* and_w  = (const float*)d_in[18];
  const float* or_w   = (const float*)d_in[19];
  const float* fc1_w  = (const float*)d_in[20];
  const float* fc1_b  = (const float*)d_in[21];
  const float* fc2_w  = (const float*)d_in[22];
  const float* fc2_b  = (const float*)d_in[23];
  const float* fc3_w  = (const float*)d_in[24];
  const float* fc3_b  = (const float*)d_in[25];
  float* out = (float*)d_out;
  float* ws  = (float*)d_ws;

  float* y1    = ws + OFF_Y1;
  float* xmiu  = ws + OFF_XMIU;
  float* c1    = ws + OFF_H1;
  float* c2    = ws + OFF_XF;
  float* h3    = ws + OFF_Y1;
  float* h4    = ws + OFF_H1;
  float* inp   = ws + OFF_INP;
  float* x1    = ws + OFF_X1;
  float* p1    = ws + OFF_P1;
  float* p2    = ws + OFF_P2;
  float* gp    = ws + OFF_GP;
  float* x2p   = ws + OFF_X2P;
  float* w1p   = ws + OFF_W1P;
  float* fc1h  = ws + OFF_FC1H;
  double* bnp  = (double*)(ws + OFF_BNP);
  float* wn    = ws + OFF_WN;

  k_misc     <<<52 + 5504 + 768, TPB, 0, stream>>>(and2_w, or2_w, and_w, or_w, wn,
                                                   x, wave_w, y1, fc1_w, w1p);
  k_bn_part  <<<128, TPB, 0, stream>>>(y1, bnp);
  k_xmiu2    <<<cdiv(128*32*171, TPB), TPB, 0, stream>>>(y1, bnp, bn_g, bn_b,
                                                         miu_ap, miu_bp, miu_an, miu_bn, xmiu);

  k_conv<32,171,171,64,171,1,ACT_NONE,16,0><<<dim3(128,3), 256, 0, stream>>>(xmiu, ae_w1, ae_b1, c1);
  k_conv<64,171, 85,32, 85,1,ACT_NONE,32,1><<<dim3(128,1), 256, 0, stream>>>(c1, ae_w2, ae_b2, c2);
  k_conv<32, 85, 84,64, 86,2,ACT_TANH,16,2><<<dim3(128,2), 256, 0, stream>>>(c2, ae_w3, ae_b3, h3);
  k_conv<64, 86,172,32,174,2,ACT_SIG ,32,3><<<dim3(128,2), 256, 0, stream>>>(h3, ae_w4, ae_b4, h4);

  k_inp      <<<cdiv(128*32*171, TPB), TPB, 0, stream>>>(h4, xmiu, inp);
  k_ul1      <<<680 + 6800, TPB, 0, stream>>>(inp, wn, x1, p1);
  k_logic2p  <<<dim3(85, 8, 2), TPB, 0, stream>>>(x1, p1, wn, p2);
  k_fin2     <<<cdiv(128*12*192, TPB), TPB, 0, stream>>>(p2, x2p);

  k_gemm<1536,1024,192,1,ACT_RELU><<<dim3(24,16,1), 256, 0, stream>>>(x2p, w1p, fc1_b, fc1h);
  k_gemm<1536,256,1024,4,ACT_NONE><<<dim3(24,4,4), 256, 0, stream>>>(fc1h, fc2_w, fc2_b, gp);
  k_tail     <<<1536, 256, 0, stream>>>(gp, fc2_b, fc3_w, fc3_b, out);
}

// Round 10
// 297.702 us; speedup vs baseline: 2.9402x; 1.0654x over previous
//
#include <hip/hip_runtime.h>

#define TPB 256
static inline int cdiv(int a, int b){ return (a + b - 1) / b; }

#define EPSL 1e-6f
#define ACT_TANH 0
#define ACT_RELU 1
#define ACT_SIG  2
#define ACT_NONE 3

__device__ __forceinline__ float sigf(float x){ return 1.0f / (1.0f + __expf(-x)); }
__device__ __forceinline__ float clip01(float x){ return fminf(fmaxf(x, 0.f), 1.f); }

// ---------------- workspace layout (float offsets; ws = 256 MiB = 67.1M floats) ----------------
#define OFF_Y1   0
#define OFF_XF   1409024
#define OFF_XMIU 2111488
#define OFF_H1   2811904
#define OFF_INP  4384768
#define OFF_X1   7886848
#define OFF_TAIL 12238848
#define OFF_P2   (OFF_INP + 400000)      // 8*128*12*170 = 2088960, ends 6.87M < OFF_X1
#define OFF_GP   0                        // 4*1536*256 = 1572864
#define OFF_X2P  OFF_INP                  // 294912 (p2 starts at +400000: clear)
#define OFF_FC1H OFF_X1
#define OFF_BNP  (OFF_TAIL + 64)         // 512 doubles = 1024 floats
#define OFF_WN   (OFF_TAIL + 64 + 1024)
#define OFF_W1P  (OFF_TAIL + 64 + 1024 + 17600)
#define OFF_P1   16000000                 // 8*128*40*170 = 6963200, ends 22.97M << 67M

// ---------------- misc: softmax(52) + conv_wave(5504) + fc1 wpad(768) ----------------
__global__ void __launch_bounds__(TPB) k_misc(const float* __restrict__ a2, const float* __restrict__ o2,
                     const float* __restrict__ aw, const float* __restrict__ ow,
                     float* __restrict__ wn,
                     const float* __restrict__ x, const float* __restrict__ ww,
                     float* __restrict__ y,
                     const float* __restrict__ w1, float* __restrict__ wp){
  int bid = blockIdx.x;
  if (bid < 52){
    const float* src; float* dst; int n;
    if (bid < 20)      { src = a2 + bid*320;      dst = wn + bid*320;              n = 320; }
    else if (bid < 40) { src = o2 + (bid-20)*320; dst = wn + 6400 + (bid-20)*320;  n = 320; }
    else if (bid < 46) { src = aw + (bid-40)*400; dst = wn + 12800 + (bid-40)*400; n = 400; }
    else               { src = ow + (bid-46)*400; dst = wn + 15200 + (bid-46)*400; n = 400; }
    __shared__ float sh[TPB];
    float m = -1e30f;
    for (int i = threadIdx.x; i < n; i += TPB) m = fmaxf(m, src[i]);
    sh[threadIdx.x] = m; __syncthreads();
    for (int off = TPB/2; off > 0; off >>= 1){
      if (threadIdx.x < off) sh[threadIdx.x] = fmaxf(sh[threadIdx.x], sh[threadIdx.x+off]);
      __syncthreads();
    }
    m = sh[0]; __syncthreads();
    float s = 0.f;
    for (int i = threadIdx.x; i < n; i += TPB) s += expf(src[i] - m);
    sh[threadIdx.x] = s; __syncthreads();
    for (int off = TPB/2; off > 0; off >>= 1){
      if (threadIdx.x < off) sh[threadIdx.x] += sh[threadIdx.x+off];
      __syncthreads();
    }
    float inv = 1.0f / sh[0];
    __syncthreads();
    for (int i = threadIdx.x; i < n; i += TPB) dst[i] = expf(src[i] - m) * inv;
  } else if (bid < 52 + 5504){
    int idx = (bid - 52)*TPB + threadIdx.x;
    int l = idx % 688; int t = idx / 688; int o = t & 15; int b = t >> 4;
    const float* xr = x + b*719 + l;
    const float* wr = ww + o*32;
    float s = 0.f;
    #pragma unroll
    for (int k = 0; k < 32; k++) s = fmaf(xr[k], wr[k], s);
    y[idx] = s;
  } else {
    int idx = (bid - 5556)*TPB + threadIdx.x;
    int k = idx % 192; int o = idx / 192;
    wp[idx] = (k < 170) ? w1[o*170 + k] : 0.f;
  }
}

// ---------------- BN stats partials: 256 blocks (16 c x 16 batch-chunks of 8) ----------------
__global__ void k_bn_part(const float* __restrict__ y, double* __restrict__ bnp){
  int c = blockIdx.x & 15, ch = blockIdx.x >> 4;
  double s = 0.0, s2 = 0.0;
  for (int i = threadIdx.x; i < 8*688; i += TPB){
    int b = ch*8 + i/688, l = i % 688;
    float v = y[(b*16 + c)*688 + l];
    s += (double)v; s2 += (double)v * (double)v;
  }
  __shared__ double sh[TPB], sh2[TPB];
  sh[threadIdx.x] = s; sh2[threadIdx.x] = s2; __syncthreads();
  for (int off = TPB/2; off > 0; off >>= 1){
    if (threadIdx.x < off){ sh[threadIdx.x] += sh[threadIdx.x+off]; sh2[threadIdx.x] += sh2[threadIdx.x+off]; }
    __syncthreads();
  }
  if (threadIdx.x == 0){ bnp[blockIdx.x] = sh[0]; bnp[256 + blockIdx.x] = sh2[0]; }
}

// ---------------- fused bn-finalize + xf + miu: y -> x_miu (128,32,171) ----------------
__global__ void k_xmiu2(const float* __restrict__ y, const double* __restrict__ bnp,
                        const float* __restrict__ g, const float* __restrict__ bb,
                        const float* __restrict__ ap, const float* __restrict__ bp,
                        const float* __restrict__ an, const float* __restrict__ bn,
                        float* __restrict__ out){
  __shared__ float smean[16], srstd[16];
  if (threadIdx.x < 16){
    int cc = threadIdx.x;
    double s = 0.0, s2 = 0.0;
    #pragma unroll
    for (int j = 0; j < 16; j++){ s += bnp[j*16 + cc]; s2 += bnp[256 + j*16 + cc]; }
    double n = 128.0*688.0;
    double m = s / n;
    double var = s2 / n - m*m;
    smean[cc] = (float)m;
    srstd[cc] = (float)(1.0 / sqrt(var + 1e-5));
  }
  __syncthreads();
  int idx = blockIdx.x*blockDim.x + threadIdx.x;
  if (idx >= 128*32*171) return;
  int l = idx % 171; int t = idx / 171; int c = t & 31; int b = t >> 5;
  int cc = c & 15;
  float mean = smean[cc], rstd = srstd[cc];
  float gc = g[cc], bc = bb[cc];
  float sign = (c < 16) ? 1.f : -1.f;
  float a  = (c < 16) ? ap[cc] : an[cc];
  float bo = (c < 16) ? bp[cc] : bn[cc];
  const float* yr = y + (b*16 + cc)*688 + 4*l;
  float v[7];
  #pragma unroll
  for (int i = 0; i < 7; i++)
    v[i] = fmaxf(fmaf(gc*(yr[i] - mean), rstd, bc), 0.f);
  float m = -1e30f;
  #pragma unroll
  for (int j = 0; j < 3; j++){
    float xf = fmaxf(fmaxf(v[2*j], v[2*j+1]), v[2*j+2]);
    m = fmaxf(m, sigf(sign * a * (xf - bo)));
  }
  out[idx] = m;
}

// ---------------- staging value generators ----------------
template<int SMODE, int LSRC, int LEFF>
__device__ __forceinline__ float stage_val(const float* __restrict__ src, int q){
  if (q < 0 || q >= LEFF) return 0.f;
  if constexpr (SMODE == 0){
    return src[q];
  } else if constexpr (SMODE == 1){
    float m = fmaxf(fmaxf(src[2*q], src[2*q+1]), src[2*q+2]);
    return tanhf(m);
  } else if constexpr (SMODE == 2){
    auto P = [&](int k){
      float m = fmaxf(fmaxf(src[2*k], src[2*k+1]), src[2*k+2]);
      return fmaxf(m, 0.f);
    };
    if (q == 0) return P(0);
    if (q == LEFF - 1) return P(LEFF/2 - 1);
    int k = q >> 1;
    return (q & 1) ? 0.75f*P(k) + 0.25f*P(k+1) : 0.25f*P(k-1) + 0.75f*P(k);
  } else {
    if (q == 0) return src[0];
    if (q == LEFF - 1) return src[LSRC - 1];
    int k = q >> 1;
    return (q & 1) ? 0.75f*src[k] + 0.25f*src[k+1] : 0.25f*src[k-1] + 0.75f*src[k];
  }
}

// ---------------- generic LDS-tiled 1D conv (kernel=3); JT positions/thread ----------------
template<int CIN, int LSRC, int LEFF, int COUT, int LOUT, int PAD, int ACT, int PL, int SMODE, int JT>
__global__ void __launch_bounds__(256) k_conv(const float* __restrict__ in,
                                              const float* __restrict__ w,
                                              const float* __restrict__ bias,
                                              float* __restrict__ outp){
  constexpr int LSEG = JT*PL;
  constexpr int WL = ((LSEG + 2) + 3) & ~3;
  constexpr int K3 = CIN*3;
  __shared__ float smem[CIN*WL + 8 + K3*COUT];
  float* sin = smem;
  float* wT  = smem + CIN*WL + 8;
  const int b = blockIdx.x;
  const int tid = threadIdx.x;
  const int base = blockIdx.y*LSEG - PAD;

  const float* gin = in + b*CIN*LSRC;
  for (int e = tid; e < CIN*WL; e += 256){
    int i = e / WL, c = e - i*WL;
    sin[e] = stage_val<SMODE, LSRC, LEFF>(gin + i*LSRC, base + c);
  }
  if (tid < 8) sin[CIN*WL + tid] = 0.f;
  for (int e = tid; e < K3*COUT; e += 256){
    int o = e & (COUT-1), m = e / COUT;
    wT[m*COUT + o] = w[o*K3 + m];
  }
  __syncthreads();

  const int to = tid / PL, tp = tid - (tid/PL)*PL;
  const int o0 = to*4;
  const int pl0 = JT*tp;
  float acc[JT][4];
  #pragma unroll
  for (int j = 0; j < JT; j++)
    #pragma unroll
    for (int oo = 0; oo < 4; oo++) acc[j][oo] = 0.f;

  for (int i = 0; i < CIN; i++){
    const float* srow = sin + i*WL + pl0;
    float xv[JT+2];
    #pragma unroll
    for (int j = 0; j < JT+2; j++) xv[j] = srow[j];
    const float* wrow = wT + (i*3)*COUT + o0;
    float wv[3][4];
    #pragma unroll
    for (int k = 0; k < 3; k++)
      *(float4*)&wv[k][0] = *(const float4*)(wrow + k*COUT);
    #pragma unroll
    for (int j = 0; j < JT; j++)
      #pragma unroll
      for (int k = 0; k < 3; k++)
        #pragma unroll
        for (int oo = 0; oo < 4; oo++)
          acc[j][oo] = fmaf(xv[j+k], wv[k][oo], acc[j][oo]);
  }

  const int pg0 = blockIdx.y*LSEG + pl0;
  float bv[4];
  #pragma unroll
  for (int oo = 0; oo < 4; oo++) bv[oo] = bias[o0 + oo];
  #pragma unroll
  for (int oo = 0; oo < 4; oo++){
    float* orow = outp + (b*COUT + o0 + oo)*LOUT;
    #pragma unroll
    for (int j = 0; j < JT; j++){
      int p = pg0 + j;
      if (p < LOUT){
        float s = acc[j][oo] + bv[oo];
        float r;
        if (ACT == ACT_TANH)      r = tanhf(s);
        else if (ACT == ACT_RELU) r = fmaxf(s, 0.f);
        else if (ACT == ACT_SIG)  r = sigf(s);
        else                      r = s;
        orow[p] = r;
      }
    }
  }
}

// ---------------- inp: fused maxpool4(h4) + segment masking -> (128,160,171) ----------------
__global__ void k_inp(const float* __restrict__ h4, const float* __restrict__ xmiu,
                      float* __restrict__ inp){
  int idx = blockIdx.x*blockDim.x + threadIdx.x;
  if (idx >= 128*32*171) return;
  int l = idx % 171; int t = idx / 171; int c = t & 31; int b = t >> 5;
  const float* hr = h4 + t*174 + l;
  float wv = fmaxf(fmaxf(hr[0], hr[1]), fmaxf(hr[2], hr[3]));
  float xm = xmiu[idx];
  float prod = wv * xm;
  const float lo[5] = {0.0f, 0.2f, 0.4f, 0.6f, 0.8f};
  const float hi[5] = {0.2f, 0.4f, 0.6f, 0.8f, 2.0f};
  float* op = inp + ((b*160) + c)*171 + l;
  #pragma unroll
  for (int s = 0; s < 5; s++){
    bool m = (wv >= lo[s]) && (wv < hi[s]);
    op[s*32*171] = m ? prod : 0.f;
  }
}

// ---------------- fused logic1p (blocks 0..1359, 8 chunks) + until 4/thread (1360..4799) ----------------
__global__ void __launch_bounds__(TPB) k_ul1(const float* __restrict__ inp, const float* __restrict__ wn,
                                             float* __restrict__ x1, float* __restrict__ p1){
  int bid = blockIdx.x;
  if (bid < 1360){                                // logic1p: (85, ch=8, v=2), heavy -> first
    int xb = bid % 85; int rr = bid / 85; int ch = rr & 7; int v = rr >> 3;
    int bl = xb*TPB + threadIdx.x;
    int l = bl % 170; int b = bl / 170;
    const float* W = wn + (v ? 6400 : 0);
    float acc[20];
    #pragma unroll
    for (int o = 0; o < 20; o++) acc[o] = 0.f;
    int c0 = ch*20;
    const float* ir = inp + (b*160 + c0)*171 + l;
    for (int c = 0; c < 20; c++){
      float u0 = clip01(ir[0]);
      float u1 = clip01(ir[1]);
      float g0, g1;
      if (v){ g0 = __logf(1.f - u0 + EPSL); g1 = __logf(1.f - u1 + EPSL); }
      else  { g0 = __logf(u0 + EPSL);       g1 = __logf(u1 + EPSL); }
      const float* wc = W + 2*(c0 + c);
      #pragma unroll
      for (int o = 0; o < 20; o++)
        acc[o] = fmaf(wc[o*320], g0, fmaf(wc[o*320 + 1], g1, acc[o]));
      ir += 171;
    }
    float* pp = p1 + ((ch*128 + b)*40 + v*20)*170 + l;
    #pragma unroll
    for (int o = 0; o < 20; o++) pp[o*170] = acc[o];
  } else {                                        // until: 4 outputs per thread
    int idx = (bid - 1360)*TPB + threadIdx.x;     // 128*160*43 = 880640 exactly
    int lh = idx % 43; int t = idx / 43; int c = t % 160; int b = t / 160;
    int l0 = 4*lh;
    const float* xr = inp + (b*160 + c)*171;
    float v[29];
    #pragma unroll
    for (int i = 0; i < 29; i++){
      int q = l0 + i;
      v[i] = (q < 171) ? xr[q] : 0.f;
    }
    float rm0 = v[0], o0 = 0.f;
    float rm1 = v[1], o1 = 0.f;
    float rm2 = v[2], o2 = 0.f;
    float rm3 = v[3], o3 = 0.f;
    #pragma unroll
    for (int d = 1; d <= 25; d++){
      o0 = fmaxf(o0, fminf(rm0, v[d]));     rm0 = fminf(rm0, v[d]);
      o1 = fmaxf(o1, fminf(rm1, v[d+1]));   rm1 = fminf(rm1, v[d+1]);
      o2 = fmaxf(o2, fminf(rm2, v[d+2]));   rm2 = fminf(rm2, v[d+2]);
      o3 = fmaxf(o3, fminf(rm3, v[d+3]));   rm3 = fminf(rm3, v[d+3]);
    }
    float* xw = x1 + ((b*200) + 40 + c)*170;
    if (l0 + 1 < 170){ float2 ov = {o0, o1}; *(float2*)&xw[l0] = ov; }
    if (l0 + 3 < 170){ float2 ov = {o2, o3}; *(float2*)&xw[l0 + 2] = ov; }
  }
}

// ---------------- logic stage 2 partials: grid (85, ch=8, v=2); logic1 inline from p1 (8 chunks) ----------------
__global__ void __launch_bounds__(TPB) k_logic2p(const float* __restrict__ x1, const float* __restrict__ p1,
                                                 const float* __restrict__ wn, float* __restrict__ p2){
  int bl = blockIdx.x*TPB + threadIdx.x;
  int l = bl % 170; int b = bl / 170;
  int ch = blockIdx.y, v = blockIdx.z;
  const float* W = wn + 12800 + (v ? 2400 : 0);
  float acc[6] = {0.f,0.f,0.f,0.f,0.f,0.f};
  int c0 = ch*25;
  bool have0 = (l > 0);
  for (int c = c0; c < c0 + 25; c++){
    float u0 = 0.f, u1;
    if (c < 40){
      float s1 = 0.f;
      #pragma unroll
      for (int q = 0; q < 8; q++) s1 += p1[((q*128 + b)*40 + c)*170 + l];
      float e = __expf(s1);
      u1 = (c < 20) ? e : fmaxf(0.f, 1.f - e);
      if (have0){
        float s0 = 0.f;
        #pragma unroll
        for (int q = 0; q < 8; q++) s0 += p1[((q*128 + b)*40 + c)*170 + l - 1];
        float e0 = __expf(s0);
        u0 = (c < 20) ? e0 : fmaxf(0.f, 1.f - e0);
      }
    } else {
      const float* xr = x1 + (b*200 + c)*170 + l;
      u1 = xr[0];
      if (have0) u0 = xr[-1];
    }
    float g0 = 0.f;
    if (have0){
      float uc = clip01(u0);
      g0 = v ? __logf(1.f - uc + EPSL) : __logf(uc + EPSL);
    }
    float uc1 = clip01(u1);
    float g1 = v ? __logf(1.f - uc1 + EPSL) : __logf(uc1 + EPSL);
    const float* wc = W + 2*c;
    #pragma unroll
    for (int o = 0; o < 6; o++)
      acc[o] = fmaf(wc[o*400], g0, fmaf(wc[o*400 + 1], g1, acc[o]));
  }
  float* pp = p2 + ((ch*128 + b)*12 + v*6)*170 + l;
  #pragma unroll
  for (int o = 0; o < 6; o++) pp[o*170] = acc[o];
}

// ---------------- fin2: combine 8 p2 chunks -> x2 padded to K=192 ----------------
__global__ void k_fin2(const float* __restrict__ p2, float* __restrict__ x2p){
  int idx = blockIdx.x*blockDim.x + threadIdx.x;
  if (idx >= 128*12*192) return;
  int l = idx % 192; int ro = idx / 192;
  if (l >= 170){ x2p[ro*192 + l] = 0.f; return; }
  int o = ro % 12; int b = ro / 12;
  float s = 0.f;
  #pragma unroll
  for (int ch = 0; ch < 8; ch++) s += p2[((ch*128 + b)*12 + o)*170 + l];
  float e = __expf(s);
  float r = (o < 6) ? e : fmaxf(0.f, 1.f - e);
  x2p[ro*192 + l] = r;
}

// ---------------- pipelined tiled GEMM ----------------
template<int M, int N, int K, int KSPLIT, int ACT>
__global__ void __launch_bounds__(256) k_gemm(const float* __restrict__ A,
                                              const float* __restrict__ W,
                                              const float* __restrict__ bias,
                                              float* __restrict__ C){
  static_assert(K % (KSPLIT*32) == 0, "K split");
  constexpr int KC = K / KSPLIT;
  constexpr int NT = KC / 32;
  constexpr int S = 68;
  __shared__ float As[2][32*S];
  __shared__ float Bs[2][32*S];
  const int m0 = blockIdx.x*64, n0 = blockIdx.y*64;
  const int kbeg = blockIdx.z*KC;
  const int tid = threadIdx.x;
  const int row = tid >> 2;
  const int c4  = (tid & 3)*4;
  const int tm  = (tid & 15)*4;
  const int tn  = (tid >> 4)*4;

  const float* Ar = A + (m0 + row)*K + kbeg + c4;
  const float* Wr = W + (n0 + row)*K + kbeg + c4;

  float4 ra0 = *(const float4*)(Ar);
  float4 ra1 = *(const float4*)(Ar + 16);
  float4 rb0 = *(const float4*)(Wr);
  float4 rb1 = *(const float4*)(Wr + 16);

  float acc[4][4] = {{0,0,0,0},{0,0,0,0},{0,0,0,0},{0,0,0,0}};
  int buf = 0;
  {
    float* a = As[0]; float* b = Bs[0];
    #pragma unroll
    for (int i = 0; i < 4; i++){
      a[(c4 + i)*S + row]      = ((const float*)&ra0)[i];
      a[(c4 + 16 + i)*S + row] = ((const float*)&ra1)[i];
      b[(c4 + i)*S + row]      = ((const float*)&rb0)[i];
      b[(c4 + 16 + i)*S + row] = ((const float*)&rb1)[i];
    }
  }
  __syncthreads();

  for (int t = 0; t < NT; t++){
    if (t + 1 < NT){
      Ar += 32; Wr += 32;
      ra0 = *(const float4*)(Ar);
      ra1 = *(const float4*)(Ar + 16);
      rb0 = *(const float4*)(Wr);
      rb1 = *(const float4*)(Wr + 16);
    }
    const float* a = As[buf]; const float* b = Bs[buf];
    #pragma unroll
    for (int k = 0; k < 32; k++){
      const float4 av = *(const float4*)(a + k*S + tm);
      const float4 bv = *(const float4*)(b + k*S + tn);
      acc[0][0] = fmaf(av.x, bv.x, acc[0][0]); acc[0][1] = fmaf(av.x, bv.y, acc[0][1]);
      acc[0][2] = fmaf(av.x, bv.z, acc[0][2]); acc[0][3] = fmaf(av.x, bv.w, acc[0][3]);
      acc[1][0] = fmaf(av.y, bv.x, acc[1][0]); acc[1][1] = fmaf(av.y, bv.y, acc[1][1]);
      acc[1][2] = fmaf(av.y, bv.z, acc[1][2]); acc[1][3] = fmaf(av.y, bv.w, acc[1][3]);
      acc[2][0] = fmaf(av.z, bv.x, acc[2][0]); acc[2][1] = fmaf(av.z, bv.y, acc[2][1]);
      acc[2][2] = fmaf(av.z, bv.z, acc[2][2]); acc[2][3] = fmaf(av.z, bv.w, acc[2][3]);
      acc[3][0] = fmaf(av.w, bv.x, acc[3][0]); acc[3][1] = fmaf(av.w, bv.y, acc[3][1]);
      acc[3][2] = fmaf(av.w, bv.z, acc[3][2]); acc[3][3] = fmaf(av.w, bv.w, acc[3][3]);
    }
    if (t + 1 < NT){
      int nb = buf ^ 1;
      float* an = As[nb]; float* bn = Bs[nb];
      #pragma unroll
      for (int i = 0; i < 4; i++){
        an[(c4 + i)*S + row]      = ((const float*)&ra0)[i];
        an[(c4 + 16 + i)*S + row] = ((const float*)&ra1)[i];
        bn[(c4 + i)*S + row]      = ((const float*)&rb0)[i];
        bn[(c4 + 16 + i)*S + row] = ((const float*)&rb1)[i];
      }
      __syncthreads();
      buf = nb;
    }
  }

  if (KSPLIT == 1){
    #pragma unroll
    for (int i = 0; i < 4; i++){
      float4 vv;
      vv.x = acc[i][0] + bias[n0 + tn];
      vv.y = acc[i][1] + bias[n0 + tn + 1];
      vv.z = acc[i][2] + bias[n0 + tn + 2];
      vv.w = acc[i][3] + bias[n0 + tn + 3];
      if (ACT == ACT_RELU){
        vv.x = fmaxf(vv.x, 0.f); vv.y = fmaxf(vv.y, 0.f);
        vv.z = fmaxf(vv.z, 0.f); vv.w = fmaxf(vv.w, 0.f);
      }
      *(float4*)&C[(m0 + tm + i)*N + n0 + tn] = vv;
    }
  } else {
    float* Cz = C + (size_t)blockIdx.z*M*N;
    #pragma unroll
    for (int i = 0; i < 4; i++){
      float4 vv = {acc[i][0], acc[i][1], acc[i][2], acc[i][3]};
      *(float4*)&Cz[(m0 + tm + i)*N + n0 + tn] = vv;
    }
  }
}

// ---------------- tail: fc2 combine(4) + bias + relu + fc3 -> out (1536,10) ----------------
__global__ void __launch_bounds__(256) k_tail(const float* __restrict__ gp,
                                              const float* __restrict__ b2,
                                              const float* __restrict__ w3,
                                              const float* __restrict__ b3,
                                              float* __restrict__ out){
  constexpr int MN = 1536*256;
  __shared__ float sh[256];
  __shared__ float ps[160];
  const int row = blockIdx.x;
  const int t = threadIdx.x;
  float s = b2[t];
  #pragma unroll
  for (int z = 0; z < 4; z++) s += gp[(size_t)z*MN + row*256 + t];
  sh[t] = fmaxf(s, 0.f);
  __syncthreads();
  if (t < 160){
    int q = t >> 4, j = t & 15;
    const float* wr = w3 + q*256 + j*16;
    const float* hr = sh + j*16;
    float p = 0.f;
    #pragma unroll
    for (int i = 0; i < 16; i++) p = fmaf(hr[i], wr[i], p);
    ps[t] = p;
  }
  __syncthreads();
  if (t < 10){
    float s3 = b3[t];
    #pragma unroll
    for (int j = 0; j < 16; j++) s3 += ps[t*16 + j];
    out[row*10 + t] = s3;
  }
}

extern "C" void kernel_launch(void* const* d_in, const int* in_sizes, int n_in,
                              void* d_out, int out_size, void* d_ws, size_t ws_size,
                              hipStream_t stream) {
  const float* x      = (const float*)d_in[0];
  const float* wave_w = (const float*)d_in[1];
  const float* bn_g   = (const float*)d_in[2];
  const float* bn_b   = (const float*)d_in[3];
  const float* miu_ap = (const float*)d_in[4];
  const float* miu_bp = (const float*)d_in[5];
  const float* miu_an = (const float*)d_in[6];
  const float* miu_bn = (const float*)d_in[7];
  const float* ae_w1  = (const float*)d_in[8];
  const float* ae_b1  = (const float*)d_in[9];
  const float* ae_w2  = (const float*)d_in[10];
  const float* ae_b2  = (const float*)d_in[11];
  const float* ae_w3  = (const float*)d_in[12];
  const float* ae_b3  = (const float*)d_in[13];
  const float* ae_w4  = (const float*)d_in[14];
  const float* ae_b4  = (const float*)d_in[15];
  const float* and2_w = (const float*)d_in[16];
  const float* or2_w  = (const float*)d_in[17];
  const float* and_w  = (const float*)d_in[18];
  const float* or_w   = (const float*)d_in[19];
  const float* fc1_w  = (const float*)d_in[20];
  const float* fc1_b  = (const float*)d_in[21];
  const float* fc2_w  = (const float*)d_in[22];
  const float* fc2_b  = (const float*)d_in[23];
  const float* fc3_w  = (const float*)d_in[24];
  const float* fc3_b  = (const float*)d_in[25];
  float* out = (float*)d_out;
  float* ws  = (float*)d_ws;

  float* y1    = ws + OFF_Y1;
  float* xmiu  = ws + OFF_XMIU;
  float* c1    = ws + OFF_H1;
  float* c2    = ws + OFF_XF;
  float* h3    = ws + OFF_Y1;
  float* h4    = ws + OFF_H1;
  float* inp   = ws + OFF_INP;
  float* x1    = ws + OFF_X1;
  float* p1    = ws + OFF_P1;
  float* p2    = ws + OFF_P2;
  float* gp    = ws + OFF_GP;
  float* x2p   = ws + OFF_X2P;
  float* w1p   = ws + OFF_W1P;
  float* fc1h  = ws + OFF_FC1H;
  double* bnp  = (double*)(ws + OFF_BNP);
  float* wn    = ws + OFF_WN;

  k_misc     <<<52 + 5504 + 768, TPB, 0, stream>>>(and2_w, or2_w, and_w, or_w, wn,
                                                   x, wave_w, y1, fc1_w, w1p);
  k_bn_part  <<<256, TPB, 0, stream>>>(y1, bnp);
  k_xmiu2    <<<cdiv(128*32*171, TPB), TPB, 0, stream>>>(y1, bnp, bn_g, bn_b,
                                                         miu_ap, miu_bp, miu_an, miu_bn, xmiu);

  k_conv<32,171,171,64,171,1,ACT_NONE,16,0,4><<<dim3(128,3), 256, 0, stream>>>(xmiu, ae_w1, ae_b1, c1);
  k_conv<64,171, 85,32, 85,1,ACT_NONE,32,1,2><<<dim3(128,2), 256, 0, stream>>>(c1, ae_w2, ae_b2, c2);
  k_conv<32, 85, 84,64, 86,2,ACT_TANH,16,2,4><<<dim3(128,2), 256, 0, stream>>>(c2, ae_w3, ae_b3, h3);
  k_conv<64, 86,172,32,174,2,ACT_SIG ,32,3,2><<<dim3(128,3), 256, 0, stream>>>(h3, ae_w4, ae_b4, h4);

  k_inp      <<<cdiv(128*32*171, TPB), TPB, 0, stream>>>(h4, xmiu, inp);
  k_ul1      <<<1360 + 3440, TPB, 0, stream>>>(inp, wn, x1, p1);
  k_logic2p  <<<dim3(85, 8, 2), TPB, 0, stream>>>(x1, p1, wn, p2);
  k_fin2     <<<cdiv(128*12*192, TPB), TPB, 0, stream>>>(p2, x2p);

  k_gemm<1536,1024,192,1,ACT_RELU><<<dim3(24,16,1), 256, 0, stream>>>(x2p, w1p, fc1_b, fc1h);
  k_gemm<1536,256,1024,4,ACT_NONE><<<dim3(24,4,4), 256, 0, stream>>>(fc1h, fc2_w, fc2_b, gp);
  k_tail     <<<1536, 256, 0, stream>>>(gp, fc2_b, fc3_w, fc3_b, out);
}